// Round 13
// baseline (367.264 us; speedup 1.0000x reference)
//
#include <hip/hip_runtime.h>
#include <hip/hip_bf16.h>
#include <cstdint>
#include <cstddef>

#define NN 100000
#define NE 1600000
#define TAU 0.3f
#define REGION 400000   // stage slots per dst-partition

typedef __attribute__((ext_vector_type(8))) short bf16x8;
typedef __attribute__((ext_vector_type(4))) float f32x4;

#if __has_builtin(__builtin_amdgcn_sdot4)
#define HAVE_SDOT4 1
#else
#define HAVE_SDOT4 0
#endif

static __device__ __forceinline__ float b2f_hi(uint w) {
  return __uint_as_float(w & 0xffff0000u);
}
static __device__ __forceinline__ float b2f_lo(uint w) {
  return __uint_as_float(w << 16);
}
static __device__ __forceinline__ ushort f2b(float f) {
  uint x = __float_as_uint(f);
  return (ushort)((x + 0x7fffu + ((x >> 16) & 1u)) >> 16);
}
// sign-extended byte k of word w -> float
static __device__ __forceinline__ float i8f(uint w, int k) {
  return (float)((int)(w << (24 - 8 * k)) >> 24);
}
static __device__ __forceinline__ int dot4i8(uint a, uint b, int c) {
#if HAVE_SDOT4
  return __builtin_amdgcn_sdot4((int)a, (int)b, c, false);
#else
  return c + (int)(char)(a) * (int)(char)(b)
           + (int)(char)(a >> 8) * (int)(char)(b >> 8)
           + (int)(char)(a >> 16) * (int)(char)(b >> 16)
           + (int)(char)(a >> 24) * (int)(char)(b >> 24);
#endif
}

// ------- K1: conv_h (blocks 0..6249) + prep (6250..6505) + stage (6506..7287) -------
__global__ __launch_bounds__(256) void setup_stage(
    const float* __restrict__ h, ushort* __restrict__ A,
    const float* __restrict__ Wq, const float* __restrict__ Wk, const float* __restrict__ Wm,
    const float* __restrict__ bq, const float* __restrict__ bk, const float* __restrict__ bm,
    const float* __restrict__ Wout,
    ushort* __restrict__ BTproj, ushort* __restrict__ BTout, float* __restrict__ bvec,
    const int* __restrict__ src, const int* __restrict__ dst,
    int* __restrict__ stageCur, int2* __restrict__ stage) {
  int b = blockIdx.x;
  int t = threadIdx.x;
  if (b < 6250) {                       // h f32 -> bf16
    int i = b * 256 + t;
    const float4* hv = (const float4*)h + (size_t)i * 2;
    float4 a = hv[0], c = hv[1];
    uint4 o;
    o.x = (uint)f2b(a.x) | ((uint)f2b(a.y) << 16);
    o.y = (uint)f2b(a.z) | ((uint)f2b(a.w) << 16);
    o.z = (uint)f2b(c.x) | ((uint)f2b(c.y) << 16);
    o.w = (uint)f2b(c.z) | ((uint)f2b(c.w) << 16);
    ((uint4*)A)[i] = o;
    return;
  }
  if (b < 6506) {                       // weight prep, 65536 threads
    int id = (b - 6250) * 256 + t;
    if (id < 384 * 128) {
      int j = id >> 7, k = id & 127;
      int w = j >> 7, r = j & 127, hh = r >> 5, d = r & 31;
      const float* W = (w == 0) ? Wq : (w == 1) ? Wk : Wm;
      BTproj[id] = f2b(W[hh * 4096 + k * 32 + d]);
      if (k == 0) {
        const float* bb = (w == 0) ? bq : (w == 1) ? bk : bm;
        bvec[j] = bb[hh * 32 + d];
      }
    } else {
      int id2 = id - 384 * 128;                // 16384
      int c = id2 >> 7, k = id2 & 127;
      BTout[id2] = f2b(Wout[k * 128 + c]);
    }
    return;
  }
  // stage branch: 782 blocks x 2048 edges, bin by dst>>14 into fixed regions
  __shared__ int cnt[8];
  __shared__ int gbase[8];
  if (t < 8) cnt[t] = 0;
  __syncthreads();
  int e0 = (b - 6506) * 2048 + t;
  int d[8], s[8];
#pragma unroll
  for (int i = 0; i < 8; i++) {
    int e = e0 + i * 256;
    if (e < NE) {
      d[i] = dst[e];
      s[i] = src[e];
      atomicAdd(&cnt[d[i] >> 14], 1);
    } else {
      d[i] = -1;
    }
  }
  __syncthreads();
  if (t < 8) gbase[t] = atomicAdd(&stageCur[t * 16], cnt[t]);
  __syncthreads();
  if (t < 8) cnt[t] = 0;
  __syncthreads();
#pragma unroll
  for (int i = 0; i < 8; i++) {
    if (d[i] >= 0) {
      int p = d[i] >> 14;
      int slot = p * REGION + gbase[p] + atomicAdd(&cnt[p], 1);
      stage[slot] = make_int2(s[i], d[i]);
    }
  }
}

// ------- K2: partition-local histogram from staged edges (p = blockIdx&7) -------
__global__ __launch_bounds__(256) void hist_part(
    const int2* __restrict__ stage, const int* __restrict__ stageCur,
    int* __restrict__ counts) {
  int p = blockIdx.x & 7;
  int k = blockIdx.x >> 3;              // 0..31
  int n = stageCur[p * 16];
  const int2* reg = stage + (size_t)p * REGION;
  for (int i = k * 256 + threadIdx.x; i < n; i += 32 * 256)
    atomicAdd(&counts[reg[i].y], 1);
}

// ---------------- MFMA GEMM: C[M][ncols] = A[M][128] * BT^T + bias ----------------
// A in LDS (32 KB only); B panel (64 cols x 128 k per wave) in registers (L2-hot, tiny).
template <int RELU, int OUTBF>
__global__ __launch_bounds__(256) void mfma_gemm(
    const ushort* __restrict__ A, const ushort* __restrict__ BT,
    const float* __restrict__ bias, void* __restrict__ Cp, int M, int ncols) {
  __shared__ ushort As[128 * 128];   // 32 KB

  int t = threadIdx.x;
  int rowBase = blockIdx.x * 128, colBase = blockIdx.y * 128;

#pragma unroll
  for (int i = 0; i < 8; i++) {
    int flat = t + i * 256;            // 2048 chunks of 16B
    int row = flat >> 4;
    int kb = (flat & 15) * 16;
    int soff = kb ^ ((row & 7) << 4);  // pre-swizzled source (G21)
    int ar = rowBase + row; if (ar >= M) ar = M - 1;
    __builtin_amdgcn_global_load_lds(
        (const __attribute__((address_space(1))) uint32_t*)((const char*)A + (size_t)ar * 256 + soff),
        (__attribute__((address_space(3))) uint32_t*)((char*)As + row * 256 + kb), 16, 0, 0);
  }

  int wv = t >> 6, L = t & 63;
  int wrow = (wv >> 1) * 64, wcol = (wv & 1) * 64;
  int lr = L & 15;
  int lk8 = (L >> 4) * 8;              // ushort offset of lane's 8 bf16 in a 32-k step

  // B fragments to registers: 16 coalesced 16B loads per lane
  bf16x8 b[4][4];
#pragma unroll
  for (int j = 0; j < 4; j++) {
    const ushort* bp = BT + (size_t)(colBase + wcol + j * 16 + lr) * 128 + lk8;
#pragma unroll
    for (int ks = 0; ks < 4; ks++)
      b[j][ks] = *(const bf16x8*)(bp + ks * 32);
  }
  __syncthreads();

  f32x4 acc[4][4] = {};
#pragma unroll
  for (int ks = 0; ks < 4; ks++) {
    bf16x8 a[4];
#pragma unroll
    for (int i = 0; i < 4; i++) {
      int row = wrow + i * 16 + lr;
      a[i] = *(const bf16x8*)((const char*)As + row * 256 +
                              ((ks * 64 + lk8 * 2) ^ ((row & 7) << 4)));
    }
#pragma unroll
    for (int i = 0; i < 4; i++)
#pragma unroll
      for (int j = 0; j < 4; j++)
        acc[i][j] = __builtin_amdgcn_mfma_f32_16x16x32_bf16(a[i], b[j][ks], acc[i][j], 0, 0, 0);
  }

  int rquad = (L >> 4) * 4;
#pragma unroll
  for (int j = 0; j < 4; j++) {
    int col = colBase + wcol + j * 16 + lr;
    float bs = bias[col];
#pragma unroll
    for (int i = 0; i < 4; i++) {
      int row0 = rowBase + wrow + i * 16 + rquad;
#pragma unroll
      for (int r = 0; r < 4; r++) {
        int row = row0 + r;
        if (row >= M) continue;
        float v = acc[i][j][r] + bs;
        if (RELU) v = fmaxf(v, 0.f);
        if (OUTBF) ((ushort*)Cp)[(size_t)row * ncols + col] = f2b(v);
        else       ((float*)Cp)[(size_t)row * ncols + col] = v;
      }
    }
  }
}

// ---------------- CSR scans ----------------
__global__ __launch_bounds__(256) void scan_a(const int* __restrict__ counts,
                                              int* __restrict__ offsets,
                                              int* __restrict__ blockSums, int n) {
  __shared__ int lds[256];
  int b = blockIdx.x, t = threadIdx.x;
  int base = b * 1024 + t * 4;
  int4 v = make_int4(0, 0, 0, 0);
  if (base < n) v = *(const int4*)&counts[base];
  int s1 = v.x + v.y, s2 = s1 + v.z, s3 = s2 + v.w;
  lds[t] = s3;
  __syncthreads();
  for (int dd = 1; dd < 256; dd <<= 1) {
    int x = (t >= dd) ? lds[t - dd] : 0;
    __syncthreads();
    lds[t] += x;
    __syncthreads();
  }
  int excl = (t > 0) ? lds[t - 1] : 0;
  if (base < n) {
    int4 o = make_int4(excl, excl + v.x, excl + s1, excl + s2);
    *(int4*)&offsets[base] = o;
  }
  if (t == 255) blockSums[b] = lds[255];
}

__global__ __launch_bounds__(128) void scan_b(int* __restrict__ blockSums, int nb) {
  __shared__ int lds[128];
  int t = threadIdx.x;
  lds[t] = (t < nb) ? blockSums[t] : 0;
  __syncthreads();
  for (int dd = 1; dd < 128; dd <<= 1) {
    int x = (t >= dd) ? lds[t - dd] : 0;
    __syncthreads();
    lds[t] += x;
    __syncthreads();
  }
  if (t < nb) blockSums[t] = (t > 0) ? lds[t - 1] : 0;
}

__global__ __launch_bounds__(256) void scan_c(int* __restrict__ offsets,
                                              const int* __restrict__ blockSums,
                                              int* __restrict__ cursor, int n) {
  int i = blockIdx.x * 256 + threadIdx.x;
  if (i < n) {
    int v = offsets[i] + blockSums[i >> 10];
    offsets[i] = v;
    cursor[i] = v;
  }
  if (i == 0) offsets[n] = NE;
}

// ------- quant: Zbf (zk|zm[,zq]) -> int8 + per-row scales -------
__global__ __launch_bounds__(256) void quant_kernel(
    const ushort* __restrict__ Zbf, char* __restrict__ Zkm, float2* __restrict__ scales,
    char* __restrict__ Zq8, float* __restrict__ sqv, int doQ8) {
  int g = blockIdx.x * 256 + threadIdx.x;   // 1.6M threads = 100K rows x 16 units
  int row = g >> 4, u = g & 15;
  const ushort* zr = Zbf + (size_t)row * 384;
  uint4 kk = *(const uint4*)(zr + 128 + u * 8);
  uint4 mm = *(const uint4*)(zr + 256 + u * 8);
  uint4 qq = *(const uint4*)(zr + u * 8);
  float kf[8] = {b2f_lo(kk.x), b2f_hi(kk.x), b2f_lo(kk.y), b2f_hi(kk.y),
                 b2f_lo(kk.z), b2f_hi(kk.z), b2f_lo(kk.w), b2f_hi(kk.w)};
  float mf[8] = {b2f_lo(mm.x), b2f_hi(mm.x), b2f_lo(mm.y), b2f_hi(mm.y),
                 b2f_lo(mm.z), b2f_hi(mm.z), b2f_lo(mm.w), b2f_hi(mm.w)};
  float qf[8] = {b2f_lo(qq.x), b2f_hi(qq.x), b2f_lo(qq.y), b2f_hi(qq.y),
                 b2f_lo(qq.z), b2f_hi(qq.z), b2f_lo(qq.w), b2f_hi(qq.w)};
  float mk = 0.f, mx = 0.f, mqv = 0.f;
#pragma unroll
  for (int i = 0; i < 8; i++) {
    mk = fmaxf(mk, fabsf(kf[i]));
    mx = fmaxf(mx, fabsf(mf[i]));
    mqv = fmaxf(mqv, fabsf(qf[i]));
  }
#pragma unroll
  for (int dd = 1; dd < 16; dd <<= 1) {
    mk = fmaxf(mk, __shfl_xor(mk, dd));
    mx = fmaxf(mx, __shfl_xor(mx, dd));
    mqv = fmaxf(mqv, __shfl_xor(mqv, dd));
  }
  mk = fmaxf(mk, 1e-20f); mx = fmaxf(mx, 1e-20f); mqv = fmaxf(mqv, 1e-20f);
  float qk = 127.0f / mk, qm = 127.0f / mx;
  int q[16];
#pragma unroll
  for (int i = 0; i < 8; i++) {
    q[i] = __float2int_rn(kf[i] * qk) & 0xff;
    q[8 + i] = __float2int_rn(mf[i] * qm) & 0xff;
  }
  uint4 o;
  o.x = (uint)(q[0] | (q[1] << 8) | (q[2] << 16) | (q[3] << 24));
  o.y = (uint)(q[4] | (q[5] << 8) | (q[6] << 16) | (q[7] << 24));
  o.z = (uint)(q[8] | (q[9] << 8) | (q[10] << 16) | (q[11] << 24));
  o.w = (uint)(q[12] | (q[13] << 8) | (q[14] << 16) | (q[15] << 24));
  *(uint4*)(Zkm + (size_t)row * 256 + u * 16) = o;
  if (u == 0) scales[row] = make_float2(mk * (1.0f / 127.0f), mx * (1.0f / 127.0f));
  if (doQ8) {
    float qs = 127.0f / mqv;
    int r[8];
#pragma unroll
    for (int i = 0; i < 8; i++) r[i] = __float2int_rn(qf[i] * qs) & 0xff;
    uint2 oq;
    oq.x = (uint)(r[0] | (r[1] << 8) | (r[2] << 16) | (r[3] << 24));
    oq.y = (uint)(r[4] | (r[5] << 8) | (r[6] << 16) | (r[7] << 24));
    *(uint2*)(Zq8 + (size_t)row * 128 + u * 8) = oq;
    if (u == 0) sqv[row] = mqv * (1.0f / 127.0f);
  }
}

// ------- scatter: per-partition from stage into CSR (partition p = blockIdx&7) -------
__global__ __launch_bounds__(256) void scatter_final(
    const int2* __restrict__ stage, const int* __restrict__ stageCur,
    int* __restrict__ cursor, int* __restrict__ csr_src) {
  int p = blockIdx.x & 7;
  int k = blockIdx.x >> 3;              // 0..129
  int n = stageCur[p * 16];
  const int2* reg = stage + (size_t)p * REGION;
  for (int i = k * 256 + threadIdx.x; i < n; i += 130 * 256) {
    int2 e = reg[i];
    int pos = atomicAdd(&cursor[e.y], 1);
    csr_src[pos] = e.x;
  }
}

// ---------------- fused attention + aggregation, int8 gathers ----------------
// QDOT=1: logits via int8 dot4 against per-node int8 zq. QDOT=0: bf16-zq float path.
template <int QDOT>
__global__ __launch_bounds__(256) void aggregate_q(
    const char* __restrict__ Zkm, const ushort* __restrict__ Zbf,
    const float2* __restrict__ scales,
    const int* __restrict__ offsets, const int* __restrict__ csr_src,
    ushort* __restrict__ aggbf,
    const char* __restrict__ Zq8, const float* __restrict__ sqv) {
  int wv = threadIdx.x >> 6, L = threadIdx.x & 63;
  int n = blockIdx.x * 4 + wv;
  if (n >= NN) return;
  int qt = L >> 4, l = L & 15;
  int lb = l << 4;                         // byte offset within 256B row

  float q0, q1, q2, q3, q4, q5, q6, q7;
  uint2 q8;
  float tq;
  if constexpr (QDOT) {
    q8 = *(const uint2*)(Zq8 + (size_t)n * 128 + l * 8);
    tq = TAU * sqv[n];
  } else {
    uint4 qw = *(const uint4*)((const char*)Zbf + (size_t)n * 768 + lb);
    q0 = b2f_lo(qw.x); q1 = b2f_hi(qw.x); q2 = b2f_lo(qw.y); q3 = b2f_hi(qw.y);
    q4 = b2f_lo(qw.z); q5 = b2f_hi(qw.z); q6 = b2f_lo(qw.w); q7 = b2f_hi(qw.w);
  }

  int start = offsets[n], end = offsets[n + 1];
  float den = 0.f;
  float a0 = 0.f, a1 = 0.f, a2 = 0.f, a3 = 0.f, a4 = 0.f, a5 = 0.f, a6 = 0.f, a7 = 0.f;
  int p = start;

  for (; p + 8 <= end; p += 8) {
    int s0 = csr_src[p + qt];
    int s1 = csr_src[p + 4 + qt];
    uint4 v0 = *(const uint4*)(Zkm + ((size_t)s0 << 8) + lb);
    uint4 v1 = *(const uint4*)(Zkm + ((size_t)s1 << 8) + lb);
    float2 sc0 = scales[s0];
    float2 sc1 = scales[s1];

    float w0, w1;
    if constexpr (QDOT) {
      int p0 = dot4i8(v0.x, q8.x, 0); p0 = dot4i8(v0.y, q8.y, p0);
      int p1 = dot4i8(v1.x, q8.x, 0); p1 = dot4i8(v1.y, q8.y, p1);
      p0 += __shfl_xor(p0, 1); p1 += __shfl_xor(p1, 1);
      p0 += __shfl_xor(p0, 2); p1 += __shfl_xor(p1, 2);
      w0 = __expf(tq * sc0.x * (float)p0);
      w1 = __expf(tq * sc1.x * (float)p1);
    } else {
      float pd0 = i8f(v0.x, 0) * q0;
      pd0 = fmaf(i8f(v0.x, 1), q1, pd0); pd0 = fmaf(i8f(v0.x, 2), q2, pd0);
      pd0 = fmaf(i8f(v0.x, 3), q3, pd0); pd0 = fmaf(i8f(v0.y, 0), q4, pd0);
      pd0 = fmaf(i8f(v0.y, 1), q5, pd0); pd0 = fmaf(i8f(v0.y, 2), q6, pd0);
      pd0 = fmaf(i8f(v0.y, 3), q7, pd0);
      float pd1 = i8f(v1.x, 0) * q0;
      pd1 = fmaf(i8f(v1.x, 1), q1, pd1); pd1 = fmaf(i8f(v1.x, 2), q2, pd1);
      pd1 = fmaf(i8f(v1.x, 3), q3, pd1); pd1 = fmaf(i8f(v1.y, 0), q4, pd1);
      pd1 = fmaf(i8f(v1.y, 1), q5, pd1); pd1 = fmaf(i8f(v1.y, 2), q6, pd1);
      pd1 = fmaf(i8f(v1.y, 3), q7, pd1);
      pd0 += __shfl_xor(pd0, 1); pd1 += __shfl_xor(pd1, 1);
      pd0 += __shfl_xor(pd0, 2); pd1 += __shfl_xor(pd1, 2);
      w0 = __expf(TAU * sc0.x * pd0);
      w1 = __expf(TAU * sc1.x * pd1);
    }
    den += w0 + w1;
    float wm0 = w0 * sc0.y, wm1 = w1 * sc1.y;

    a0 = fmaf(i8f(v0.z, 0), wm0, a0); a1 = fmaf(i8f(v0.z, 1), wm0, a1);
    a2 = fmaf(i8f(v0.z, 2), wm0, a2); a3 = fmaf(i8f(v0.z, 3), wm0, a3);
    a4 = fmaf(i8f(v0.w, 0), wm0, a4); a5 = fmaf(i8f(v0.w, 1), wm0, a5);
    a6 = fmaf(i8f(v0.w, 2), wm0, a6); a7 = fmaf(i8f(v0.w, 3), wm0, a7);
    a0 = fmaf(i8f(v1.z, 0), wm1, a0); a1 = fmaf(i8f(v1.z, 1), wm1, a1);
    a2 = fmaf(i8f(v1.z, 2), wm1, a2); a3 = fmaf(i8f(v1.z, 3), wm1, a3);
    a4 = fmaf(i8f(v1.w, 0), wm1, a4); a5 = fmaf(i8f(v1.w, 1), wm1, a5);
    a6 = fmaf(i8f(v1.w, 2), wm1, a6); a7 = fmaf(i8f(v1.w, 3), wm1, a7);
  }

  for (; p < end; p += 4) {               // masked tail, whole wave stays
    int e = p + qt;
    int idx = (e < end) ? e : (end - 1);
    int s0 = csr_src[idx];
    uint4 v = *(const uint4*)(Zkm + ((size_t)s0 << 8) + lb);
    float2 sc = scales[s0];
    float w;
    if constexpr (QDOT) {
      int p0 = dot4i8(v.x, q8.x, 0); p0 = dot4i8(v.y, q8.y, p0);
      p0 += __shfl_xor(p0, 1);
      p0 += __shfl_xor(p0, 2);
      w = (e < end) ? __expf(tq * sc.x * (float)p0) : 0.f;
    } else {
      float pd = i8f(v.x, 0) * q0;
      pd = fmaf(i8f(v.x, 1), q1, pd); pd = fmaf(i8f(v.x, 2), q2, pd);
      pd = fmaf(i8f(v.x, 3), q3, pd); pd = fmaf(i8f(v.y, 0), q4, pd);
      pd = fmaf(i8f(v.y, 1), q5, pd); pd = fmaf(i8f(v.y, 2), q6, pd);
      pd = fmaf(i8f(v.y, 3), q7, pd);
      pd += __shfl_xor(pd, 1);
      pd += __shfl_xor(pd, 2);
      w = (e < end) ? __expf(TAU * sc.x * pd) : 0.f;
    }
    den += w;
    float wm = w * sc.y;
    a0 = fmaf(i8f(v.z, 0), wm, a0); a1 = fmaf(i8f(v.z, 1), wm, a1);
    a2 = fmaf(i8f(v.z, 2), wm, a2); a3 = fmaf(i8f(v.z, 3), wm, a3);
    a4 = fmaf(i8f(v.w, 0), wm, a4); a5 = fmaf(i8f(v.w, 1), wm, a5);
    a6 = fmaf(i8f(v.w, 2), wm, a6); a7 = fmaf(i8f(v.w, 3), wm, a7);
  }

  // combine the four quarters (same l -> same dims/head)
  den += __shfl_xor(den, 16); den += __shfl_xor(den, 32);
  a0 += __shfl_xor(a0, 16); a0 += __shfl_xor(a0, 32);
  a1 += __shfl_xor(a1, 16); a1 += __shfl_xor(a1, 32);
  a2 += __shfl_xor(a2, 16); a2 += __shfl_xor(a2, 32);
  a3 += __shfl_xor(a3, 16); a3 += __shfl_xor(a3, 32);
  a4 += __shfl_xor(a4, 16); a4 += __shfl_xor(a4, 32);
  a5 += __shfl_xor(a5, 16); a5 += __shfl_xor(a5, 32);
  a6 += __shfl_xor(a6, 16); a6 += __shfl_xor(a6, 32);
  a7 += __shfl_xor(a7, 16); a7 += __shfl_xor(a7, 32);

  float inv = (den > 0.f) ? 1.0f / den : 0.f;
  if (qt == 0) {
    uint4 o;
    o.x = (uint)f2b(a0 * inv) | ((uint)f2b(a1 * inv) << 16);
    o.y = (uint)f2b(a2 * inv) | ((uint)f2b(a3 * inv) << 16);
    o.z = (uint)f2b(a4 * inv) | ((uint)f2b(a5 * inv) << 16);
    o.w = (uint)f2b(a6 * inv) | ((uint)f2b(a7 * inv) << 16);
    *(uint4*)((char*)aggbf + (size_t)n * 256 + lb) = o;
  }
}

// ---------------- launch ----------------
extern "C" void kernel_launch(void* const* d_in, const int* in_sizes, int n_in,
                              void* d_out, int out_size, void* d_ws, size_t ws_size,
                              hipStream_t stream) {
  const float* h    = (const float*)d_in[0];
  const int*   src  = (const int*)d_in[1];
  const int*   dst  = (const int*)d_in[2];
  const float* Wq   = (const float*)d_in[3];
  const float* bq   = (const float*)d_in[4];
  const float* Wk   = (const float*)d_in[5];
  const float* bk   = (const float*)d_in[6];
  const float* Wm   = (const float*)d_in[7];
  const float* bm   = (const float*)d_in[8];
  const float* Wout = (const float*)d_in[9];
  const float* bout = (const float*)d_in[10];
  float* out = (float*)d_out;

  char* base = (char*)d_ws;
  ushort* Abf    = (ushort*)base;                         // NN*128 bf16 (reused as Zkm)
  char*   Zkm    = base;                                  // NN*256B int8, overlaps Abf
  ushort* Zbf    = (ushort*)(base + 25600000);            // NN*384 bf16
  ushort* aggbf  = (ushort*)(base + 102400000);           // NN*128 bf16
  int2*   stage  = (int2*)(base + 102400000);             // 8*REGION int2, dead before aggbf
  float2* scales = (float2*)(base + 128000000);           // NN float2
  ushort* BTproj = (ushort*)(base + 128800000);           // 98304 B
  ushort* BTout  = (ushort*)(base + 128898304);           // 32768 B
  float*  bvec   = (float*)(base + 128931072);            // 2048 B pad
  int* counts    = (int*)(base + 128933120);              // 400000 B
  int* stageCur  = (int*)(base + 129333120);              // 8 ctrs, 64B stride (1024 B)
  int* offsets   = (int*)(base + 129334144);              // (NN+1)*4 -> pad 400128
  int* cursor    = (int*)(base + 129734272);              // 400000 B
  int* blockSums = (int*)(base + 130134272);              // 512 B
  int* csr_src   = (int*)(base + 130134784);              // NE*4 -> ends 136534784
  char* Zq8      = base + 136534784;                      // NN*128 int8 (12.8 MB)
  float* sqv     = (float*)(base + 149334784);            // NN f32 -> ends 149734784

  int useQ8 = (ws_size >= (size_t)149734784) ? 1 : 0;

  hipMemsetAsync(counts, 0, 401024, stream);

  setup_stage<<<7288, 256, 0, stream>>>(h, Abf, Wq, Wk, Wm, bq, bk, bm, Wout,
                                        BTproj, BTout, bvec, src, dst, stageCur, stage);
  hist_part<<<256, 256, 0, stream>>>(stage, stageCur, counts);
  scan_a<<<98, 256, 0, stream>>>(counts, offsets, blockSums, NN);
  scan_b<<<1, 128, 0, stream>>>(blockSums, 98);
  scan_c<<<391, 256, 0, stream>>>(offsets, blockSums, cursor, NN);

  mfma_gemm<0, 1><<<dim3(782, 3), 256, 0, stream>>>(Abf, BTproj, bvec, Zbf, NN, 384);

  quant_kernel<<<6250, 256, 0, stream>>>(Zbf, Zkm, scales, Zq8, sqv, useQ8);
  scatter_final<<<1040, 256, 0, stream>>>(stage, stageCur, cursor, csr_src);

  if (useQ8)
    aggregate_q<1><<<25000, 256, 0, stream>>>(Zkm, Zbf, scales, offsets, csr_src,
                                              aggbf, Zq8, sqv);
  else
    aggregate_q<0><<<25000, 256, 0, stream>>>(Zkm, Zbf, scales, offsets, csr_src,
                                              aggbf, Zq8, sqv);

  mfma_gemm<1, 0><<<dim3(782, 1), 256, 0, stream>>>(aggbf, BTout, bout, out, NN, 128);
}

// Round 14
// 339.863 us; speedup vs baseline: 1.0806x; 1.0806x over previous
//
#include <hip/hip_runtime.h>
#include <hip/hip_bf16.h>
#include <cstdint>
#include <cstddef>

#define NN 100000
#define NE 1600000
#define TAU 0.3f
#define REGION 400000   // stage slots per dst-partition

typedef __attribute__((ext_vector_type(8))) short bf16x8;
typedef __attribute__((ext_vector_type(4))) float f32x4;

#if __has_builtin(__builtin_amdgcn_sdot4)
#define HAVE_SDOT4 1
#else
#define HAVE_SDOT4 0
#endif

static __device__ __forceinline__ float b2f_hi(uint w) {
  return __uint_as_float(w & 0xffff0000u);
}
static __device__ __forceinline__ float b2f_lo(uint w) {
  return __uint_as_float(w << 16);
}
static __device__ __forceinline__ ushort f2b(float f) {
  uint x = __float_as_uint(f);
  return (ushort)((x + 0x7fffu + ((x >> 16) & 1u)) >> 16);
}
// sign-extended byte k of word w -> float
static __device__ __forceinline__ float i8f(uint w, int k) {
  return (float)((int)(w << (24 - 8 * k)) >> 24);
}
static __device__ __forceinline__ int dot4i8(uint a, uint b, int c) {
#if HAVE_SDOT4
  return __builtin_amdgcn_sdot4((int)a, (int)b, c, false);
#else
  return c + (int)(char)(a) * (int)(char)(b)
           + (int)(char)(a >> 8) * (int)(char)(b >> 8)
           + (int)(char)(a >> 16) * (int)(char)(b >> 16)
           + (int)(char)(a >> 24) * (int)(char)(b >> 24);
#endif
}

// ------- K1: conv_h (blocks 0..6249) + prep (6250..6505) + stage (6506..7287) -------
__global__ __launch_bounds__(256) void setup_stage(
    const float* __restrict__ h, ushort* __restrict__ A,
    const float* __restrict__ Wq, const float* __restrict__ Wk, const float* __restrict__ Wm,
    const float* __restrict__ bq, const float* __restrict__ bk, const float* __restrict__ bm,
    const float* __restrict__ Wout,
    ushort* __restrict__ BTproj, ushort* __restrict__ BTout, float* __restrict__ bvec,
    const int* __restrict__ src, const int* __restrict__ dst,
    int* __restrict__ stageCur, int2* __restrict__ stage) {
  int b = blockIdx.x;
  int t = threadIdx.x;
  if (b < 6250) {                       // h f32 -> bf16
    int i = b * 256 + t;
    const float4* hv = (const float4*)h + (size_t)i * 2;
    float4 a = hv[0], c = hv[1];
    uint4 o;
    o.x = (uint)f2b(a.x) | ((uint)f2b(a.y) << 16);
    o.y = (uint)f2b(a.z) | ((uint)f2b(a.w) << 16);
    o.z = (uint)f2b(c.x) | ((uint)f2b(c.y) << 16);
    o.w = (uint)f2b(c.z) | ((uint)f2b(c.w) << 16);
    ((uint4*)A)[i] = o;
    return;
  }
  if (b < 6506) {                       // weight prep, 65536 threads
    int id = (b - 6250) * 256 + t;
    if (id < 384 * 128) {
      int j = id >> 7, k = id & 127;
      int w = j >> 7, r = j & 127, hh = r >> 5, d = r & 31;
      const float* W = (w == 0) ? Wq : (w == 1) ? Wk : Wm;
      BTproj[id] = f2b(W[hh * 4096 + k * 32 + d]);
      if (k == 0) {
        const float* bb = (w == 0) ? bq : (w == 1) ? bk : bm;
        bvec[j] = bb[hh * 32 + d];
      }
    } else {
      int id2 = id - 384 * 128;                // 16384
      int c = id2 >> 7, k = id2 & 127;
      BTout[id2] = f2b(Wout[k * 128 + c]);
    }
    return;
  }
  // stage branch: 782 blocks x 2048 edges, bin by dst>>14 into fixed regions
  __shared__ int cnt[8];
  __shared__ int gbase[8];
  if (t < 8) cnt[t] = 0;
  __syncthreads();
  int e0 = (b - 6506) * 2048 + t;
  int d[8], s[8];
#pragma unroll
  for (int i = 0; i < 8; i++) {
    int e = e0 + i * 256;
    if (e < NE) {
      d[i] = dst[e];
      s[i] = src[e];
      atomicAdd(&cnt[d[i] >> 14], 1);
    } else {
      d[i] = -1;
    }
  }
  __syncthreads();
  if (t < 8) gbase[t] = atomicAdd(&stageCur[t * 16], cnt[t]);
  __syncthreads();
  if (t < 8) cnt[t] = 0;
  __syncthreads();
#pragma unroll
  for (int i = 0; i < 8; i++) {
    if (d[i] >= 0) {
      int p = d[i] >> 14;
      int slot = p * REGION + gbase[p] + atomicAdd(&cnt[p], 1);
      stage[slot] = make_int2(s[i], d[i]);
    }
  }
}

// ------- K2: partition-local histogram from staged edges (p = blockIdx&7) -------
__global__ __launch_bounds__(256) void hist_part(
    const int2* __restrict__ stage, const int* __restrict__ stageCur,
    int* __restrict__ counts) {
  int p = blockIdx.x & 7;
  int k = blockIdx.x >> 3;              // 0..31
  int n = stageCur[p * 16];
  const int2* reg = stage + (size_t)p * REGION;
  for (int i = k * 256 + threadIdx.x; i < n; i += 32 * 256)
    atomicAdd(&counts[reg[i].y], 1);
}

// ---------------- MFMA GEMM: C[M][ncols] = A[M][128] * BT^T + bias ----------------
// 64x128 tile: As 16 KB + Bs 32 KB = 48 KB -> 3 blocks/CU. 4 waves of 32x64.
template <int RELU, int OUTBF>
__global__ __launch_bounds__(256) void mfma_gemm(
    const ushort* __restrict__ A, const ushort* __restrict__ BT,
    const float* __restrict__ bias, void* __restrict__ Cp, int M, int ncols) {
  __shared__ ushort As[64 * 128];    // 16 KB
  __shared__ ushort Bs[128 * 128];   // 32 KB

  int t = threadIdx.x;
  int rowBase = blockIdx.x * 64, colBase = blockIdx.y * 128;

#pragma unroll
  for (int i = 0; i < 4; i++) {      // A: 1024 chunks of 16B
    int flat = t + i * 256;
    int row = flat >> 4;
    int kb = (flat & 15) * 16;
    int soff = kb ^ ((row & 7) << 4);
    int ar = rowBase + row; if (ar >= M) ar = M - 1;
    __builtin_amdgcn_global_load_lds(
        (const __attribute__((address_space(1))) uint32_t*)((const char*)A + (size_t)ar * 256 + soff),
        (__attribute__((address_space(3))) uint32_t*)((char*)As + row * 256 + kb), 16, 0, 0);
  }
#pragma unroll
  for (int i = 0; i < 8; i++) {      // B: 2048 chunks of 16B
    int flat = t + i * 256;
    int row = flat >> 4;
    int kb = (flat & 15) * 16;
    int soff = kb ^ ((row & 7) << 4);
    __builtin_amdgcn_global_load_lds(
        (const __attribute__((address_space(1))) uint32_t*)((const char*)BT + (size_t)(colBase + row) * 256 + soff),
        (__attribute__((address_space(3))) uint32_t*)((char*)Bs + row * 256 + kb), 16, 0, 0);
  }
  __syncthreads();

  int wv = t >> 6, L = t & 63;
  int wrow = (wv >> 1) * 32, wcol = (wv & 1) * 64;
  int lr = L & 15;
  int lk = (L >> 4) * 16;
  f32x4 acc[2][4] = {};

#pragma unroll
  for (int ks = 0; ks < 4; ks++) {
    bf16x8 a[2], b[4];
#pragma unroll
    for (int i = 0; i < 2; i++) {
      int row = wrow + i * 16 + lr;
      a[i] = *(const bf16x8*)((const char*)As + row * 256 + ((ks * 64 + lk) ^ ((row & 7) << 4)));
    }
#pragma unroll
    for (int j = 0; j < 4; j++) {
      int col = wcol + j * 16 + lr;
      b[j] = *(const bf16x8*)((const char*)Bs + col * 256 + ((ks * 64 + lk) ^ ((col & 7) << 4)));
    }
#pragma unroll
    for (int i = 0; i < 2; i++)
#pragma unroll
      for (int j = 0; j < 4; j++)
        acc[i][j] = __builtin_amdgcn_mfma_f32_16x16x32_bf16(a[i], b[j], acc[i][j], 0, 0, 0);
  }

  int rquad = (L >> 4) * 4;
#pragma unroll
  for (int j = 0; j < 4; j++) {
    int col = colBase + wcol + j * 16 + lr;
    float bs = bias[col];
#pragma unroll
    for (int i = 0; i < 2; i++) {
      int row0 = rowBase + wrow + i * 16 + rquad;
#pragma unroll
      for (int r = 0; r < 4; r++) {
        int row = row0 + r;
        if (row >= M) continue;
        float v = acc[i][j][r] + bs;
        if (RELU) v = fmaxf(v, 0.f);
        if (OUTBF) ((ushort*)Cp)[(size_t)row * ncols + col] = f2b(v);
        else       ((float*)Cp)[(size_t)row * ncols + col] = v;
      }
    }
  }
}

// ---------------- CSR scans ----------------
__global__ __launch_bounds__(256) void scan_a(const int* __restrict__ counts,
                                              int* __restrict__ offsets,
                                              int* __restrict__ blockSums, int n) {
  __shared__ int lds[256];
  int b = blockIdx.x, t = threadIdx.x;
  int base = b * 1024 + t * 4;
  int4 v = make_int4(0, 0, 0, 0);
  if (base < n) v = *(const int4*)&counts[base];
  int s1 = v.x + v.y, s2 = s1 + v.z, s3 = s2 + v.w;
  lds[t] = s3;
  __syncthreads();
  for (int dd = 1; dd < 256; dd <<= 1) {
    int x = (t >= dd) ? lds[t - dd] : 0;
    __syncthreads();
    lds[t] += x;
    __syncthreads();
  }
  int excl = (t > 0) ? lds[t - 1] : 0;
  if (base < n) {
    int4 o = make_int4(excl, excl + v.x, excl + s1, excl + s2);
    *(int4*)&offsets[base] = o;
  }
  if (t == 255) blockSums[b] = lds[255];
}

__global__ __launch_bounds__(128) void scan_b(int* __restrict__ blockSums, int nb) {
  __shared__ int lds[128];
  int t = threadIdx.x;
  lds[t] = (t < nb) ? blockSums[t] : 0;
  __syncthreads();
  for (int dd = 1; dd < 128; dd <<= 1) {
    int x = (t >= dd) ? lds[t - dd] : 0;
    __syncthreads();
    lds[t] += x;
    __syncthreads();
  }
  if (t < nb) blockSums[t] = (t > 0) ? lds[t - 1] : 0;
}

__global__ __launch_bounds__(256) void scan_c(int* __restrict__ offsets,
                                              const int* __restrict__ blockSums,
                                              int* __restrict__ cursor, int n) {
  int i = blockIdx.x * 256 + threadIdx.x;
  if (i < n) {
    int v = offsets[i] + blockSums[i >> 10];
    offsets[i] = v;
    cursor[i] = v;
  }
  if (i == 0) offsets[n] = NE;
}

// ------- quant: Zbf (zk|zm,zq) -> int8 + per-row scales -------
__global__ __launch_bounds__(256) void quant_kernel(
    const ushort* __restrict__ Zbf, char* __restrict__ Zkm, float2* __restrict__ scales,
    char* __restrict__ Zq8, float* __restrict__ sqv, int doQ8) {
  int g = blockIdx.x * 256 + threadIdx.x;   // 1.6M threads = 100K rows x 16 units
  int row = g >> 4, u = g & 15;
  const ushort* zr = Zbf + (size_t)row * 384;
  uint4 kk = *(const uint4*)(zr + 128 + u * 8);
  uint4 mm = *(const uint4*)(zr + 256 + u * 8);
  uint4 qq = *(const uint4*)(zr + u * 8);
  float kf[8] = {b2f_lo(kk.x), b2f_hi(kk.x), b2f_lo(kk.y), b2f_hi(kk.y),
                 b2f_lo(kk.z), b2f_hi(kk.z), b2f_lo(kk.w), b2f_hi(kk.w)};
  float mf[8] = {b2f_lo(mm.x), b2f_hi(mm.x), b2f_lo(mm.y), b2f_hi(mm.y),
                 b2f_lo(mm.z), b2f_hi(mm.z), b2f_lo(mm.w), b2f_hi(mm.w)};
  float qf[8] = {b2f_lo(qq.x), b2f_hi(qq.x), b2f_lo(qq.y), b2f_hi(qq.y),
                 b2f_lo(qq.z), b2f_hi(qq.z), b2f_lo(qq.w), b2f_hi(qq.w)};
  float mk = 0.f, mx = 0.f, mqv = 0.f;
#pragma unroll
  for (int i = 0; i < 8; i++) {
    mk = fmaxf(mk, fabsf(kf[i]));
    mx = fmaxf(mx, fabsf(mf[i]));
    mqv = fmaxf(mqv, fabsf(qf[i]));
  }
#pragma unroll
  for (int dd = 1; dd < 16; dd <<= 1) {
    mk = fmaxf(mk, __shfl_xor(mk, dd));
    mx = fmaxf(mx, __shfl_xor(mx, dd));
    mqv = fmaxf(mqv, __shfl_xor(mqv, dd));
  }
  mk = fmaxf(mk, 1e-20f); mx = fmaxf(mx, 1e-20f); mqv = fmaxf(mqv, 1e-20f);
  float qk = 127.0f / mk, qm = 127.0f / mx;
  int q[16];
#pragma unroll
  for (int i = 0; i < 8; i++) {
    q[i] = __float2int_rn(kf[i] * qk) & 0xff;
    q[8 + i] = __float2int_rn(mf[i] * qm) & 0xff;
  }
  uint4 o;
  o.x = (uint)(q[0] | (q[1] << 8) | (q[2] << 16) | (q[3] << 24));
  o.y = (uint)(q[4] | (q[5] << 8) | (q[6] << 16) | (q[7] << 24));
  o.z = (uint)(q[8] | (q[9] << 8) | (q[10] << 16) | (q[11] << 24));
  o.w = (uint)(q[12] | (q[13] << 8) | (q[14] << 16) | (q[15] << 24));
  *(uint4*)(Zkm + (size_t)row * 256 + u * 16) = o;
  if (u == 0) scales[row] = make_float2(mk * (1.0f / 127.0f), mx * (1.0f / 127.0f));
  if (doQ8) {
    float qs = 127.0f / mqv;
    int r[8];
#pragma unroll
    for (int i = 0; i < 8; i++) r[i] = __float2int_rn(qf[i] * qs) & 0xff;
    uint2 oq;
    oq.x = (uint)(r[0] | (r[1] << 8) | (r[2] << 16) | (r[3] << 24));
    oq.y = (uint)(r[4] | (r[5] << 8) | (r[6] << 16) | (r[7] << 24));
    *(uint2*)(Zq8 + (size_t)row * 128 + u * 8) = oq;
    if (u == 0) sqv[row] = mqv * (1.0f / 127.0f);
  }
}

// ------- scatter: per-partition from stage into CSR (partition p = blockIdx&7) -------
__global__ __launch_bounds__(256) void scatter_final(
    const int2* __restrict__ stage, const int* __restrict__ stageCur,
    int* __restrict__ cursor, int* __restrict__ csr_src) {
  int p = blockIdx.x & 7;
  int k = blockIdx.x >> 3;              // 0..129
  int n = stageCur[p * 16];
  const int2* reg = stage + (size_t)p * REGION;
  for (int i = k * 256 + threadIdx.x; i < n; i += 130 * 256) {
    int2 e = reg[i];
    int pos = atomicAdd(&cursor[e.y], 1);
    csr_src[pos] = e.x;
  }
}

// ---------------- fused attention + aggregation, int8 gathers ----------------
// QDOT=1: logits via int8 dot4 against per-node int8 zq. QDOT=0: bf16-zq float path.
template <int QDOT>
__global__ __launch_bounds__(256) void aggregate_q(
    const char* __restrict__ Zkm, const ushort* __restrict__ Zbf,
    const float2* __restrict__ scales,
    const int* __restrict__ offsets, const int* __restrict__ csr_src,
    ushort* __restrict__ aggbf,
    const char* __restrict__ Zq8, const float* __restrict__ sqv) {
  int wv = threadIdx.x >> 6, L = threadIdx.x & 63;
  int n = blockIdx.x * 4 + wv;
  if (n >= NN) return;
  int qt = L >> 4, l = L & 15;
  int lb = l << 4;                         // byte offset within 256B row

  float q0, q1, q2, q3, q4, q5, q6, q7;
  uint2 q8;
  float tq;
  if constexpr (QDOT) {
    q8 = *(const uint2*)(Zq8 + (size_t)n * 128 + l * 8);
    tq = TAU * sqv[n];
  } else {
    uint4 qw = *(const uint4*)((const char*)Zbf + (size_t)n * 768 + lb);
    q0 = b2f_lo(qw.x); q1 = b2f_hi(qw.x); q2 = b2f_lo(qw.y); q3 = b2f_hi(qw.y);
    q4 = b2f_lo(qw.z); q5 = b2f_hi(qw.z); q6 = b2f_lo(qw.w); q7 = b2f_hi(qw.w);
  }

  int start = offsets[n], end = offsets[n + 1];
  float den = 0.f;
  float a0 = 0.f, a1 = 0.f, a2 = 0.f, a3 = 0.f, a4 = 0.f, a5 = 0.f, a6 = 0.f, a7 = 0.f;
  int p = start;

  for (; p + 8 <= end; p += 8) {
    int s0 = csr_src[p + qt];
    int s1 = csr_src[p + 4 + qt];
    uint4 v0 = *(const uint4*)(Zkm + ((size_t)s0 << 8) + lb);
    uint4 v1 = *(const uint4*)(Zkm + ((size_t)s1 << 8) + lb);
    float2 sc0 = scales[s0];
    float2 sc1 = scales[s1];

    float w0, w1;
    if constexpr (QDOT) {
      int p0 = dot4i8(v0.x, q8.x, 0); p0 = dot4i8(v0.y, q8.y, p0);
      int p1 = dot4i8(v1.x, q8.x, 0); p1 = dot4i8(v1.y, q8.y, p1);
      p0 += __shfl_xor(p0, 1); p1 += __shfl_xor(p1, 1);
      p0 += __shfl_xor(p0, 2); p1 += __shfl_xor(p1, 2);
      w0 = __expf(tq * sc0.x * (float)p0);
      w1 = __expf(tq * sc1.x * (float)p1);
    } else {
      float pd0 = i8f(v0.x, 0) * q0;
      pd0 = fmaf(i8f(v0.x, 1), q1, pd0); pd0 = fmaf(i8f(v0.x, 2), q2, pd0);
      pd0 = fmaf(i8f(v0.x, 3), q3, pd0); pd0 = fmaf(i8f(v0.y, 0), q4, pd0);
      pd0 = fmaf(i8f(v0.y, 1), q5, pd0); pd0 = fmaf(i8f(v0.y, 2), q6, pd0);
      pd0 = fmaf(i8f(v0.y, 3), q7, pd0);
      float pd1 = i8f(v1.x, 0) * q0;
      pd1 = fmaf(i8f(v1.x, 1), q1, pd1); pd1 = fmaf(i8f(v1.x, 2), q2, pd1);
      pd1 = fmaf(i8f(v1.x, 3), q3, pd1); pd1 = fmaf(i8f(v1.y, 0), q4, pd1);
      pd1 = fmaf(i8f(v1.y, 1), q5, pd1); pd1 = fmaf(i8f(v1.y, 2), q6, pd1);
      pd1 = fmaf(i8f(v1.y, 3), q7, pd1);
      pd0 += __shfl_xor(pd0, 1); pd1 += __shfl_xor(pd1, 1);
      pd0 += __shfl_xor(pd0, 2); pd1 += __shfl_xor(pd1, 2);
      w0 = __expf(TAU * sc0.x * pd0);
      w1 = __expf(TAU * sc1.x * pd1);
    }
    den += w0 + w1;
    float wm0 = w0 * sc0.y, wm1 = w1 * sc1.y;

    a0 = fmaf(i8f(v0.z, 0), wm0, a0); a1 = fmaf(i8f(v0.z, 1), wm0, a1);
    a2 = fmaf(i8f(v0.z, 2), wm0, a2); a3 = fmaf(i8f(v0.z, 3), wm0, a3);
    a4 = fmaf(i8f(v0.w, 0), wm0, a4); a5 = fmaf(i8f(v0.w, 1), wm0, a5);
    a6 = fmaf(i8f(v0.w, 2), wm0, a6); a7 = fmaf(i8f(v0.w, 3), wm0, a7);
    a0 = fmaf(i8f(v1.z, 0), wm1, a0); a1 = fmaf(i8f(v1.z, 1), wm1, a1);
    a2 = fmaf(i8f(v1.z, 2), wm1, a2); a3 = fmaf(i8f(v1.z, 3), wm1, a3);
    a4 = fmaf(i8f(v1.w, 0), wm1, a4); a5 = fmaf(i8f(v1.w, 1), wm1, a5);
    a6 = fmaf(i8f(v1.w, 2), wm1, a6); a7 = fmaf(i8f(v1.w, 3), wm1, a7);
  }

  for (; p < end; p += 4) {               // masked tail, whole wave stays
    int e = p + qt;
    int idx = (e < end) ? e : (end - 1);
    int s0 = csr_src[idx];
    uint4 v = *(const uint4*)(Zkm + ((size_t)s0 << 8) + lb);
    float2 sc = scales[s0];
    float w;
    if constexpr (QDOT) {
      int p0 = dot4i8(v.x, q8.x, 0); p0 = dot4i8(v.y, q8.y, p0);
      p0 += __shfl_xor(p0, 1);
      p0 += __shfl_xor(p0, 2);
      w = (e < end) ? __expf(tq * sc.x * (float)p0) : 0.f;
    } else {
      float pd = i8f(v.x, 0) * q0;
      pd = fmaf(i8f(v.x, 1), q1, pd); pd = fmaf(i8f(v.x, 2), q2, pd);
      pd = fmaf(i8f(v.x, 3), q3, pd); pd = fmaf(i8f(v.y, 0), q4, pd);
      pd = fmaf(i8f(v.y, 1), q5, pd); pd = fmaf(i8f(v.y, 2), q6, pd);
      pd = fmaf(i8f(v.y, 3), q7, pd);
      pd += __shfl_xor(pd, 1);
      pd += __shfl_xor(pd, 2);
      w = (e < end) ? __expf(TAU * sc.x * pd) : 0.f;
    }
    den += w;
    float wm = w * sc.y;
    a0 = fmaf(i8f(v.z, 0), wm, a0); a1 = fmaf(i8f(v.z, 1), wm, a1);
    a2 = fmaf(i8f(v.z, 2), wm, a2); a3 = fmaf(i8f(v.z, 3), wm, a3);
    a4 = fmaf(i8f(v.w, 0), wm, a4); a5 = fmaf(i8f(v.w, 1), wm, a5);
    a6 = fmaf(i8f(v.w, 2), wm, a6); a7 = fmaf(i8f(v.w, 3), wm, a7);
  }

  // combine the four quarters (same l -> same dims/head)
  den += __shfl_xor(den, 16); den += __shfl_xor(den, 32);
  a0 += __shfl_xor(a0, 16); a0 += __shfl_xor(a0, 32);
  a1 += __shfl_xor(a1, 16); a1 += __shfl_xor(a1, 32);
  a2 += __shfl_xor(a2, 16); a2 += __shfl_xor(a2, 32);
  a3 += __shfl_xor(a3, 16); a3 += __shfl_xor(a3, 32);
  a4 += __shfl_xor(a4, 16); a4 += __shfl_xor(a4, 32);
  a5 += __shfl_xor(a5, 16); a5 += __shfl_xor(a5, 32);
  a6 += __shfl_xor(a6, 16); a6 += __shfl_xor(a6, 32);
  a7 += __shfl_xor(a7, 16); a7 += __shfl_xor(a7, 32);

  float inv = (den > 0.f) ? 1.0f / den : 0.f;
  if (qt == 0) {
    uint4 o;
    o.x = (uint)f2b(a0 * inv) | ((uint)f2b(a1 * inv) << 16);
    o.y = (uint)f2b(a2 * inv) | ((uint)f2b(a3 * inv) << 16);
    o.z = (uint)f2b(a4 * inv) | ((uint)f2b(a5 * inv) << 16);
    o.w = (uint)f2b(a6 * inv) | ((uint)f2b(a7 * inv) << 16);
    *(uint4*)((char*)aggbf + (size_t)n * 256 + lb) = o;
  }
}

// ---------------- launch ----------------
extern "C" void kernel_launch(void* const* d_in, const int* in_sizes, int n_in,
                              void* d_out, int out_size, void* d_ws, size_t ws_size,
                              hipStream_t stream) {
  const float* h    = (const float*)d_in[0];
  const int*   src  = (const int*)d_in[1];
  const int*   dst  = (const int*)d_in[2];
  const float* Wq   = (const float*)d_in[3];
  const float* bq   = (const float*)d_in[4];
  const float* Wk   = (const float*)d_in[5];
  const float* bk   = (const float*)d_in[6];
  const float* Wm   = (const float*)d_in[7];
  const float* bm   = (const float*)d_in[8];
  const float* Wout = (const float*)d_in[9];
  const float* bout = (const float*)d_in[10];
  float* out = (float*)d_out;

  char* base = (char*)d_ws;
  ushort* Abf    = (ushort*)base;                         // NN*128 bf16 (reused as Zkm)
  char*   Zkm    = base;                                  // NN*256B int8, overlaps Abf
  ushort* Zbf    = (ushort*)(base + 25600000);            // NN*384 bf16
  ushort* aggbf  = (ushort*)(base + 102400000);           // NN*128 bf16
  int2*   stage  = (int2*)(base + 102400000);             // 8*REGION int2, dead before aggbf
  float2* scales = (float2*)(base + 128000000);           // NN float2
  ushort* BTproj = (ushort*)(base + 128800000);           // 98304 B
  ushort* BTout  = (ushort*)(base + 128898304);           // 32768 B
  float*  bvec   = (float*)(base + 128931072);            // 2048 B pad
  int* counts    = (int*)(base + 128933120);              // 400000 B
  int* stageCur  = (int*)(base + 129333120);              // 8 ctrs, 64B stride (1024 B)
  int* offsets   = (int*)(base + 129334144);              // (NN+1)*4 -> pad 400128
  int* cursor    = (int*)(base + 129734272);              // 400000 B
  int* blockSums = (int*)(base + 130134272);              // 512 B
  int* csr_src   = (int*)(base + 130134784);              // NE*4 -> ends 136534784
  char* Zq8      = base + 136534784;                      // NN*128 int8 (12.8 MB)
  float* sqv     = (float*)(base + 149334784);            // NN f32 -> ends 149734784

  int useQ8 = (ws_size >= (size_t)149734784) ? 1 : 0;

  hipMemsetAsync(counts, 0, 401024, stream);

  setup_stage<<<7288, 256, 0, stream>>>(h, Abf, Wq, Wk, Wm, bq, bk, bm, Wout,
                                        BTproj, BTout, bvec, src, dst, stageCur, stage);
  hist_part<<<256, 256, 0, stream>>>(stage, stageCur, counts);
  scan_a<<<98, 256, 0, stream>>>(counts, offsets, blockSums, NN);
  scan_b<<<1, 128, 0, stream>>>(blockSums, 98);
  scan_c<<<391, 256, 0, stream>>>(offsets, blockSums, cursor, NN);

  mfma_gemm<0, 1><<<dim3(1563, 3), 256, 0, stream>>>(Abf, BTproj, bvec, Zbf, NN, 384);

  quant_kernel<<<6250, 256, 0, stream>>>(Zbf, Zkm, scales, Zq8, sqv, useQ8);
  scatter_final<<<1040, 256, 0, stream>>>(stage, stageCur, cursor, csr_src);

  if (useQ8)
    aggregate_q<1><<<25000, 256, 0, stream>>>(Zkm, Zbf, scales, offsets, csr_src,
                                              aggbf, Zq8, sqv);
  else
    aggregate_q<0><<<25000, 256, 0, stream>>>(Zkm, Zbf, scales, offsets, csr_src,
                                              aggbf, Zq8, sqv);

  mfma_gemm<1, 0><<<dim3(1563, 1), 256, 0, stream>>>(aggbf, BTout, bout, out, NN, 128);
}

// Round 15
// 320.498 us; speedup vs baseline: 1.1459x; 1.0604x over previous
//
#include <hip/hip_runtime.h>
#include <hip/hip_bf16.h>
#include <cstdint>
#include <cstddef>

#define NN 100000
#define NE 1600000
#define TAU 0.3f
#define REGION 400000   // stage-1 slots per dst-partition (8 partitions)
#define REGION2 5120    // stage-2 slots per (partition,sub-bucket); mean 4096, +16 sigma

typedef __attribute__((ext_vector_type(8))) short bf16x8;
typedef __attribute__((ext_vector_type(4))) float f32x4;

#if __has_builtin(__builtin_amdgcn_sdot4)
#define HAVE_SDOT4 1
#else
#define HAVE_SDOT4 0
#endif

static __device__ __forceinline__ float b2f_hi(uint w) {
  return __uint_as_float(w & 0xffff0000u);
}
static __device__ __forceinline__ float b2f_lo(uint w) {
  return __uint_as_float(w << 16);
}
static __device__ __forceinline__ ushort f2b(float f) {
  uint x = __float_as_uint(f);
  return (ushort)((x + 0x7fffu + ((x >> 16) & 1u)) >> 16);
}
// sign-extended byte k of word w -> float
static __device__ __forceinline__ float i8f(uint w, int k) {
  return (float)((int)(w << (24 - 8 * k)) >> 24);
}
static __device__ __forceinline__ int dot4i8(uint a, uint b, int c) {
#if HAVE_SDOT4
  return __builtin_amdgcn_sdot4((int)a, (int)b, c, false);
#else
  return c + (int)(char)(a) * (int)(char)(b)
           + (int)(char)(a >> 8) * (int)(char)(b >> 8)
           + (int)(char)(a >> 16) * (int)(char)(b >> 16)
           + (int)(char)(a >> 24) * (int)(char)(b >> 24);
#endif
}

// ------- K1: conv_h (blocks 0..6249) + prep (6250..6505) + stage (6506..7287) -------
__global__ __launch_bounds__(256) void setup_stage(
    const float* __restrict__ h, ushort* __restrict__ A,
    const float* __restrict__ Wq, const float* __restrict__ Wk, const float* __restrict__ Wm,
    const float* __restrict__ bq, const float* __restrict__ bk, const float* __restrict__ bm,
    const float* __restrict__ Wout,
    ushort* __restrict__ BTproj, ushort* __restrict__ BTout, float* __restrict__ bvec,
    const int* __restrict__ src, const int* __restrict__ dst,
    int* __restrict__ stageCur, int2* __restrict__ stage) {
  int b = blockIdx.x;
  int t = threadIdx.x;
  if (b < 6250) {                       // h f32 -> bf16
    int i = b * 256 + t;
    const float4* hv = (const float4*)h + (size_t)i * 2;
    float4 a = hv[0], c = hv[1];
    uint4 o;
    o.x = (uint)f2b(a.x) | ((uint)f2b(a.y) << 16);
    o.y = (uint)f2b(a.z) | ((uint)f2b(a.w) << 16);
    o.z = (uint)f2b(c.x) | ((uint)f2b(c.y) << 16);
    o.w = (uint)f2b(c.z) | ((uint)f2b(c.w) << 16);
    ((uint4*)A)[i] = o;
    return;
  }
  if (b < 6506) {                       // weight prep, 65536 threads
    int id = (b - 6250) * 256 + t;
    if (id < 384 * 128) {
      int j = id >> 7, k = id & 127;
      int w = j >> 7, r = j & 127, hh = r >> 5, d = r & 31;
      const float* W = (w == 0) ? Wq : (w == 1) ? Wk : Wm;
      BTproj[id] = f2b(W[hh * 4096 + k * 32 + d]);
      if (k == 0) {
        const float* bb = (w == 0) ? bq : (w == 1) ? bk : bm;
        bvec[j] = bb[hh * 32 + d];
      }
    } else {
      int id2 = id - 384 * 128;                // 16384
      int c = id2 >> 7, k = id2 & 127;
      BTout[id2] = f2b(Wout[k * 128 + c]);
    }
    return;
  }
  // stage branch: 782 blocks x 2048 edges, bin by dst>>14 into fixed regions
  __shared__ int cnt[8];
  __shared__ int gbase[8];
  if (t < 8) cnt[t] = 0;
  __syncthreads();
  int e0 = (b - 6506) * 2048 + t;
  int d[8], s[8];
#pragma unroll
  for (int i = 0; i < 8; i++) {
    int e = e0 + i * 256;
    if (e < NE) {
      d[i] = dst[e];
      s[i] = src[e];
      atomicAdd(&cnt[d[i] >> 14], 1);
    } else {
      d[i] = -1;
    }
  }
  __syncthreads();
  if (t < 8) gbase[t] = atomicAdd(&stageCur[t * 16], cnt[t]);
  __syncthreads();
  if (t < 8) cnt[t] = 0;
  __syncthreads();
#pragma unroll
  for (int i = 0; i < 8; i++) {
    if (d[i] >= 0) {
      int p = d[i] >> 14;
      int slot = p * REGION + gbase[p] + atomicAdd(&cnt[p], 1);
      stage[slot] = make_int2(s[i], d[i]);
    }
  }
}

// ------- stage2: split each partition into 64 sub-buckets of 256 dsts -------
// packed u32 = (src << 14) | (dst & 16383); dense block-contiguous writes.
__global__ __launch_bounds__(256) void stage2_kernel(
    const int2* __restrict__ stage, const int* __restrict__ stageCur,
    int* __restrict__ subCur, uint* __restrict__ stage2) {
  int p = blockIdx.x & 7;
  int kb = blockIdx.x >> 3;              // 0..63 block within partition
  int t = threadIdx.x;
  int n = stageCur[p * 16];
  const int2* reg = stage + (size_t)p * REGION;
  __shared__ int cnt[64];
  __shared__ int gbase[64];
  for (int base = kb * 2048; base < n; base += 64 * 2048) {
    if (t < 64) cnt[t] = 0;
    __syncthreads();
    uint v[8]; int sb[8];
#pragma unroll
    for (int i = 0; i < 8; i++) {
      int idx = base + t + i * 256;
      if (idx < n) {
        int2 e = reg[idx];
        int dlow = e.y & 16383;
        sb[i] = dlow >> 8;               // sub-bucket 0..63
        v[i] = ((uint)e.x << 14) | (uint)dlow;
        atomicAdd(&cnt[sb[i]], 1);
      } else sb[i] = -1;
    }
    __syncthreads();
    if (t < 64) gbase[t] = cnt[t] ? atomicAdd(&subCur[(p * 64 + t) * 16], cnt[t]) : 0;
    __syncthreads();
    if (t < 64) cnt[t] = 0;
    __syncthreads();
#pragma unroll
    for (int i = 0; i < 8; i++) {
      if (sb[i] >= 0) {
        int slot = gbase[sb[i]] + atomicAdd(&cnt[sb[i]], 1);
        stage2[((size_t)(p * 64 + sb[i])) * REGION2 + slot] = v[i];
      }
    }
    __syncthreads();
  }
}

// ------- K2: partition-local histogram from stage-1 (p = blockIdx&7) -------
__global__ __launch_bounds__(256) void hist_part(
    const int2* __restrict__ stage, const int* __restrict__ stageCur,
    int* __restrict__ counts) {
  int p = blockIdx.x & 7;
  int k = blockIdx.x >> 3;              // 0..31
  int n = stageCur[p * 16];
  const int2* reg = stage + (size_t)p * REGION;
  for (int i = k * 256 + threadIdx.x; i < n; i += 32 * 256)
    atomicAdd(&counts[reg[i].y], 1);
}

// ---------------- MFMA GEMM: 64x128 tile, 48 KB LDS, 3 blocks/CU ----------------
template <int RELU, int OUTBF>
__global__ __launch_bounds__(256) void mfma_gemm(
    const ushort* __restrict__ A, const ushort* __restrict__ BT,
    const float* __restrict__ bias, void* __restrict__ Cp, int M, int ncols) {
  __shared__ ushort As[64 * 128];    // 16 KB
  __shared__ ushort Bs[128 * 128];   // 32 KB

  int t = threadIdx.x;
  int rowBase = blockIdx.x * 64, colBase = blockIdx.y * 128;

#pragma unroll
  for (int i = 0; i < 4; i++) {      // A: 1024 chunks of 16B
    int flat = t + i * 256;
    int row = flat >> 4;
    int kb = (flat & 15) * 16;
    int soff = kb ^ ((row & 7) << 4);
    int ar = rowBase + row; if (ar >= M) ar = M - 1;
    __builtin_amdgcn_global_load_lds(
        (const __attribute__((address_space(1))) uint32_t*)((const char*)A + (size_t)ar * 256 + soff),
        (__attribute__((address_space(3))) uint32_t*)((char*)As + row * 256 + kb), 16, 0, 0);
  }
#pragma unroll
  for (int i = 0; i < 8; i++) {      // B: 2048 chunks of 16B
    int flat = t + i * 256;
    int row = flat >> 4;
    int kb = (flat & 15) * 16;
    int soff = kb ^ ((row & 7) << 4);
    __builtin_amdgcn_global_load_lds(
        (const __attribute__((address_space(1))) uint32_t*)((const char*)BT + (size_t)(colBase + row) * 256 + soff),
        (__attribute__((address_space(3))) uint32_t*)((char*)Bs + row * 256 + kb), 16, 0, 0);
  }
  __syncthreads();

  int wv = t >> 6, L = t & 63;
  int wrow = (wv >> 1) * 32, wcol = (wv & 1) * 64;
  int lr = L & 15;
  int lk = (L >> 4) * 16;
  f32x4 acc[2][4] = {};

#pragma unroll
  for (int ks = 0; ks < 4; ks++) {
    bf16x8 a[2], b[4];
#pragma unroll
    for (int i = 0; i < 2; i++) {
      int row = wrow + i * 16 + lr;
      a[i] = *(const bf16x8*)((const char*)As + row * 256 + ((ks * 64 + lk) ^ ((row & 7) << 4)));
    }
#pragma unroll
    for (int j = 0; j < 4; j++) {
      int col = wcol + j * 16 + lr;
      b[j] = *(const bf16x8*)((const char*)Bs + col * 256 + ((ks * 64 + lk) ^ ((col & 7) << 4)));
    }
#pragma unroll
    for (int i = 0; i < 2; i++)
#pragma unroll
      for (int j = 0; j < 4; j++)
        acc[i][j] = __builtin_amdgcn_mfma_f32_16x16x32_bf16(a[i], b[j], acc[i][j], 0, 0, 0);
  }

  int rquad = (L >> 4) * 4;
#pragma unroll
  for (int j = 0; j < 4; j++) {
    int col = colBase + wcol + j * 16 + lr;
    float bs = bias[col];
#pragma unroll
    for (int i = 0; i < 2; i++) {
      int row0 = rowBase + wrow + i * 16 + rquad;
#pragma unroll
      for (int r = 0; r < 4; r++) {
        int row = row0 + r;
        if (row >= M) continue;
        float v = acc[i][j][r] + bs;
        if (RELU) v = fmaxf(v, 0.f);
        if (OUTBF) ((ushort*)Cp)[(size_t)row * ncols + col] = f2b(v);
        else       ((float*)Cp)[(size_t)row * ncols + col] = v;
      }
    }
  }
}

// ---------------- CSR scans ----------------
__global__ __launch_bounds__(256) void scan_a(const int* __restrict__ counts,
                                              int* __restrict__ offsets,
                                              int* __restrict__ blockSums, int n) {
  __shared__ int lds[256];
  int b = blockIdx.x, t = threadIdx.x;
  int base = b * 1024 + t * 4;
  int4 v = make_int4(0, 0, 0, 0);
  if (base < n) v = *(const int4*)&counts[base];
  int s1 = v.x + v.y, s2 = s1 + v.z, s3 = s2 + v.w;
  lds[t] = s3;
  __syncthreads();
  for (int dd = 1; dd < 256; dd <<= 1) {
    int x = (t >= dd) ? lds[t - dd] : 0;
    __syncthreads();
    lds[t] += x;
    __syncthreads();
  }
  int excl = (t > 0) ? lds[t - 1] : 0;
  if (base < n) {
    int4 o = make_int4(excl, excl + v.x, excl + s1, excl + s2);
    *(int4*)&offsets[base] = o;
  }
  if (t == 255) blockSums[b] = lds[255];
}

__global__ __launch_bounds__(128) void scan_b(int* __restrict__ blockSums, int nb) {
  __shared__ int lds[128];
  int t = threadIdx.x;
  lds[t] = (t < nb) ? blockSums[t] : 0;
  __syncthreads();
  for (int dd = 1; dd < 128; dd <<= 1) {
    int x = (t >= dd) ? lds[t - dd] : 0;
    __syncthreads();
    lds[t] += x;
    __syncthreads();
  }
  if (t < nb) blockSums[t] = (t > 0) ? lds[t - 1] : 0;
}

__global__ __launch_bounds__(256) void scan_c(int* __restrict__ offsets,
                                              const int* __restrict__ blockSums,
                                              int* __restrict__ cursor, int n) {
  int i = blockIdx.x * 256 + threadIdx.x;
  if (i < n) {
    int v = offsets[i] + blockSums[i >> 10];
    offsets[i] = v;
    cursor[i] = v;
  }
  if (i == 0) offsets[n] = NE;
}

// ------- quant: Zbf (zk|zm,zq) -> int8 + per-row scales -------
__global__ __launch_bounds__(256) void quant_kernel(
    const ushort* __restrict__ Zbf, char* __restrict__ Zkm, float2* __restrict__ scales,
    char* __restrict__ Zq8, float* __restrict__ sqv, int doQ8) {
  int g = blockIdx.x * 256 + threadIdx.x;   // 1.6M threads = 100K rows x 16 units
  int row = g >> 4, u = g & 15;
  const ushort* zr = Zbf + (size_t)row * 384;
  uint4 kk = *(const uint4*)(zr + 128 + u * 8);
  uint4 mm = *(const uint4*)(zr + 256 + u * 8);
  uint4 qq = *(const uint4*)(zr + u * 8);
  float kf[8] = {b2f_lo(kk.x), b2f_hi(kk.x), b2f_lo(kk.y), b2f_hi(kk.y),
                 b2f_lo(kk.z), b2f_hi(kk.z), b2f_lo(kk.w), b2f_hi(kk.w)};
  float mf[8] = {b2f_lo(mm.x), b2f_hi(mm.x), b2f_lo(mm.y), b2f_hi(mm.y),
                 b2f_lo(mm.z), b2f_hi(mm.z), b2f_lo(mm.w), b2f_hi(mm.w)};
  float qf[8] = {b2f_lo(qq.x), b2f_hi(qq.x), b2f_lo(qq.y), b2f_hi(qq.y),
                 b2f_lo(qq.z), b2f_hi(qq.z), b2f_lo(qq.w), b2f_hi(qq.w)};
  float mk = 0.f, mx = 0.f, mqv = 0.f;
#pragma unroll
  for (int i = 0; i < 8; i++) {
    mk = fmaxf(mk, fabsf(kf[i]));
    mx = fmaxf(mx, fabsf(mf[i]));
    mqv = fmaxf(mqv, fabsf(qf[i]));
  }
#pragma unroll
  for (int dd = 1; dd < 16; dd <<= 1) {
    mk = fmaxf(mk, __shfl_xor(mk, dd));
    mx = fmaxf(mx, __shfl_xor(mx, dd));
    mqv = fmaxf(mqv, __shfl_xor(mqv, dd));
  }
  mk = fmaxf(mk, 1e-20f); mx = fmaxf(mx, 1e-20f); mqv = fmaxf(mqv, 1e-20f);
  float qk = 127.0f / mk, qm = 127.0f / mx;
  int q[16];
#pragma unroll
  for (int i = 0; i < 8; i++) {
    q[i] = __float2int_rn(kf[i] * qk) & 0xff;
    q[8 + i] = __float2int_rn(mf[i] * qm) & 0xff;
  }
  uint4 o;
  o.x = (uint)(q[0] | (q[1] << 8) | (q[2] << 16) | (q[3] << 24));
  o.y = (uint)(q[4] | (q[5] << 8) | (q[6] << 16) | (q[7] << 24));
  o.z = (uint)(q[8] | (q[9] << 8) | (q[10] << 16) | (q[11] << 24));
  o.w = (uint)(q[12] | (q[13] << 8) | (q[14] << 16) | (q[15] << 24));
  *(uint4*)(Zkm + (size_t)row * 256 + u * 16) = o;
  if (u == 0) scales[row] = make_float2(mk * (1.0f / 127.0f), mx * (1.0f / 127.0f));
  if (doQ8) {
    float qs = 127.0f / mqv;
    int r[8];
#pragma unroll
    for (int i = 0; i < 8; i++) r[i] = __float2int_rn(qf[i] * qs) & 0xff;
    uint2 oq;
    oq.x = (uint)(r[0] | (r[1] << 8) | (r[2] << 16) | (r[3] << 24));
    oq.y = (uint)(r[4] | (r[5] << 8) | (r[6] << 16) | (r[7] << 24));
    *(uint2*)(Zq8 + (size_t)row * 128 + u * 8) = oq;
    if (u == 0) sqv[row] = mqv * (1.0f / 127.0f);
  }
}

// ------- scatter (fallback): per-partition from stage-1 into CSR -------
__global__ __launch_bounds__(256) void scatter_final(
    const int2* __restrict__ stage, const int* __restrict__ stageCur,
    int* __restrict__ cursor, int* __restrict__ csr_src) {
  int p = blockIdx.x & 7;
  int k = blockIdx.x >> 3;              // 0..129
  int n = stageCur[p * 16];
  const int2* reg = stage + (size_t)p * REGION;
  for (int i = k * 256 + threadIdx.x; i < n; i += 130 * 256) {
    int2 e = reg[i];
    int pos = atomicAdd(&cursor[e.y], 1);
    csr_src[pos] = e.x;
  }
}

// ------- scatter2: per sub-bucket (16KB CSR window) from stage2 -------
__global__ __launch_bounds__(256) void scatter_final2(
    const uint* __restrict__ stage2, const int* __restrict__ subCur,
    int* __restrict__ cursor, int* __restrict__ csr_src) {
  int p = blockIdx.x & 7;
  int sb = (blockIdx.x >> 3) & 63;
  int half = blockIdx.x >> 9;            // 0..1
  int g = p * 64 + sb;
  int n = subCur[g * 16];
  const uint* reg = stage2 + (size_t)g * REGION2;
  int dbase = p * 16384;
  for (int i = half * 256 + threadIdx.x; i < n; i += 512) {
    uint v = reg[i];
    int d = dbase + (int)(v & 16383u);
    int pos = atomicAdd(&cursor[d], 1);
    csr_src[pos] = (int)(v >> 14);
  }
}

// ---------------- fused attention + aggregation, int8 gathers ----------------
template <int QDOT>
__global__ __launch_bounds__(256) void aggregate_q(
    const char* __restrict__ Zkm, const ushort* __restrict__ Zbf,
    const float2* __restrict__ scales,
    const int* __restrict__ offsets, const int* __restrict__ csr_src,
    ushort* __restrict__ aggbf,
    const char* __restrict__ Zq8, const float* __restrict__ sqv) {
  int wv = threadIdx.x >> 6, L = threadIdx.x & 63;
  int n = blockIdx.x * 4 + wv;
  if (n >= NN) return;
  int qt = L >> 4, l = L & 15;
  int lb = l << 4;                         // byte offset within 256B row

  float q0, q1, q2, q3, q4, q5, q6, q7;
  uint2 q8;
  float tq;
  if constexpr (QDOT) {
    q8 = *(const uint2*)(Zq8 + (size_t)n * 128 + l * 8);
    tq = TAU * sqv[n];
  } else {
    uint4 qw = *(const uint4*)((const char*)Zbf + (size_t)n * 768 + lb);
    q0 = b2f_lo(qw.x); q1 = b2f_hi(qw.x); q2 = b2f_lo(qw.y); q3 = b2f_hi(qw.y);
    q4 = b2f_lo(qw.z); q5 = b2f_hi(qw.z); q6 = b2f_lo(qw.w); q7 = b2f_hi(qw.w);
  }

  int start = offsets[n], end = offsets[n + 1];
  float den = 0.f;
  float a0 = 0.f, a1 = 0.f, a2 = 0.f, a3 = 0.f, a4 = 0.f, a5 = 0.f, a6 = 0.f, a7 = 0.f;
  int p = start;

  for (; p + 8 <= end; p += 8) {
    int s0 = csr_src[p + qt];
    int s1 = csr_src[p + 4 + qt];
    uint4 v0 = *(const uint4*)(Zkm + ((size_t)s0 << 8) + lb);
    uint4 v1 = *(const uint4*)(Zkm + ((size_t)s1 << 8) + lb);
    float2 sc0 = scales[s0];
    float2 sc1 = scales[s1];

    float w0, w1;
    if constexpr (QDOT) {
      int p0 = dot4i8(v0.x, q8.x, 0); p0 = dot4i8(v0.y, q8.y, p0);
      int p1 = dot4i8(v1.x, q8.x, 0); p1 = dot4i8(v1.y, q8.y, p1);
      p0 += __shfl_xor(p0, 1); p1 += __shfl_xor(p1, 1);
      p0 += __shfl_xor(p0, 2); p1 += __shfl_xor(p1, 2);
      w0 = __expf(tq * sc0.x * (float)p0);
      w1 = __expf(tq * sc1.x * (float)p1);
    } else {
      float pd0 = i8f(v0.x, 0) * q0;
      pd0 = fmaf(i8f(v0.x, 1), q1, pd0); pd0 = fmaf(i8f(v0.x, 2), q2, pd0);
      pd0 = fmaf(i8f(v0.x, 3), q3, pd0); pd0 = fmaf(i8f(v0.y, 0), q4, pd0);
      pd0 = fmaf(i8f(v0.y, 1), q5, pd0); pd0 = fmaf(i8f(v0.y, 2), q6, pd0);
      pd0 = fmaf(i8f(v0.y, 3), q7, pd0);
      float pd1 = i8f(v1.x, 0) * q0;
      pd1 = fmaf(i8f(v1.x, 1), q1, pd1); pd1 = fmaf(i8f(v1.x, 2), q2, pd1);
      pd1 = fmaf(i8f(v1.x, 3), q3, pd1); pd1 = fmaf(i8f(v1.y, 0), q4, pd1);
      pd1 = fmaf(i8f(v1.y, 1), q5, pd1); pd1 = fmaf(i8f(v1.y, 2), q6, pd1);
      pd1 = fmaf(i8f(v1.y, 3), q7, pd1);
      pd0 += __shfl_xor(pd0, 1); pd1 += __shfl_xor(pd1, 1);
      pd0 += __shfl_xor(pd0, 2); pd1 += __shfl_xor(pd1, 2);
      w0 = __expf(TAU * sc0.x * pd0);
      w1 = __expf(TAU * sc1.x * pd1);
    }
    den += w0 + w1;
    float wm0 = w0 * sc0.y, wm1 = w1 * sc1.y;

    a0 = fmaf(i8f(v0.z, 0), wm0, a0); a1 = fmaf(i8f(v0.z, 1), wm0, a1);
    a2 = fmaf(i8f(v0.z, 2), wm0, a2); a3 = fmaf(i8f(v0.z, 3), wm0, a3);
    a4 = fmaf(i8f(v0.w, 0), wm0, a4); a5 = fmaf(i8f(v0.w, 1), wm0, a5);
    a6 = fmaf(i8f(v0.w, 2), wm0, a6); a7 = fmaf(i8f(v0.w, 3), wm0, a7);
    a0 = fmaf(i8f(v1.z, 0), wm1, a0); a1 = fmaf(i8f(v1.z, 1), wm1, a1);
    a2 = fmaf(i8f(v1.z, 2), wm1, a2); a3 = fmaf(i8f(v1.z, 3), wm1, a3);
    a4 = fmaf(i8f(v1.w, 0), wm1, a4); a5 = fmaf(i8f(v1.w, 1), wm1, a5);
    a6 = fmaf(i8f(v1.w, 2), wm1, a6); a7 = fmaf(i8f(v1.w, 3), wm1, a7);
  }

  for (; p < end; p += 4) {               // masked tail, whole wave stays
    int e = p + qt;
    int idx = (e < end) ? e : (end - 1);
    int s0 = csr_src[idx];
    uint4 v = *(const uint4*)(Zkm + ((size_t)s0 << 8) + lb);
    float2 sc = scales[s0];
    float w;
    if constexpr (QDOT) {
      int p0 = dot4i8(v.x, q8.x, 0); p0 = dot4i8(v.y, q8.y, p0);
      p0 += __shfl_xor(p0, 1);
      p0 += __shfl_xor(p0, 2);
      w = (e < end) ? __expf(tq * sc.x * (float)p0) : 0.f;
    } else {
      float pd = i8f(v.x, 0) * q0;
      pd = fmaf(i8f(v.x, 1), q1, pd); pd = fmaf(i8f(v.x, 2), q2, pd);
      pd = fmaf(i8f(v.x, 3), q3, pd); pd = fmaf(i8f(v.y, 0), q4, pd);
      pd = fmaf(i8f(v.y, 1), q5, pd); pd = fmaf(i8f(v.y, 2), q6, pd);
      pd = fmaf(i8f(v.y, 3), q7, pd);
      pd += __shfl_xor(pd, 1);
      pd += __shfl_xor(pd, 2);
      w = (e < end) ? __expf(TAU * sc.x * pd) : 0.f;
    }
    den += w;
    float wm = w * sc.y;
    a0 = fmaf(i8f(v.z, 0), wm, a0); a1 = fmaf(i8f(v.z, 1), wm, a1);
    a2 = fmaf(i8f(v.z, 2), wm, a2); a3 = fmaf(i8f(v.z, 3), wm, a3);
    a4 = fmaf(i8f(v.w, 0), wm, a4); a5 = fmaf(i8f(v.w, 1), wm, a5);
    a6 = fmaf(i8f(v.w, 2), wm, a6); a7 = fmaf(i8f(v.w, 3), wm, a7);
  }

  // combine the four quarters (same l -> same dims/head)
  den += __shfl_xor(den, 16); den += __shfl_xor(den, 32);
  a0 += __shfl_xor(a0, 16); a0 += __shfl_xor(a0, 32);
  a1 += __shfl_xor(a1, 16); a1 += __shfl_xor(a1, 32);
  a2 += __shfl_xor(a2, 16); a2 += __shfl_xor(a2, 32);
  a3 += __shfl_xor(a3, 16); a3 += __shfl_xor(a3, 32);
  a4 += __shfl_xor(a4, 16); a4 += __shfl_xor(a4, 32);
  a5 += __shfl_xor(a5, 16); a5 += __shfl_xor(a5, 32);
  a6 += __shfl_xor(a6, 16); a6 += __shfl_xor(a6, 32);
  a7 += __shfl_xor(a7, 16); a7 += __shfl_xor(a7, 32);

  float inv = (den > 0.f) ? 1.0f / den : 0.f;
  if (qt == 0) {
    uint4 o;
    o.x = (uint)f2b(a0 * inv) | ((uint)f2b(a1 * inv) << 16);
    o.y = (uint)f2b(a2 * inv) | ((uint)f2b(a3 * inv) << 16);
    o.z = (uint)f2b(a4 * inv) | ((uint)f2b(a5 * inv) << 16);
    o.w = (uint)f2b(a6 * inv) | ((uint)f2b(a7 * inv) << 16);
    *(uint4*)((char*)aggbf + (size_t)n * 256 + lb) = o;
  }
}

// ---------------- launch ----------------
extern "C" void kernel_launch(void* const* d_in, const int* in_sizes, int n_in,
                              void* d_out, int out_size, void* d_ws, size_t ws_size,
                              hipStream_t stream) {
  const float* h    = (const float*)d_in[0];
  const int*   src  = (const int*)d_in[1];
  const int*   dst  = (const int*)d_in[2];
  const float* Wq   = (const float*)d_in[3];
  const float* bq   = (const float*)d_in[4];
  const float* Wk   = (const float*)d_in[5];
  const float* bk   = (const float*)d_in[6];
  const float* Wm   = (const float*)d_in[7];
  const float* bm   = (const float*)d_in[8];
  const float* Wout = (const float*)d_in[9];
  const float* bout = (const float*)d_in[10];
  float* out = (float*)d_out;

  char* base = (char*)d_ws;
  ushort* Abf    = (ushort*)base;                         // NN*128 bf16 (reused as Zkm)
  char*   Zkm    = base;                                  // NN*256B int8, overlaps Abf
  ushort* Zbf    = (ushort*)(base + 25600000);            // NN*384 bf16
  ushort* aggbf  = (ushort*)(base + 102400000);           // NN*128 bf16
  int2*   stage  = (int2*)(base + 102400000);             // 8*REGION int2, dead before aggbf
  float2* scales = (float2*)(base + 128000000);           // NN float2 -> 128800000
  ushort* BTproj = (ushort*)(base + 128800000);           // -> 128898304
  ushort* BTout  = (ushort*)(base + 128898304);           // -> 128931072
  float*  bvec   = (float*)(base + 128931072);            // -> 128933120
  int* counts    = (int*)(base + 128933120);              // 400000 -> 129333120
  int* stageCur  = (int*)(base + 129333120);              // 1024   -> 129334144
  int* subCur    = (int*)(base + 129334144);              // 32768  -> 129366912
  int* offsets   = (int*)(base + 129366912);              // 400128 -> 129767040
  int* cursor    = (int*)(base + 129767040);              // 400000 -> 130167040
  int* blockSums = (int*)(base + 130167040);              // 512    -> 130167552
  int* csr_src   = (int*)(base + 130167552);              // 6400000 -> 136567552
  char* Zq8      = base + 136567552;                      // 12800000 -> 149367552
  float* sqv     = (float*)(base + 149367552);            // 400000 -> 149767552
  uint* stage2   = (uint*)(base + 149767552);             // 512*REGION2*4 = 10485760 -> 160253312

  int useQ8 = (ws_size >= (size_t)149767552) ? 1 : 0;
  int useS2 = (ws_size >= (size_t)160253312) ? 1 : 0;

  hipMemsetAsync(counts, 0, 433792, stream);   // counts + stageCur + subCur

  setup_stage<<<7288, 256, 0, stream>>>(h, Abf, Wq, Wk, Wm, bq, bk, bm, Wout,
                                        BTproj, BTout, bvec, src, dst, stageCur, stage);
  if (useS2)
    stage2_kernel<<<512, 256, 0, stream>>>(stage, stageCur, subCur, stage2);
  hist_part<<<256, 256, 0, stream>>>(stage, stageCur, counts);
  scan_a<<<98, 256, 0, stream>>>(counts, offsets, blockSums, NN);
  scan_b<<<1, 128, 0, stream>>>(blockSums, 98);
  scan_c<<<391, 256, 0, stream>>>(offsets, blockSums, cursor, NN);

  mfma_gemm<0, 1><<<dim3(1563, 3), 256, 0, stream>>>(Abf, BTproj, bvec, Zbf, NN, 384);

  quant_kernel<<<6250, 256, 0, stream>>>(Zbf, Zkm, scales, Zq8, sqv, useQ8);
  if (useS2)
    scatter_final2<<<1024, 256, 0, stream>>>(stage2, subCur, cursor, csr_src);
  else
    scatter_final<<<1040, 256, 0, stream>>>(stage, stageCur, cursor, csr_src);

  if (useQ8)
    aggregate_q<1><<<25000, 256, 0, stream>>>(Zkm, Zbf, scales, offsets, csr_src,
                                              aggbf, Zq8, sqv);
  else
    aggregate_q<0><<<25000, 256, 0, stream>>>(Zkm, Zbf, scales, offsets, csr_src,
                                              aggbf, Zq8, sqv);

  mfma_gemm<1, 0><<<dim3(1563, 1), 256, 0, stream>>>(aggbf, BTout, bout, out, NN, 128);
}

// Round 16
// 280.723 us; speedup vs baseline: 1.3083x; 1.1417x over previous
//
#include <hip/hip_runtime.h>
#include <hip/hip_bf16.h>
#include <cstdint>
#include <cstddef>

#define NN 100000
#define NE 1600000
#define TAU 0.3f
#define REGION 400000   // stage-1 slots per dst-partition (8 partitions)
#define REGION2 5120    // stage-2 slots per (partition,sub-bucket)

typedef __attribute__((ext_vector_type(8))) short bf16x8;
typedef __attribute__((ext_vector_type(4))) float f32x4;

#if __has_builtin(__builtin_amdgcn_sdot4)
#define HAVE_SDOT4 1
#else
#define HAVE_SDOT4 0
#endif

static __device__ __forceinline__ float b2f_hi(uint w) {
  return __uint_as_float(w & 0xffff0000u);
}
static __device__ __forceinline__ float b2f_lo(uint w) {
  return __uint_as_float(w << 16);
}
static __device__ __forceinline__ ushort f2b(float f) {
  uint x = __float_as_uint(f);
  return (ushort)((x + 0x7fffu + ((x >> 16) & 1u)) >> 16);
}
// sign-extended byte k of word w -> float
static __device__ __forceinline__ float i8f(uint w, int k) {
  return (float)((int)(w << (24 - 8 * k)) >> 24);
}
static __device__ __forceinline__ int dot4i8(uint a, uint b, int c) {
#if HAVE_SDOT4
  return __builtin_amdgcn_sdot4((int)a, (int)b, c, false);
#else
  return c + (int)(char)(a) * (int)(char)(b)
           + (int)(char)(a >> 8) * (int)(char)(b >> 8)
           + (int)(char)(a >> 16) * (int)(char)(b >> 16)
           + (int)(char)(a >> 24) * (int)(char)(b >> 24);
#endif
}
#if __has_builtin(__builtin_amdgcn_cvt_f32_ubyte0)
#define UB0(w) __builtin_amdgcn_cvt_f32_ubyte0(w)
#define UB1(w) __builtin_amdgcn_cvt_f32_ubyte1(w)
#define UB2(w) __builtin_amdgcn_cvt_f32_ubyte2(w)
#define UB3(w) __builtin_amdgcn_cvt_f32_ubyte3(w)
#else
#define UB0(w) ((float)((w) & 0xffu))
#define UB1(w) ((float)(((w) >> 8) & 0xffu))
#define UB2(w) ((float)(((w) >> 16) & 0xffu))
#define UB3(w) ((float)(((w) >> 24) & 0xffu))
#endif

// ------- K1: conv_h (blocks 0..6249) + prep (6250..6505) + stage (6506..7287) -------
__global__ __launch_bounds__(256) void setup_stage(
    const float* __restrict__ h, ushort* __restrict__ A,
    const float* __restrict__ Wq, const float* __restrict__ Wk, const float* __restrict__ Wm,
    const float* __restrict__ bq, const float* __restrict__ bk, const float* __restrict__ bm,
    const float* __restrict__ Wout,
    ushort* __restrict__ BTproj, ushort* __restrict__ BTout, float* __restrict__ bvec,
    const int* __restrict__ src, const int* __restrict__ dst,
    int* __restrict__ stageCur, int2* __restrict__ stage) {
  int b = blockIdx.x;
  int t = threadIdx.x;
  if (b < 6250) {                       // h f32 -> bf16
    int i = b * 256 + t;
    const float4* hv = (const float4*)h + (size_t)i * 2;
    float4 a = hv[0], c = hv[1];
    uint4 o;
    o.x = (uint)f2b(a.x) | ((uint)f2b(a.y) << 16);
    o.y = (uint)f2b(a.z) | ((uint)f2b(a.w) << 16);
    o.z = (uint)f2b(c.x) | ((uint)f2b(c.y) << 16);
    o.w = (uint)f2b(c.z) | ((uint)f2b(c.w) << 16);
    ((uint4*)A)[i] = o;
    return;
  }
  if (b < 6506) {                       // weight prep, 65536 threads
    int id = (b - 6250) * 256 + t;
    if (id < 384 * 128) {
      int j = id >> 7, k = id & 127;
      int w = j >> 7, r = j & 127, hh = r >> 5, d = r & 31;
      const float* W = (w == 0) ? Wq : (w == 1) ? Wk : Wm;
      BTproj[id] = f2b(W[hh * 4096 + k * 32 + d]);
      if (k == 0) {
        const float* bb = (w == 0) ? bq : (w == 1) ? bk : bm;
        bvec[j] = bb[hh * 32 + d];
      }
    } else {
      int id2 = id - 384 * 128;                // 16384
      int c = id2 >> 7, k = id2 & 127;
      BTout[id2] = f2b(Wout[k * 128 + c]);
    }
    return;
  }
  // stage branch: 782 blocks x 2048 edges, bin by dst>>14 into fixed regions
  __shared__ int cnt[8];
  __shared__ int gbase[8];
  if (t < 8) cnt[t] = 0;
  __syncthreads();
  int e0 = (b - 6506) * 2048 + t;
  int d[8], s[8];
#pragma unroll
  for (int i = 0; i < 8; i++) {
    int e = e0 + i * 256;
    if (e < NE) {
      d[i] = dst[e];
      s[i] = src[e];
      atomicAdd(&cnt[d[i] >> 14], 1);
    } else {
      d[i] = -1;
    }
  }
  __syncthreads();
  if (t < 8) gbase[t] = atomicAdd(&stageCur[t * 16], cnt[t]);
  __syncthreads();
  if (t < 8) cnt[t] = 0;
  __syncthreads();
#pragma unroll
  for (int i = 0; i < 8; i++) {
    if (d[i] >= 0) {
      int p = d[i] >> 14;
      int slot = p * REGION + gbase[p] + atomicAdd(&cnt[p], 1);
      stage[slot] = make_int2(s[i], d[i]);
    }
  }
}

// ------- stage2 (+fused partition-local histogram): 64 sub-buckets of 256 dsts -------
// packed u32 = (src << 14) | (dst & 16383); dense block-contiguous writes.
template <int DOHIST>
__global__ __launch_bounds__(256) void stage2_kernel(
    const int2* __restrict__ stage, const int* __restrict__ stageCur,
    int* __restrict__ subCur, uint* __restrict__ stage2,
    int* __restrict__ counts) {
  int p = blockIdx.x & 7;
  int kb = blockIdx.x >> 3;              // 0..63 block within partition
  int t = threadIdx.x;
  int n = stageCur[p * 16];
  const int2* reg = stage + (size_t)p * REGION;
  int dbase = p * 16384;
  __shared__ int cnt[64];
  __shared__ int gbase[64];
  for (int base = kb * 2048; base < n; base += 64 * 2048) {
    if (t < 64) cnt[t] = 0;
    __syncthreads();
    uint v[8]; int sb[8];
#pragma unroll
    for (int i = 0; i < 8; i++) {
      int idx = base + t + i * 256;
      if (idx < n) {
        int2 e = reg[idx];
        int dlow = e.y & 16383;
        sb[i] = dlow >> 8;               // sub-bucket 0..63
        v[i] = ((uint)e.x << 14) | (uint)dlow;
        atomicAdd(&cnt[sb[i]], 1);
        if (DOHIST) atomicAdd(&counts[dbase + dlow], 1);   // partition-local
      } else sb[i] = -1;
    }
    __syncthreads();
    if (t < 64) gbase[t] = cnt[t] ? atomicAdd(&subCur[(p * 64 + t) * 16], cnt[t]) : 0;
    __syncthreads();
    if (t < 64) cnt[t] = 0;
    __syncthreads();
#pragma unroll
    for (int i = 0; i < 8; i++) {
      if (sb[i] >= 0) {
        int slot = gbase[sb[i]] + atomicAdd(&cnt[sb[i]], 1);
        stage2[((size_t)(p * 64 + sb[i])) * REGION2 + slot] = v[i];
      }
    }
    __syncthreads();
  }
}

// ------- K2 (fallback): partition-local histogram from stage-1 -------
__global__ __launch_bounds__(256) void hist_part(
    const int2* __restrict__ stage, const int* __restrict__ stageCur,
    int* __restrict__ counts) {
  int p = blockIdx.x & 7;
  int k = blockIdx.x >> 3;              // 0..31
  int n = stageCur[p * 16];
  const int2* reg = stage + (size_t)p * REGION;
  for (int i = k * 256 + threadIdx.x; i < n; i += 32 * 256)
    atomicAdd(&counts[reg[i].y], 1);
}

// ---------------- MFMA GEMM: 64x128 tile, 48 KB LDS, 3 blocks/CU ----------------
// MODE 0: float out + relu. MODE 1: bf16 out. MODE 2: fused int8 quant epilogue
//   (blockIdx.y: 0=zq->Zq8+sqv, 1=zk->Zkm bytes0-7 signed + scales.x,
//    2=zm->Zkm bytes8-15 BIASED(+128) + scales.y)
template <int MODE>
__global__ __launch_bounds__(256) void mfma_gemm(
    const ushort* __restrict__ A, const ushort* __restrict__ BT,
    const float* __restrict__ bias, void* __restrict__ Cp, int M, int ncols,
    char* __restrict__ Zkm, char* __restrict__ Zq8,
    float* __restrict__ scales, float* __restrict__ sqv) {
  __shared__ ushort As[64 * 128];    // 16 KB
  __shared__ ushort Bs[128 * 128];   // 32 KB

  int t = threadIdx.x;
  int rowBase = blockIdx.x * 64, colBase = blockIdx.y * 128;

#pragma unroll
  for (int i = 0; i < 4; i++) {      // A: 1024 chunks of 16B
    int flat = t + i * 256;
    int row = flat >> 4;
    int kb = (flat & 15) * 16;
    int soff = kb ^ ((row & 7) << 4);
    int ar = rowBase + row; if (ar >= M) ar = M - 1;
    __builtin_amdgcn_global_load_lds(
        (const __attribute__((address_space(1))) uint32_t*)((const char*)A + (size_t)ar * 256 + soff),
        (__attribute__((address_space(3))) uint32_t*)((char*)As + row * 256 + kb), 16, 0, 0);
  }
#pragma unroll
  for (int i = 0; i < 8; i++) {      // B: 2048 chunks of 16B
    int flat = t + i * 256;
    int row = flat >> 4;
    int kb = (flat & 15) * 16;
    int soff = kb ^ ((row & 7) << 4);
    __builtin_amdgcn_global_load_lds(
        (const __attribute__((address_space(1))) uint32_t*)((const char*)BT + (size_t)(colBase + row) * 256 + soff),
        (__attribute__((address_space(3))) uint32_t*)((char*)Bs + row * 256 + kb), 16, 0, 0);
  }
  __syncthreads();

  int wv = t >> 6, L = t & 63;
  int wrow = (wv >> 1) * 32, wcol = (wv & 1) * 64;
  int lr = L & 15;
  int lk = (L >> 4) * 16;
  f32x4 acc[2][4] = {};

#pragma unroll
  for (int ks = 0; ks < 4; ks++) {
    bf16x8 a[2], b[4];
#pragma unroll
    for (int i = 0; i < 2; i++) {
      int row = wrow + i * 16 + lr;
      a[i] = *(const bf16x8*)((const char*)As + row * 256 + ((ks * 64 + lk) ^ ((row & 7) << 4)));
    }
#pragma unroll
    for (int j = 0; j < 4; j++) {
      int col = wcol + j * 16 + lr;
      b[j] = *(const bf16x8*)((const char*)Bs + col * 256 + ((ks * 64 + lk) ^ ((col & 7) << 4)));
    }
#pragma unroll
    for (int i = 0; i < 2; i++)
#pragma unroll
      for (int j = 0; j < 4; j++)
        acc[i][j] = __builtin_amdgcn_mfma_f32_16x16x32_bf16(a[i], b[j], acc[i][j], 0, 0, 0);
  }

  int rquad = (L >> 4) * 4;

  if (MODE == 2) {
    // ---- fused quant epilogue: C tile (f32) -> LDS -> per-row int8 ----
    __syncthreads();                     // all MFMA reads of As/Bs done
    float* Cs = (float*)Bs;              // 64*128*4 = 32 KB
#pragma unroll
    for (int j = 0; j < 4; j++) {
      float bs = bias[colBase + wcol + j * 16 + lr];
#pragma unroll
      for (int i = 0; i < 2; i++) {
        int rl = wrow + i * 16 + rquad;
#pragma unroll
        for (int r = 0; r < 4; r++)
          Cs[(rl + r) * 128 + wcol + j * 16 + lr] = acc[i][j][r] + bs;
      }
    }
    __syncthreads();

    int row = t >> 2, part = t & 3;      // 4 threads per row, 32 cols each
    int row_g = rowBase + row;
    const float4* rp = (const float4*)(Cs + row * 128 + part * 32);
    float4 v[8];
    float vmax = 0.f;
#pragma unroll
    for (int i = 0; i < 8; i++) {
      v[i] = rp[i];
      vmax = fmaxf(vmax, fmaxf(fmaxf(fabsf(v[i].x), fabsf(v[i].y)),
                               fmaxf(fabsf(v[i].z), fabsf(v[i].w))));
    }
    vmax = fmaxf(vmax, __shfl_xor(vmax, 1));
    vmax = fmaxf(vmax, __shfl_xor(vmax, 2));
    vmax = fmaxf(vmax, 1e-20f);
    float qs = 127.0f / vmax;
    int w = blockIdx.y;
    if (row_g < M) {
      if (w == 0) {
        uint b8[8];
#pragma unroll
        for (int i = 0; i < 8; i++)
          b8[i] = (uint)(__float2int_rn(v[i].x * qs) & 0xff)
                | ((uint)(__float2int_rn(v[i].y * qs) & 0xff) << 8)
                | ((uint)(__float2int_rn(v[i].z * qs) & 0xff) << 16)
                | ((uint)(__float2int_rn(v[i].w * qs) & 0xff) << 24);
        uint4* dst4 = (uint4*)(Zq8 + (size_t)row_g * 128 + part * 32);
        dst4[0] = make_uint4(b8[0], b8[1], b8[2], b8[3]);
        dst4[1] = make_uint4(b8[4], b8[5], b8[6], b8[7]);
        if (part == 0) sqv[row_g] = vmax * (1.0f / 127.0f);
      } else {
#pragma unroll
        for (int u = 0; u < 2; u++) {
          // two uint2 stores per pair of float4s (unit = part*4 + 2u + {0,1})
#pragma unroll
          for (int h = 0; h < 2; h++) {
            int un = part * 4 + u * 2 + h;
            float4 va = v[u * 4 + h * 2], vb = v[u * 4 + h * 2 + 1];
            uint lo, hi;
            if (w == 1) {
              lo = (uint)(__float2int_rn(va.x * qs) & 0xff)
                 | ((uint)(__float2int_rn(va.y * qs) & 0xff) << 8)
                 | ((uint)(__float2int_rn(va.z * qs) & 0xff) << 16)
                 | ((uint)(__float2int_rn(va.w * qs) & 0xff) << 24);
              hi = (uint)(__float2int_rn(vb.x * qs) & 0xff)
                 | ((uint)(__float2int_rn(vb.y * qs) & 0xff) << 8)
                 | ((uint)(__float2int_rn(vb.z * qs) & 0xff) << 16)
                 | ((uint)(__float2int_rn(vb.w * qs) & 0xff) << 24);
            } else {
              lo = (uint)((__float2int_rn(va.x * qs) + 128) & 0xff)
                 | ((uint)((__float2int_rn(va.y * qs) + 128) & 0xff) << 8)
                 | ((uint)((__float2int_rn(va.z * qs) + 128) & 0xff) << 16)
                 | ((uint)((__float2int_rn(va.w * qs) + 128) & 0xff) << 24);
              hi = (uint)((__float2int_rn(vb.x * qs) + 128) & 0xff)
                 | ((uint)((__float2int_rn(vb.y * qs) + 128) & 0xff) << 8)
                 | ((uint)((__float2int_rn(vb.z * qs) + 128) & 0xff) << 16)
                 | ((uint)((__float2int_rn(vb.w * qs) + 128) & 0xff) << 24);
            }
            uint2* d2 = (uint2*)(Zkm + (size_t)row_g * 256 + un * 16 + (w == 2 ? 8 : 0));
            *d2 = make_uint2(lo, hi);
          }
        }
        if (part == 0) scales[row_g * 2 + (w - 1)] = vmax * (1.0f / 127.0f);
      }
    }
    return;
  }

  // MODE 0/1: plain store
#pragma unroll
  for (int j = 0; j < 4; j++) {
    int col = colBase + wcol + j * 16 + lr;
    float bs = bias[col];
#pragma unroll
    for (int i = 0; i < 2; i++) {
      int row0 = rowBase + wrow + i * 16 + rquad;
#pragma unroll
      for (int r = 0; r < 4; r++) {
        int row = row0 + r;
        if (row >= M) continue;
        float vv = acc[i][j][r] + bs;
        if (MODE == 0) {
          vv = fmaxf(vv, 0.f);
          ((float*)Cp)[(size_t)row * ncols + col] = vv;
        } else {
          ((ushort*)Cp)[(size_t)row * ncols + col] = f2b(vv);
        }
      }
    }
  }
}

// ---------------- CSR scans ----------------
__global__ __launch_bounds__(256) void scan_a(const int* __restrict__ counts,
                                              int* __restrict__ offsets,
                                              int* __restrict__ blockSums, int n) {
  __shared__ int lds[256];
  int b = blockIdx.x, t = threadIdx.x;
  int base = b * 1024 + t * 4;
  int4 v = make_int4(0, 0, 0, 0);
  if (base < n) v = *(const int4*)&counts[base];
  int s1 = v.x + v.y, s2 = s1 + v.z, s3 = s2 + v.w;
  lds[t] = s3;
  __syncthreads();
  for (int dd = 1; dd < 256; dd <<= 1) {
    int x = (t >= dd) ? lds[t - dd] : 0;
    __syncthreads();
    lds[t] += x;
    __syncthreads();
  }
  int excl = (t > 0) ? lds[t - 1] : 0;
  if (base < n) {
    int4 o = make_int4(excl, excl + v.x, excl + s1, excl + s2);
    *(int4*)&offsets[base] = o;
  }
  if (t == 255) blockSums[b] = lds[255];
}

__global__ __launch_bounds__(128) void scan_b(int* __restrict__ blockSums, int nb) {
  __shared__ int lds[128];
  int t = threadIdx.x;
  lds[t] = (t < nb) ? blockSums[t] : 0;
  __syncthreads();
  for (int dd = 1; dd < 128; dd <<= 1) {
    int x = (t >= dd) ? lds[t - dd] : 0;
    __syncthreads();
    lds[t] += x;
    __syncthreads();
  }
  if (t < nb) blockSums[t] = (t > 0) ? lds[t - 1] : 0;
}

__global__ __launch_bounds__(256) void scan_c(int* __restrict__ offsets,
                                              const int* __restrict__ blockSums,
                                              int* __restrict__ cursor, int n) {
  int i = blockIdx.x * 256 + threadIdx.x;
  if (i < n) {
    int v = offsets[i] + blockSums[i >> 10];
    offsets[i] = v;
    cursor[i] = v;
  }
  if (i == 0) offsets[n] = NE;
}

// ------- quant (fallback only): Zbf -> int8 (signed m) -------
__global__ __launch_bounds__(256) void quant_kernel(
    const ushort* __restrict__ Zbf, char* __restrict__ Zkm, float2* __restrict__ scales,
    char* __restrict__ Zq8, float* __restrict__ sqv) {
  int g = blockIdx.x * 256 + threadIdx.x;
  int row = g >> 4, u = g & 15;
  const ushort* zr = Zbf + (size_t)row * 384;
  uint4 kk = *(const uint4*)(zr + 128 + u * 8);
  uint4 mm = *(const uint4*)(zr + 256 + u * 8);
  uint4 qq = *(const uint4*)(zr + u * 8);
  float kf[8] = {b2f_lo(kk.x), b2f_hi(kk.x), b2f_lo(kk.y), b2f_hi(kk.y),
                 b2f_lo(kk.z), b2f_hi(kk.z), b2f_lo(kk.w), b2f_hi(kk.w)};
  float mf[8] = {b2f_lo(mm.x), b2f_hi(mm.x), b2f_lo(mm.y), b2f_hi(mm.y),
                 b2f_lo(mm.z), b2f_hi(mm.z), b2f_lo(mm.w), b2f_hi(mm.w)};
  float qf[8] = {b2f_lo(qq.x), b2f_hi(qq.x), b2f_lo(qq.y), b2f_hi(qq.y),
                 b2f_lo(qq.z), b2f_hi(qq.z), b2f_lo(qq.w), b2f_hi(qq.w)};
  float mk = 0.f, mx = 0.f, mqv = 0.f;
#pragma unroll
  for (int i = 0; i < 8; i++) {
    mk = fmaxf(mk, fabsf(kf[i]));
    mx = fmaxf(mx, fabsf(mf[i]));
    mqv = fmaxf(mqv, fabsf(qf[i]));
  }
#pragma unroll
  for (int dd = 1; dd < 16; dd <<= 1) {
    mk = fmaxf(mk, __shfl_xor(mk, dd));
    mx = fmaxf(mx, __shfl_xor(mx, dd));
    mqv = fmaxf(mqv, __shfl_xor(mqv, dd));
  }
  mk = fmaxf(mk, 1e-20f); mx = fmaxf(mx, 1e-20f); mqv = fmaxf(mqv, 1e-20f);
  float qk = 127.0f / mk, qm = 127.0f / mx;
  int q[16];
#pragma unroll
  for (int i = 0; i < 8; i++) {
    q[i] = __float2int_rn(kf[i] * qk) & 0xff;
    q[8 + i] = (__float2int_rn(mf[i] * qm) + 128) & 0xff;   // biased m (matches aggregate)
  }
  uint4 o;
  o.x = (uint)(q[0] | (q[1] << 8) | (q[2] << 16) | (q[3] << 24));
  o.y = (uint)(q[4] | (q[5] << 8) | (q[6] << 16) | (q[7] << 24));
  o.z = (uint)(q[8] | (q[9] << 8) | (q[10] << 16) | (q[11] << 24));
  o.w = (uint)(q[12] | (q[13] << 8) | (q[14] << 16) | (q[15] << 24));
  *(uint4*)(Zkm + (size_t)row * 256 + u * 16) = o;
  if (u == 0) scales[row] = make_float2(mk * (1.0f / 127.0f), mx * (1.0f / 127.0f));
  float qsv = 127.0f / mqv;
  int r[8];
#pragma unroll
  for (int i = 0; i < 8; i++) r[i] = __float2int_rn(qf[i] * qsv) & 0xff;
  uint2 oq;
  oq.x = (uint)(r[0] | (r[1] << 8) | (r[2] << 16) | (r[3] << 24));
  oq.y = (uint)(r[4] | (r[5] << 8) | (r[6] << 16) | (r[7] << 24));
  *(uint2*)(Zq8 + (size_t)row * 128 + u * 8) = oq;
  if (u == 0) sqv[row] = mqv * (1.0f / 127.0f);
}

// ------- scatter2: per sub-bucket (16KB CSR window) from stage2 -------
__global__ __launch_bounds__(256) void scatter_final2(
    const uint* __restrict__ stage2, const int* __restrict__ subCur,
    int* __restrict__ cursor, int* __restrict__ csr_src) {
  int p = blockIdx.x & 7;
  int sb = (blockIdx.x >> 3) & 63;
  int half = blockIdx.x >> 9;            // 0..1
  int g = p * 64 + sb;
  int n = subCur[g * 16];
  const uint* reg = stage2 + (size_t)g * REGION2;
  int dbase = p * 16384;
  for (int i = half * 256 + threadIdx.x; i < n; i += 512) {
    uint v = reg[i];
    int d = dbase + (int)(v & 16383u);
    int pos = atomicAdd(&cursor[d], 1);
    csr_src[pos] = (int)(v >> 14);
  }
}

// ------- scatter (fallback) -------
__global__ __launch_bounds__(256) void scatter_final(
    const int2* __restrict__ stage, const int* __restrict__ stageCur,
    int* __restrict__ cursor, int* __restrict__ csr_src) {
  int p = blockIdx.x & 7;
  int k = blockIdx.x >> 3;
  int n = stageCur[p * 16];
  const int2* reg = stage + (size_t)p * REGION;
  for (int i = k * 256 + threadIdx.x; i < n; i += 130 * 256) {
    int2 e = reg[i];
    int pos = atomicAdd(&cursor[e.y], 1);
    csr_src[pos] = e.x;
  }
}

// ---------------- fused attention + aggregation, int8 gathers ----------------
// zk signed int8 (dot4 vs int8 zq); zm BIASED uint8, dequant via cvt_f32_ubyte +
// algebraic bias removal (a_d -= 128 * sum(wm)).
__global__ __launch_bounds__(256) void aggregate_q(
    const char* __restrict__ Zkm, const float* __restrict__ scales,
    const int* __restrict__ offsets, const int* __restrict__ csr_src,
    ushort* __restrict__ aggbf,
    const char* __restrict__ Zq8, const float* __restrict__ sqv) {
  int wv = threadIdx.x >> 6, L = threadIdx.x & 63;
  int n = blockIdx.x * 4 + wv;
  if (n >= NN) return;
  int qt = L >> 4, l = L & 15;
  int lb = l << 4;                         // byte offset within 256B row

  uint2 q8 = *(const uint2*)(Zq8 + (size_t)n * 128 + l * 8);
  float tq = TAU * sqv[n];

  int start = offsets[n], end = offsets[n + 1];
  float den = 0.f, swm = 0.f;
  float a0 = 0.f, a1 = 0.f, a2 = 0.f, a3 = 0.f, a4 = 0.f, a5 = 0.f, a6 = 0.f, a7 = 0.f;
  int p = start;

  for (; p + 8 <= end; p += 8) {
    int s0 = csr_src[p + qt];
    int s1 = csr_src[p + 4 + qt];
    uint4 v0 = *(const uint4*)(Zkm + ((size_t)s0 << 8) + lb);
    uint4 v1 = *(const uint4*)(Zkm + ((size_t)s1 << 8) + lb);
    float2 sc0 = *(const float2*)(scales + s0 * 2);
    float2 sc1 = *(const float2*)(scales + s1 * 2);

    int p0 = dot4i8(v0.x, q8.x, 0); p0 = dot4i8(v0.y, q8.y, p0);
    int p1 = dot4i8(v1.x, q8.x, 0); p1 = dot4i8(v1.y, q8.y, p1);
    p0 += __shfl_xor(p0, 1); p1 += __shfl_xor(p1, 1);
    p0 += __shfl_xor(p0, 2); p1 += __shfl_xor(p1, 2);
    float w0 = __expf(tq * sc0.x * (float)p0);
    float w1 = __expf(tq * sc1.x * (float)p1);
    den += w0 + w1;
    float wm0 = w0 * sc0.y, wm1 = w1 * sc1.y;
    swm += wm0 + wm1;

    a0 = fmaf(UB0(v0.z), wm0, a0); a1 = fmaf(UB1(v0.z), wm0, a1);
    a2 = fmaf(UB2(v0.z), wm0, a2); a3 = fmaf(UB3(v0.z), wm0, a3);
    a4 = fmaf(UB0(v0.w), wm0, a4); a5 = fmaf(UB1(v0.w), wm0, a5);
    a6 = fmaf(UB2(v0.w), wm0, a6); a7 = fmaf(UB3(v0.w), wm0, a7);
    a0 = fmaf(UB0(v1.z), wm1, a0); a1 = fmaf(UB1(v1.z), wm1, a1);
    a2 = fmaf(UB2(v1.z), wm1, a2); a3 = fmaf(UB3(v1.z), wm1, a3);
    a4 = fmaf(UB0(v1.w), wm1, a4); a5 = fmaf(UB1(v1.w), wm1, a5);
    a6 = fmaf(UB2(v1.w), wm1, a6); a7 = fmaf(UB3(v1.w), wm1, a7);
  }

  for (; p < end; p += 4) {               // masked tail, whole wave stays
    int e = p + qt;
    int idx = (e < end) ? e : (end - 1);
    int s0 = csr_src[idx];
    uint4 v = *(const uint4*)(Zkm + ((size_t)s0 << 8) + lb);
    float2 sc = *(const float2*)(scales + s0 * 2);
    int p0 = dot4i8(v.x, q8.x, 0); p0 = dot4i8(v.y, q8.y, p0);
    p0 += __shfl_xor(p0, 1);
    p0 += __shfl_xor(p0, 2);
    float w = (e < end) ? __expf(tq * sc.x * (float)p0) : 0.f;
    den += w;
    float wm = w * sc.y;
    swm += wm;
    a0 = fmaf(UB0(v.z), wm, a0); a1 = fmaf(UB1(v.z), wm, a1);
    a2 = fmaf(UB2(v.z), wm, a2); a3 = fmaf(UB3(v.z), wm, a3);
    a4 = fmaf(UB0(v.w), wm, a4); a5 = fmaf(UB1(v.w), wm, a5);
    a6 = fmaf(UB2(v.w), wm, a6); a7 = fmaf(UB3(v.w), wm, a7);
  }

  // combine the four quarters
  den += __shfl_xor(den, 16); den += __shfl_xor(den, 32);
  swm += __shfl_xor(swm, 16); swm += __shfl_xor(swm, 32);
  a0 += __shfl_xor(a0, 16); a0 += __shfl_xor(a0, 32);
  a1 += __shfl_xor(a1, 16); a1 += __shfl_xor(a1, 32);
  a2 += __shfl_xor(a2, 16); a2 += __shfl_xor(a2, 32);
  a3 += __shfl_xor(a3, 16); a3 += __shfl_xor(a3, 32);
  a4 += __shfl_xor(a4, 16); a4 += __shfl_xor(a4, 32);
  a5 += __shfl_xor(a5, 16); a5 += __shfl_xor(a5, 32);
  a6 += __shfl_xor(a6, 16); a6 += __shfl_xor(a6, 32);
  a7 += __shfl_xor(a7, 16); a7 += __shfl_xor(a7, 32);

  float bcorr = 128.f * swm;
  float inv = (den > 0.f) ? 1.0f / den : 0.f;
  if (qt == 0) {
    uint4 o;
    o.x = (uint)f2b((a0 - bcorr) * inv) | ((uint)f2b((a1 - bcorr) * inv) << 16);
    o.y = (uint)f2b((a2 - bcorr) * inv) | ((uint)f2b((a3 - bcorr) * inv) << 16);
    o.z = (uint)f2b((a4 - bcorr) * inv) | ((uint)f2b((a5 - bcorr) * inv) << 16);
    o.w = (uint)f2b((a6 - bcorr) * inv) | ((uint)f2b((a7 - bcorr) * inv) << 16);
    *(uint4*)((char*)aggbf + (size_t)n * 256 + lb) = o;
  }
}

// ---------------- launch ----------------
extern "C" void kernel_launch(void* const* d_in, const int* in_sizes, int n_in,
                              void* d_out, int out_size, void* d_ws, size_t ws_size,
                              hipStream_t stream) {
  const float* h    = (const float*)d_in[0];
  const int*   src  = (const int*)d_in[1];
  const int*   dst  = (const int*)d_in[2];
  const float* Wq   = (const float*)d_in[3];
  const float* bq   = (const float*)d_in[4];
  const float* Wk   = (const float*)d_in[5];
  const float* bk   = (const float*)d_in[6];
  const float* Wm   = (const float*)d_in[7];
  const float* bm   = (const float*)d_in[8];
  const float* Wout = (const float*)d_in[9];
  const float* bout = (const float*)d_in[10];
  float* out = (float*)d_out;

  char* base = (char*)d_ws;
  ushort* Abf    = (ushort*)base;                         // NN*128 bf16
  char*   Zkm    = base + 25600000;                       // NN*256B int8 (freed Zbf slot)
  char*   Zq8    = base + 51200000;                       // NN*128 int8
  ushort* Zbf    = (ushort*)(base + 25600000);            // fallback only
  ushort* aggbf  = (ushort*)(base + 102400000);           // NN*128 bf16
  int2*   stage  = (int2*)(base + 102400000);             // 8*REGION int2 (dead before aggbf)
  float*  scales = (float*)(base + 128000000);            // NN float2
  ushort* BTproj = (ushort*)(base + 128800000);
  ushort* BTout  = (ushort*)(base + 128898304);
  float*  bvec   = (float*)(base + 128931072);
  int* counts    = (int*)(base + 128933120);              // 400000
  int* stageCur  = (int*)(base + 129333120);              // 1024
  int* subCur    = (int*)(base + 129334144);              // 32768
  int* offsets   = (int*)(base + 129366912);              // 400128
  int* cursor    = (int*)(base + 129767040);              // 400000
  int* blockSums = (int*)(base + 130167040);              // 512
  int* csr_src   = (int*)(base + 130167552);              // NE*4 -> 136567552
  char* Zq8_fb   = base + 136567552;                      // fallback Zq8
  float* sqv     = (float*)(base + 149367552);            // NN f32 -> 149767552
  uint* stage2   = (uint*)(base + 149767552);             // -> 160253312

  int fast = (ws_size >= (size_t)160253312) ? 1 : 0;

  hipMemsetAsync(counts, 0, 433792, stream);   // counts + stageCur + subCur

  setup_stage<<<7288, 256, 0, stream>>>(h, Abf, Wq, Wk, Wm, bq, bk, bm, Wout,
                                        BTproj, BTout, bvec, src, dst, stageCur, stage);
  if (fast) {
    stage2_kernel<1><<<512, 256, 0, stream>>>(stage, stageCur, subCur, stage2, counts);
  } else {
    hist_part<<<256, 256, 0, stream>>>(stage, stageCur, counts);
  }
  scan_a<<<98, 256, 0, stream>>>(counts, offsets, blockSums, NN);
  scan_b<<<1, 128, 0, stream>>>(blockSums, 98);
  scan_c<<<391, 256, 0, stream>>>(offsets, blockSums, cursor, NN);

  if (fast) {
    mfma_gemm<2><<<dim3(1563, 3), 256, 0, stream>>>(
        Abf, BTproj, bvec, nullptr, NN, 384, Zkm, Zq8, scales, sqv);
    scatter_final2<<<1024, 256, 0, stream>>>(stage2, subCur, cursor, csr_src);
    aggregate_q<<<25000, 256, 0, stream>>>(Zkm, scales, offsets, csr_src, aggbf, Zq8, sqv);
  } else {
    mfma_gemm<1><<<dim3(1563, 3), 256, 0, stream>>>(
        Abf, BTproj, bvec, Zbf, NN, 384, nullptr, nullptr, nullptr, nullptr);
    quant_kernel<<<6250, 256, 0, stream>>>(Zbf, (char*)base, (float2*)scales, Zq8_fb, sqv);
    scatter_final<<<1040, 256, 0, stream>>>(stage, stageCur, cursor, csr_src);
    aggregate_q<<<25000, 256, 0, stream>>>((char*)base, scales, offsets, csr_src,
                                           aggbf, Zq8_fb, sqv);
  }

  mfma_gemm<0><<<dim3(1563, 1), 256, 0, stream>>>(
      aggbf, BTout, bout, out, NN, 128, nullptr, nullptr, nullptr, nullptr);
}

// Round 17
// 278.810 us; speedup vs baseline: 1.3173x; 1.0069x over previous
//
#include <hip/hip_runtime.h>
#include <hip/hip_bf16.h>
#include <cstdint>
#include <cstddef>

#define NN 100000
#define NE 1600000
#define TAU 0.3f
#define REGION 400000   // stage-1 slots per dst-partition (8 partitions)
#define REGION2 5120    // stage-2 slots per (partition,sub-bucket)

typedef __attribute__((ext_vector_type(8))) short bf16x8;
typedef __attribute__((ext_vector_type(4))) float f32x4;

#if __has_builtin(__builtin_amdgcn_sdot4)
#define HAVE_SDOT4 1
#else
#define HAVE_SDOT4 0
#endif

static __device__ __forceinline__ float b2f_hi(uint w) {
  return __uint_as_float(w & 0xffff0000u);
}
static __device__ __forceinline__ float b2f_lo(uint w) {
  return __uint_as_float(w << 16);
}
static __device__ __forceinline__ ushort f2b(float f) {
  uint x = __float_as_uint(f);
  return (ushort)((x + 0x7fffu + ((x >> 16) & 1u)) >> 16);
}
static __device__ __forceinline__ float i8f(uint w, int k) {
  return (float)((int)(w << (24 - 8 * k)) >> 24);
}
static __device__ __forceinline__ int dot4i8(uint a, uint b, int c) {
#if HAVE_SDOT4
  return __builtin_amdgcn_sdot4((int)a, (int)b, c, false);
#else
  return c + (int)(char)(a) * (int)(char)(b)
           + (int)(char)(a >> 8) * (int)(char)(b >> 8)
           + (int)(char)(a >> 16) * (int)(char)(b >> 16)
           + (int)(char)(a >> 24) * (int)(char)(b >> 24);
#endif
}
#if __has_builtin(__builtin_amdgcn_cvt_f32_ubyte0)
#define UB0(w) __builtin_amdgcn_cvt_f32_ubyte0(w)
#define UB1(w) __builtin_amdgcn_cvt_f32_ubyte1(w)
#define UB2(w) __builtin_amdgcn_cvt_f32_ubyte2(w)
#define UB3(w) __builtin_amdgcn_cvt_f32_ubyte3(w)
#else
#define UB0(w) ((float)((w) & 0xffu))
#define UB1(w) ((float)(((w) >> 8) & 0xffu))
#define UB2(w) ((float)(((w) >> 16) & 0xffu))
#define UB3(w) ((float)(((w) >> 24) & 0xffu))
#endif

// ------- K1: conv_h (blocks 0..6249) + prep (6250..6505) + stage (6506..7287) -------
__global__ __launch_bounds__(256) void setup_stage(
    const float* __restrict__ h, ushort* __restrict__ A,
    const float* __restrict__ Wq, const float* __restrict__ Wk, const float* __restrict__ Wm,
    const float* __restrict__ bq, const float* __restrict__ bk, const float* __restrict__ bm,
    const float* __restrict__ Wout,
    ushort* __restrict__ BTproj, ushort* __restrict__ BTout, float* __restrict__ bvec,
    const int* __restrict__ src, const int* __restrict__ dst,
    int* __restrict__ stageCur, int2* __restrict__ stage) {
  int b = blockIdx.x;
  int t = threadIdx.x;
  if (b < 6250) {                       // h f32 -> bf16
    int i = b * 256 + t;
    const float4* hv = (const float4*)h + (size_t)i * 2;
    float4 a = hv[0], c = hv[1];
    uint4 o;
    o.x = (uint)f2b(a.x) | ((uint)f2b(a.y) << 16);
    o.y = (uint)f2b(a.z) | ((uint)f2b(a.w) << 16);
    o.z = (uint)f2b(c.x) | ((uint)f2b(c.y) << 16);
    o.w = (uint)f2b(c.z) | ((uint)f2b(c.w) << 16);
    ((uint4*)A)[i] = o;
    return;
  }
  if (b < 6506) {                       // weight prep, 65536 threads
    int id = (b - 6250) * 256 + t;
    if (id < 384 * 128) {
      int j = id >> 7, k = id & 127;
      int w = j >> 7, r = j & 127, hh = r >> 5, d = r & 31;
      const float* W = (w == 0) ? Wq : (w == 1) ? Wk : Wm;
      BTproj[id] = f2b(W[hh * 4096 + k * 32 + d]);
      if (k == 0) {
        const float* bb = (w == 0) ? bq : (w == 1) ? bk : bm;
        bvec[j] = bb[hh * 32 + d];
      }
    } else {
      int id2 = id - 384 * 128;                // 16384
      int c = id2 >> 7, k = id2 & 127;
      BTout[id2] = f2b(Wout[k * 128 + c]);
    }
    return;
  }
  // stage branch: 782 blocks x 2048 edges, bin by dst>>14 into fixed regions
  __shared__ int cnt[8];
  __shared__ int gbase[8];
  if (t < 8) cnt[t] = 0;
  __syncthreads();
  int e0 = (b - 6506) * 2048 + t;
  int d[8], s[8];
#pragma unroll
  for (int i = 0; i < 8; i++) {
    int e = e0 + i * 256;
    if (e < NE) {
      d[i] = dst[e];
      s[i] = src[e];
      atomicAdd(&cnt[d[i] >> 14], 1);
    } else {
      d[i] = -1;
    }
  }
  __syncthreads();
  if (t < 8) gbase[t] = atomicAdd(&stageCur[t * 16], cnt[t]);
  __syncthreads();
  if (t < 8) cnt[t] = 0;
  __syncthreads();
#pragma unroll
  for (int i = 0; i < 8; i++) {
    if (d[i] >= 0) {
      int p = d[i] >> 14;
      int slot = p * REGION + gbase[p] + atomicAdd(&cnt[p], 1);
      stage[slot] = make_int2(s[i], d[i]);
    }
  }
}

// ------- stage2 v2: LDS-reorder binning into 64 sub-buckets (+fused histogram) -------
// Edges grouped by sub-bucket in an LDS buffer, then flushed as contiguous runs.
template <int DOHIST>
__global__ __launch_bounds__(256) void stage2_kernel(
    const int2* __restrict__ stage, const int* __restrict__ stageCur,
    int* __restrict__ subCur, uint* __restrict__ stage2,
    int* __restrict__ counts) {
  int p = blockIdx.x & 7;
  int kb = blockIdx.x >> 3;              // 0..127 block within partition
  int t = threadIdx.x;
  int n = stageCur[p * 16];
  const int2* reg = stage + (size_t)p * REGION;
  int dbase = p * 16384;
  __shared__ int cnt[64];
  __shared__ int pos[64];                // exclusive prefix (chunk-local)
  __shared__ int gb[64];                 // reserved global base per sub-bucket
  __shared__ int mvs;
  __shared__ uint buf[2048];

  for (int base = kb * 2048; base < n; base += 128 * 2048) {
    if (t < 64) cnt[t] = 0;
    __syncthreads();
    uint v[8]; int sb[8];
#pragma unroll
    for (int i = 0; i < 8; i++) {
      int idx = base + t + i * 256;
      if (idx < n) {
        int2 e = reg[idx];
        int dlow = e.y & 16383;
        sb[i] = dlow >> 8;               // sub-bucket 0..63
        v[i] = ((uint)e.x << 14) | (uint)dlow;
        atomicAdd(&cnt[sb[i]], 1);
        if (DOHIST) atomicAdd(&counts[dbase + dlow], 1);   // partition-local
      } else sb[i] = -1;
    }
    __syncthreads();
    if (t < 64) {                        // one wave: scan + reserve
      int c = cnt[t];
      int x = c;
#pragma unroll
      for (int d = 1; d < 64; d <<= 1) {
        int y = __shfl_up(x, d);
        if (t >= d) x += y;
      }
      pos[t] = x - c;
      gb[t] = c ? atomicAdd(&subCur[(p * 64 + t) * 16], c) : 0;
      if (t == 63) mvs = x;
      cnt[t] = 0;                        // reuse as placement cursor
    }
    __syncthreads();
#pragma unroll
    for (int i = 0; i < 8; i++) {
      if (sb[i] >= 0) {
        int loc = pos[sb[i]] + atomicAdd(&cnt[sb[i]], 1);
        buf[loc] = v[i];
      }
    }
    __syncthreads();
    int mv = mvs;
    for (int j = t; j < mv; j += 256) {  // contiguous runs per sub-bucket
      uint w = buf[j];
      int s2 = (int)((w & 16383u) >> 8);
      stage2[((size_t)(p * 64 + s2)) * REGION2 + gb[s2] + (j - pos[s2])] = w;
    }
    __syncthreads();
  }
}

// ------- K2 (fallback): partition-local histogram from stage-1 -------
__global__ __launch_bounds__(256) void hist_part(
    const int2* __restrict__ stage, const int* __restrict__ stageCur,
    int* __restrict__ counts) {
  int p = blockIdx.x & 7;
  int k = blockIdx.x >> 3;              // 0..31
  int n = stageCur[p * 16];
  const int2* reg = stage + (size_t)p * REGION;
  for (int i = k * 256 + threadIdx.x; i < n; i += 32 * 256)
    atomicAdd(&counts[reg[i].y], 1);
}

// ---------------- MFMA GEMM: 64x128 tile, 48 KB LDS, 3 blocks/CU ----------------
// MODE 0: float out + relu. MODE 1: bf16 out. MODE 2: fused int8 quant epilogue
template <int MODE>
__global__ __launch_bounds__(256) void mfma_gemm(
    const ushort* __restrict__ A, const ushort* __restrict__ BT,
    const float* __restrict__ bias, void* __restrict__ Cp, int M, int ncols,
    char* __restrict__ Zkm, char* __restrict__ Zq8,
    float* __restrict__ scales, float* __restrict__ sqv) {
  __shared__ ushort As[64 * 128];    // 16 KB
  __shared__ ushort Bs[128 * 128];   // 32 KB

  int t = threadIdx.x;
  int rowBase = blockIdx.x * 64, colBase = blockIdx.y * 128;

#pragma unroll
  for (int i = 0; i < 4; i++) {      // A: 1024 chunks of 16B
    int flat = t + i * 256;
    int row = flat >> 4;
    int kb = (flat & 15) * 16;
    int soff = kb ^ ((row & 7) << 4);
    int ar = rowBase + row; if (ar >= M) ar = M - 1;
    __builtin_amdgcn_global_load_lds(
        (const __attribute__((address_space(1))) uint32_t*)((const char*)A + (size_t)ar * 256 + soff),
        (__attribute__((address_space(3))) uint32_t*)((char*)As + row * 256 + kb), 16, 0, 0);
  }
#pragma unroll
  for (int i = 0; i < 8; i++) {      // B: 2048 chunks of 16B
    int flat = t + i * 256;
    int row = flat >> 4;
    int kb = (flat & 15) * 16;
    int soff = kb ^ ((row & 7) << 4);
    __builtin_amdgcn_global_load_lds(
        (const __attribute__((address_space(1))) uint32_t*)((const char*)BT + (size_t)(colBase + row) * 256 + soff),
        (__attribute__((address_space(3))) uint32_t*)((char*)Bs + row * 256 + kb), 16, 0, 0);
  }
  __syncthreads();

  int wv = t >> 6, L = t & 63;
  int wrow = (wv >> 1) * 32, wcol = (wv & 1) * 64;
  int lr = L & 15;
  int lk = (L >> 4) * 16;
  f32x4 acc[2][4] = {};

#pragma unroll
  for (int ks = 0; ks < 4; ks++) {
    bf16x8 a[2], b[4];
#pragma unroll
    for (int i = 0; i < 2; i++) {
      int row = wrow + i * 16 + lr;
      a[i] = *(const bf16x8*)((const char*)As + row * 256 + ((ks * 64 + lk) ^ ((row & 7) << 4)));
    }
#pragma unroll
    for (int j = 0; j < 4; j++) {
      int col = wcol + j * 16 + lr;
      b[j] = *(const bf16x8*)((const char*)Bs + col * 256 + ((ks * 64 + lk) ^ ((col & 7) << 4)));
    }
#pragma unroll
    for (int i = 0; i < 2; i++)
#pragma unroll
      for (int j = 0; j < 4; j++)
        acc[i][j] = __builtin_amdgcn_mfma_f32_16x16x32_bf16(a[i], b[j], acc[i][j], 0, 0, 0);
  }

  int rquad = (L >> 4) * 4;

  if (MODE == 2) {
    __syncthreads();
    float* Cs = (float*)Bs;              // 64*128*4 = 32 KB
#pragma unroll
    for (int j = 0; j < 4; j++) {
      float bs = bias[colBase + wcol + j * 16 + lr];
#pragma unroll
      for (int i = 0; i < 2; i++) {
        int rl = wrow + i * 16 + rquad;
#pragma unroll
        for (int r = 0; r < 4; r++)
          Cs[(rl + r) * 128 + wcol + j * 16 + lr] = acc[i][j][r] + bs;
      }
    }
    __syncthreads();

    int row = t >> 2, part = t & 3;      // 4 threads per row, 32 cols each
    int row_g = rowBase + row;
    const float4* rp = (const float4*)(Cs + row * 128 + part * 32);
    float4 v[8];
    float vmax = 0.f;
#pragma unroll
    for (int i = 0; i < 8; i++) {
      v[i] = rp[i];
      vmax = fmaxf(vmax, fmaxf(fmaxf(fabsf(v[i].x), fabsf(v[i].y)),
                               fmaxf(fabsf(v[i].z), fabsf(v[i].w))));
    }
    vmax = fmaxf(vmax, __shfl_xor(vmax, 1));
    vmax = fmaxf(vmax, __shfl_xor(vmax, 2));
    vmax = fmaxf(vmax, 1e-20f);
    float qs = 127.0f / vmax;
    int w = blockIdx.y;
    if (row_g < M) {
      if (w == 0) {
        uint b8[8];
#pragma unroll
        for (int i = 0; i < 8; i++)
          b8[i] = (uint)(__float2int_rn(v[i].x * qs) & 0xff)
                | ((uint)(__float2int_rn(v[i].y * qs) & 0xff) << 8)
                | ((uint)(__float2int_rn(v[i].z * qs) & 0xff) << 16)
                | ((uint)(__float2int_rn(v[i].w * qs) & 0xff) << 24);
        uint4* dst4 = (uint4*)(Zq8 + (size_t)row_g * 128 + part * 32);
        dst4[0] = make_uint4(b8[0], b8[1], b8[2], b8[3]);
        dst4[1] = make_uint4(b8[4], b8[5], b8[6], b8[7]);
        if (part == 0) sqv[row_g] = vmax * (1.0f / 127.0f);
      } else {
#pragma unroll
        for (int u = 0; u < 2; u++) {
#pragma unroll
          for (int hh = 0; hh < 2; hh++) {
            int un = part * 4 + u * 2 + hh;
            float4 va = v[u * 4 + hh * 2], vb = v[u * 4 + hh * 2 + 1];
            uint lo, hi;
            if (w == 1) {
              lo = (uint)(__float2int_rn(va.x * qs) & 0xff)
                 | ((uint)(__float2int_rn(va.y * qs) & 0xff) << 8)
                 | ((uint)(__float2int_rn(va.z * qs) & 0xff) << 16)
                 | ((uint)(__float2int_rn(va.w * qs) & 0xff) << 24);
              hi = (uint)(__float2int_rn(vb.x * qs) & 0xff)
                 | ((uint)(__float2int_rn(vb.y * qs) & 0xff) << 8)
                 | ((uint)(__float2int_rn(vb.z * qs) & 0xff) << 16)
                 | ((uint)(__float2int_rn(vb.w * qs) & 0xff) << 24);
            } else {
              lo = (uint)((__float2int_rn(va.x * qs) + 128) & 0xff)
                 | ((uint)((__float2int_rn(va.y * qs) + 128) & 0xff) << 8)
                 | ((uint)((__float2int_rn(va.z * qs) + 128) & 0xff) << 16)
                 | ((uint)((__float2int_rn(va.w * qs) + 128) & 0xff) << 24);
              hi = (uint)((__float2int_rn(vb.x * qs) + 128) & 0xff)
                 | ((uint)((__float2int_rn(vb.y * qs) + 128) & 0xff) << 8)
                 | ((uint)((__float2int_rn(vb.z * qs) + 128) & 0xff) << 16)
                 | ((uint)((__float2int_rn(vb.w * qs) + 128) & 0xff) << 24);
            }
            uint2* d2 = (uint2*)(Zkm + (size_t)row_g * 256 + un * 16 + (w == 2 ? 8 : 0));
            *d2 = make_uint2(lo, hi);
          }
        }
        if (part == 0) scales[row_g * 2 + (w - 1)] = vmax * (1.0f / 127.0f);
      }
    }
    return;
  }

#pragma unroll
  for (int j = 0; j < 4; j++) {
    int col = colBase + wcol + j * 16 + lr;
    float bs = bias[col];
#pragma unroll
    for (int i = 0; i < 2; i++) {
      int row0 = rowBase + wrow + i * 16 + rquad;
#pragma unroll
      for (int r = 0; r < 4; r++) {
        int row = row0 + r;
        if (row >= M) continue;
        float vv = acc[i][j][r] + bs;
        if (MODE == 0) {
          vv = fmaxf(vv, 0.f);
          ((float*)Cp)[(size_t)row * ncols + col] = vv;
        } else {
          ((ushort*)Cp)[(size_t)row * ncols + col] = f2b(vv);
        }
      }
    }
  }
}

// ---------------- CSR scans ----------------
__global__ __launch_bounds__(256) void scan_a(const int* __restrict__ counts,
                                              int* __restrict__ offsets,
                                              int* __restrict__ blockSums, int n) {
  __shared__ int lds[256];
  int b = blockIdx.x, t = threadIdx.x;
  int base = b * 1024 + t * 4;
  int4 v = make_int4(0, 0, 0, 0);
  if (base < n) v = *(const int4*)&counts[base];
  int s1 = v.x + v.y, s2 = s1 + v.z, s3 = s2 + v.w;
  lds[t] = s3;
  __syncthreads();
  for (int dd = 1; dd < 256; dd <<= 1) {
    int x = (t >= dd) ? lds[t - dd] : 0;
    __syncthreads();
    lds[t] += x;
    __syncthreads();
  }
  int excl = (t > 0) ? lds[t - 1] : 0;
  if (base < n) {
    int4 o = make_int4(excl, excl + v.x, excl + s1, excl + s2);
    *(int4*)&offsets[base] = o;
  }
  if (t == 255) blockSums[b] = lds[255];
}

__global__ __launch_bounds__(128) void scan_b(int* __restrict__ blockSums, int nb) {
  __shared__ int lds[128];
  int t = threadIdx.x;
  lds[t] = (t < nb) ? blockSums[t] : 0;
  __syncthreads();
  for (int dd = 1; dd < 128; dd <<= 1) {
    int x = (t >= dd) ? lds[t - dd] : 0;
    __syncthreads();
    lds[t] += x;
    __syncthreads();
  }
  if (t < nb) blockSums[t] = (t > 0) ? lds[t - 1] : 0;
}

__global__ __launch_bounds__(256) void scan_c(int* __restrict__ offsets,
                                              const int* __restrict__ blockSums,
                                              int* __restrict__ cursor, int n) {
  int i = blockIdx.x * 256 + threadIdx.x;
  if (i < n) {
    int v = offsets[i] + blockSums[i >> 10];
    offsets[i] = v;
    cursor[i] = v;
  }
  if (i == 0) offsets[n] = NE;
}

// ------- quant (fallback only): Zbf -> int8 (biased m) -------
__global__ __launch_bounds__(256) void quant_kernel(
    const ushort* __restrict__ Zbf, char* __restrict__ Zkm, float2* __restrict__ scales,
    char* __restrict__ Zq8, float* __restrict__ sqv) {
  int g = blockIdx.x * 256 + threadIdx.x;
  int row = g >> 4, u = g & 15;
  const ushort* zr = Zbf + (size_t)row * 384;
  uint4 kk = *(const uint4*)(zr + 128 + u * 8);
  uint4 mm = *(const uint4*)(zr + 256 + u * 8);
  uint4 qq = *(const uint4*)(zr + u * 8);
  float kf[8] = {b2f_lo(kk.x), b2f_hi(kk.x), b2f_lo(kk.y), b2f_hi(kk.y),
                 b2f_lo(kk.z), b2f_hi(kk.z), b2f_lo(kk.w), b2f_hi(kk.w)};
  float mf[8] = {b2f_lo(mm.x), b2f_hi(mm.x), b2f_lo(mm.y), b2f_hi(mm.y),
                 b2f_lo(mm.z), b2f_hi(mm.z), b2f_lo(mm.w), b2f_hi(mm.w)};
  float qf[8] = {b2f_lo(qq.x), b2f_hi(qq.x), b2f_lo(qq.y), b2f_hi(qq.y),
                 b2f_lo(qq.z), b2f_hi(qq.z), b2f_lo(qq.w), b2f_hi(qq.w)};
  float mk = 0.f, mx = 0.f, mqv = 0.f;
#pragma unroll
  for (int i = 0; i < 8; i++) {
    mk = fmaxf(mk, fabsf(kf[i]));
    mx = fmaxf(mx, fabsf(mf[i]));
    mqv = fmaxf(mqv, fabsf(qf[i]));
  }
#pragma unroll
  for (int dd = 1; dd < 16; dd <<= 1) {
    mk = fmaxf(mk, __shfl_xor(mk, dd));
    mx = fmaxf(mx, __shfl_xor(mx, dd));
    mqv = fmaxf(mqv, __shfl_xor(mqv, dd));
  }
  mk = fmaxf(mk, 1e-20f); mx = fmaxf(mx, 1e-20f); mqv = fmaxf(mqv, 1e-20f);
  float qk = 127.0f / mk, qm = 127.0f / mx;
  int q[16];
#pragma unroll
  for (int i = 0; i < 8; i++) {
    q[i] = __float2int_rn(kf[i] * qk) & 0xff;
    q[8 + i] = (__float2int_rn(mf[i] * qm) + 128) & 0xff;
  }
  uint4 o;
  o.x = (uint)(q[0] | (q[1] << 8) | (q[2] << 16) | (q[3] << 24));
  o.y = (uint)(q[4] | (q[5] << 8) | (q[6] << 16) | (q[7] << 24));
  o.z = (uint)(q[8] | (q[9] << 8) | (q[10] << 16) | (q[11] << 24));
  o.w = (uint)(q[12] | (q[13] << 8) | (q[14] << 16) | (q[15] << 24));
  *(uint4*)(Zkm + (size_t)row * 256 + u * 16) = o;
  if (u == 0) scales[row] = make_float2(mk * (1.0f / 127.0f), mx * (1.0f / 127.0f));
  float qsv = 127.0f / mqv;
  int r[8];
#pragma unroll
  for (int i = 0; i < 8; i++) r[i] = __float2int_rn(qf[i] * qsv) & 0xff;
  uint2 oq;
  oq.x = (uint)(r[0] | (r[1] << 8) | (r[2] << 16) | (r[3] << 24));
  oq.y = (uint)(r[4] | (r[5] << 8) | (r[6] << 16) | (r[7] << 24));
  *(uint2*)(Zq8 + (size_t)row * 128 + u * 8) = oq;
  if (u == 0) sqv[row] = mqv * (1.0f / 127.0f);
}

// ------- scatter2: per sub-bucket (16KB CSR window) from stage2 -------
__global__ __launch_bounds__(256) void scatter_final2(
    const uint* __restrict__ stage2, const int* __restrict__ subCur,
    int* __restrict__ cursor, int* __restrict__ csr_src) {
  int p = blockIdx.x & 7;
  int sb = (blockIdx.x >> 3) & 63;
  int half = blockIdx.x >> 9;            // 0..1
  int g = p * 64 + sb;
  int n = subCur[g * 16];
  const uint* reg = stage2 + (size_t)g * REGION2;
  int dbase = p * 16384;
  for (int i = half * 256 + threadIdx.x; i < n; i += 512) {
    uint v = reg[i];
    int d = dbase + (int)(v & 16383u);
    int pos = atomicAdd(&cursor[d], 1);
    csr_src[pos] = (int)(v >> 14);
  }
}

// ------- scatter (fallback) -------
__global__ __launch_bounds__(256) void scatter_final(
    const int2* __restrict__ stage, const int* __restrict__ stageCur,
    int* __restrict__ cursor, int* __restrict__ csr_src) {
  int p = blockIdx.x & 7;
  int k = blockIdx.x >> 3;
  int n = stageCur[p * 16];
  const int2* reg = stage + (size_t)p * REGION;
  for (int i = k * 256 + threadIdx.x; i < n; i += 130 * 256) {
    int2 e = reg[i];
    int pos = atomicAdd(&cursor[e.y], 1);
    csr_src[pos] = e.x;
  }
}

// ---------------- fused attention + aggregation, int8 gathers ----------------
__global__ __launch_bounds__(256) void aggregate_q(
    const char* __restrict__ Zkm, const float* __restrict__ scales,
    const int* __restrict__ offsets, const int* __restrict__ csr_src,
    ushort* __restrict__ aggbf,
    const char* __restrict__ Zq8, const float* __restrict__ sqv) {
  int wv = threadIdx.x >> 6, L = threadIdx.x & 63;
  int n = blockIdx.x * 4 + wv;
  if (n >= NN) return;
  int qt = L >> 4, l = L & 15;
  int lb = l << 4;                         // byte offset within 256B row

  uint2 q8 = *(const uint2*)(Zq8 + (size_t)n * 128 + l * 8);
  float tq = TAU * sqv[n];

  int start = offsets[n], end = offsets[n + 1];
  float den = 0.f, swm = 0.f;
  float a0 = 0.f, a1 = 0.f, a2 = 0.f, a3 = 0.f, a4 = 0.f, a5 = 0.f, a6 = 0.f, a7 = 0.f;
  int p = start;

  for (; p + 8 <= end; p += 8) {
    int s0 = csr_src[p + qt];
    int s1 = csr_src[p + 4 + qt];
    uint4 v0 = *(const uint4*)(Zkm + ((size_t)s0 << 8) + lb);
    uint4 v1 = *(const uint4*)(Zkm + ((size_t)s1 << 8) + lb);
    float2 sc0 = *(const float2*)(scales + s0 * 2);
    float2 sc1 = *(const float2*)(scales + s1 * 2);

    int p0 = dot4i8(v0.x, q8.x, 0); p0 = dot4i8(v0.y, q8.y, p0);
    int p1 = dot4i8(v1.x, q8.x, 0); p1 = dot4i8(v1.y, q8.y, p1);
    p0 += __shfl_xor(p0, 1); p1 += __shfl_xor(p1, 1);
    p0 += __shfl_xor(p0, 2); p1 += __shfl_xor(p1, 2);
    float w0 = __expf(tq * sc0.x * (float)p0);
    float w1 = __expf(tq * sc1.x * (float)p1);
    den += w0 + w1;
    float wm0 = w0 * sc0.y, wm1 = w1 * sc1.y;
    swm += wm0 + wm1;

    a0 = fmaf(UB0(v0.z), wm0, a0); a1 = fmaf(UB1(v0.z), wm0, a1);
    a2 = fmaf(UB2(v0.z), wm0, a2); a3 = fmaf(UB3(v0.z), wm0, a3);
    a4 = fmaf(UB0(v0.w), wm0, a4); a5 = fmaf(UB1(v0.w), wm0, a5);
    a6 = fmaf(UB2(v0.w), wm0, a6); a7 = fmaf(UB3(v0.w), wm0, a7);
    a0 = fmaf(UB0(v1.z), wm1, a0); a1 = fmaf(UB1(v1.z), wm1, a1);
    a2 = fmaf(UB2(v1.z), wm1, a2); a3 = fmaf(UB3(v1.z), wm1, a3);
    a4 = fmaf(UB0(v1.w), wm1, a4); a5 = fmaf(UB1(v1.w), wm1, a5);
    a6 = fmaf(UB2(v1.w), wm1, a6); a7 = fmaf(UB3(v1.w), wm1, a7);
  }

  for (; p < end; p += 4) {               // masked tail, whole wave stays
    int e = p + qt;
    int idx = (e < end) ? e : (end - 1);
    int s0 = csr_src[idx];
    uint4 v = *(const uint4*)(Zkm + ((size_t)s0 << 8) + lb);
    float2 sc = *(const float2*)(scales + s0 * 2);
    int p0 = dot4i8(v.x, q8.x, 0); p0 = dot4i8(v.y, q8.y, p0);
    p0 += __shfl_xor(p0, 1);
    p0 += __shfl_xor(p0, 2);
    float w = (e < end) ? __expf(tq * sc.x * (float)p0) : 0.f;
    den += w;
    float wm = w * sc.y;
    swm += wm;
    a0 = fmaf(UB0(v.z), wm, a0); a1 = fmaf(UB1(v.z), wm, a1);
    a2 = fmaf(UB2(v.z), wm, a2); a3 = fmaf(UB3(v.z), wm, a3);
    a4 = fmaf(UB0(v.w), wm, a4); a5 = fmaf(UB1(v.w), wm, a5);
    a6 = fmaf(UB2(v.w), wm, a6); a7 = fmaf(UB3(v.w), wm, a7);
  }

  den += __shfl_xor(den, 16); den += __shfl_xor(den, 32);
  swm += __shfl_xor(swm, 16); swm += __shfl_xor(swm, 32);
  a0 += __shfl_xor(a0, 16); a0 += __shfl_xor(a0, 32);
  a1 += __shfl_xor(a1, 16); a1 += __shfl_xor(a1, 32);
  a2 += __shfl_xor(a2, 16); a2 += __shfl_xor(a2, 32);
  a3 += __shfl_xor(a3, 16); a3 += __shfl_xor(a3, 32);
  a4 += __shfl_xor(a4, 16); a4 += __shfl_xor(a4, 32);
  a5 += __shfl_xor(a5, 16); a5 += __shfl_xor(a5, 32);
  a6 += __shfl_xor(a6, 16); a6 += __shfl_xor(a6, 32);
  a7 += __shfl_xor(a7, 16); a7 += __shfl_xor(a7, 32);

  float bcorr = 128.f * swm;
  float inv = (den > 0.f) ? 1.0f / den : 0.f;
  if (qt == 0) {
    uint4 o;
    o.x = (uint)f2b((a0 - bcorr) * inv) | ((uint)f2b((a1 - bcorr) * inv) << 16);
    o.y = (uint)f2b((a2 - bcorr) * inv) | ((uint)f2b((a3 - bcorr) * inv) << 16);
    o.z = (uint)f2b((a4 - bcorr) * inv) | ((uint)f2b((a5 - bcorr) * inv) << 16);
    o.w = (uint)f2b((a6 - bcorr) * inv) | ((uint)f2b((a7 - bcorr) * inv) << 16);
    *(uint4*)((char*)aggbf + (size_t)n * 256 + lb) = o;
  }
}

// ---------------- launch ----------------
extern "C" void kernel_launch(void* const* d_in, const int* in_sizes, int n_in,
                              void* d_out, int out_size, void* d_ws, size_t ws_size,
                              hipStream_t stream) {
  const float* h    = (const float*)d_in[0];
  const int*   src  = (const int*)d_in[1];
  const int*   dst  = (const int*)d_in[2];
  const float* Wq   = (const float*)d_in[3];
  const float* bq   = (const float*)d_in[4];
  const float* Wk   = (const float*)d_in[5];
  const float* bk   = (const float*)d_in[6];
  const float* Wm   = (const float*)d_in[7];
  const float* bm   = (const float*)d_in[8];
  const float* Wout = (const float*)d_in[9];
  const float* bout = (const float*)d_in[10];
  float* out = (float*)d_out;

  char* base = (char*)d_ws;
  ushort* Abf    = (ushort*)base;                         // NN*128 bf16
  char*   Zkm    = base + 25600000;                       // NN*256B int8
  char*   Zq8    = base + 51200000;                       // NN*128 int8
  ushort* Zbf    = (ushort*)(base + 25600000);            // fallback only
  ushort* aggbf  = (ushort*)(base + 102400000);           // NN*128 bf16
  int2*   stage  = (int2*)(base + 102400000);             // dead before aggbf written
  float*  scales = (float*)(base + 128000000);            // NN float2
  ushort* BTproj = (ushort*)(base + 128800000);
  ushort* BTout  = (ushort*)(base + 128898304);
  float*  bvec   = (float*)(base + 128931072);
  int* counts    = (int*)(base + 128933120);              // 400000
  int* stageCur  = (int*)(base + 129333120);              // 1024
  int* subCur    = (int*)(base + 129334144);              // 32768
  int* offsets   = (int*)(base + 129366912);              // 400128
  int* cursor    = (int*)(base + 129767040);              // 400000
  int* blockSums = (int*)(base + 130167040);              // 512
  int* csr_src   = (int*)(base + 130167552);              // NE*4 -> 136567552
  char* Zq8_fb   = base + 136567552;                      // fallback Zq8
  float* sqv     = (float*)(base + 149367552);            // NN f32 -> 149767552
  uint* stage2   = (uint*)(base + 149767552);             // -> 160253312

  int fast = (ws_size >= (size_t)160253312) ? 1 : 0;

  hipMemsetAsync(counts, 0, 433792, stream);   // counts + stageCur + subCur

  setup_stage<<<7288, 256, 0, stream>>>(h, Abf, Wq, Wk, Wm, bq, bk, bm, Wout,
                                        BTproj, BTout, bvec, src, dst, stageCur, stage);
  if (fast) {
    stage2_kernel<1><<<1024, 256, 0, stream>>>(stage, stageCur, subCur, stage2, counts);
  } else {
    hist_part<<<256, 256, 0, stream>>>(stage, stageCur, counts);
  }
  scan_a<<<98, 256, 0, stream>>>(counts, offsets, blockSums, NN);
  scan_b<<<1, 128, 0, stream>>>(blockSums, 98);
  scan_c<<<391, 256, 0, stream>>>(offsets, blockSums, cursor, NN);

  if (fast) {
    mfma_gemm<2><<<dim3(1563, 3), 256, 0, stream>>>(
        Abf, BTproj, bvec, nullptr, NN, 384, Zkm, Zq8, scales, sqv);
    scatter_final2<<<1024, 256, 0, stream>>>(stage2, subCur, cursor, csr_src);
    aggregate_q<<<25000, 256, 0, stream>>>(Zkm, scales, offsets, csr_src, aggbf, Zq8, sqv);
  } else {
    mfma_gemm<1><<<dim3(1563, 3), 256, 0, stream>>>(
        Abf, BTproj, bvec, Zbf, NN, 384, nullptr, nullptr, nullptr, nullptr);
    quant_kernel<<<6250, 256, 0, stream>>>(Zbf, (char*)base, (float2*)scales, Zq8_fb, sqv);
    scatter_final<<<1040, 256, 0, stream>>>(stage, stageCur, cursor, csr_src);
    aggregate_q<<<25000, 256, 0, stream>>>((char*)base, scales, offsets, csr_src,
                                           aggbf, Zq8_fb, sqv);
  }

  mfma_gemm<0><<<dim3(1563, 1), 256, 0, stream>>>(
      aggbf, BTout, bout, out, NN, 128, nullptr, nullptr, nullptr, nullptr);
}

// Round 18
// 202.453 us; speedup vs baseline: 1.8141x; 1.3772x over previous
//
#include <hip/hip_runtime.h>
#include <hip/hip_bf16.h>
#include <cstdint>
#include <cstddef>

#define NN 100000
#define NE 1600000
#define TAU 0.3f
#define REGION 400000   // stage-1 slots per dst-partition (8 partitions)
#define REGION2 5120    // stage-2 slots per (partition,sub-bucket)

typedef __attribute__((ext_vector_type(8))) short bf16x8;
typedef __attribute__((ext_vector_type(4))) float f32x4;

#if __has_builtin(__builtin_amdgcn_sdot4)
#define HAVE_SDOT4 1
#else
#define HAVE_SDOT4 0
#endif

static __device__ __forceinline__ float b2f_hi(uint w) {
  return __uint_as_float(w & 0xffff0000u);
}
static __device__ __forceinline__ float b2f_lo(uint w) {
  return __uint_as_float(w << 16);
}
static __device__ __forceinline__ ushort f2b(float f) {
  uint x = __float_as_uint(f);
  return (ushort)((x + 0x7fffu + ((x >> 16) & 1u)) >> 16);
}
static __device__ __forceinline__ float i8f(uint w, int k) {
  return (float)((int)(w << (24 - 8 * k)) >> 24);
}
static __device__ __forceinline__ int dot4i8(uint a, uint b, int c) {
#if HAVE_SDOT4
  return __builtin_amdgcn_sdot4((int)a, (int)b, c, false);
#else
  return c + (int)(char)(a) * (int)(char)(b)
           + (int)(char)(a >> 8) * (int)(char)(b >> 8)
           + (int)(char)(a >> 16) * (int)(char)(b >> 16)
           + (int)(char)(a >> 24) * (int)(char)(b >> 24);
#endif
}
#if __has_builtin(__builtin_amdgcn_cvt_f32_ubyte0)
#define UB0(w) __builtin_amdgcn_cvt_f32_ubyte0(w)
#define UB1(w) __builtin_amdgcn_cvt_f32_ubyte1(w)
#define UB2(w) __builtin_amdgcn_cvt_f32_ubyte2(w)
#define UB3(w) __builtin_amdgcn_cvt_f32_ubyte3(w)
#else
#define UB0(w) ((float)((w) & 0xffu))
#define UB1(w) ((float)(((w) >> 8) & 0xffu))
#define UB2(w) ((float)(((w) >> 16) & 0xffu))
#define UB3(w) ((float)(((w) >> 24) & 0xffu))
#endif

// ------- K1: conv_h (blocks 0..6249) + prep (6250..6505) + stage (6506..7287) -------
__global__ __launch_bounds__(256) void setup_stage(
    const float* __restrict__ h, ushort* __restrict__ A,
    const float* __restrict__ Wq, const float* __restrict__ Wk, const float* __restrict__ Wm,
    const float* __restrict__ bq, const float* __restrict__ bk, const float* __restrict__ bm,
    const float* __restrict__ Wout,
    ushort* __restrict__ BTproj, ushort* __restrict__ BTout, float* __restrict__ bvec,
    const int* __restrict__ src, const int* __restrict__ dst,
    int* __restrict__ stageCur, int2* __restrict__ stage) {
  int b = blockIdx.x;
  int t = threadIdx.x;
  if (b < 6250) {                       // h f32 -> bf16
    int i = b * 256 + t;
    const float4* hv = (const float4*)h + (size_t)i * 2;
    float4 a = hv[0], c = hv[1];
    uint4 o;
    o.x = (uint)f2b(a.x) | ((uint)f2b(a.y) << 16);
    o.y = (uint)f2b(a.z) | ((uint)f2b(a.w) << 16);
    o.z = (uint)f2b(c.x) | ((uint)f2b(c.y) << 16);
    o.w = (uint)f2b(c.z) | ((uint)f2b(c.w) << 16);
    ((uint4*)A)[i] = o;
    return;
  }
  if (b < 6506) {                       // weight prep, 65536 threads
    int id = (b - 6250) * 256 + t;
    if (id < 384 * 128) {
      int j = id >> 7, k = id & 127;
      int w = j >> 7, r = j & 127, hh = r >> 5, d = r & 31;
      const float* W = (w == 0) ? Wq : (w == 1) ? Wk : Wm;
      BTproj[id] = f2b(W[hh * 4096 + k * 32 + d]);
      if (k == 0) {
        const float* bb = (w == 0) ? bq : (w == 1) ? bk : bm;
        bvec[j] = bb[hh * 32 + d];
      }
    } else {
      int id2 = id - 384 * 128;                // 16384
      int c = id2 >> 7, k = id2 & 127;
      BTout[id2] = f2b(Wout[k * 128 + c]);
    }
    return;
  }
  // stage branch: 782 blocks x 2048 edges, bin by dst>>14 into fixed regions
  __shared__ int cnt[8];
  __shared__ int gbase[8];
  if (t < 8) cnt[t] = 0;
  __syncthreads();
  int e0 = (b - 6506) * 2048 + t;
  int d[8], s[8];
#pragma unroll
  for (int i = 0; i < 8; i++) {
    int e = e0 + i * 256;
    if (e < NE) {
      d[i] = dst[e];
      s[i] = src[e];
      atomicAdd(&cnt[d[i] >> 14], 1);
    } else {
      d[i] = -1;
    }
  }
  __syncthreads();
  if (t < 8) gbase[t] = atomicAdd(&stageCur[t * 16], cnt[t]);
  __syncthreads();
  if (t < 8) cnt[t] = 0;
  __syncthreads();
#pragma unroll
  for (int i = 0; i < 8; i++) {
    if (d[i] >= 0) {
      int p = d[i] >> 14;
      int slot = p * REGION + gbase[p] + atomicAdd(&cnt[p], 1);
      stage[slot] = make_int2(s[i], d[i]);
    }
  }
}

// ------- stage2: LDS-reorder binning into 64 sub-buckets (NO global atomics per edge
// except subCur reservations, ~50K total) -------
__global__ __launch_bounds__(256) void stage2_kernel(
    const int2* __restrict__ stage, const int* __restrict__ stageCur,
    int* __restrict__ subCur, uint* __restrict__ stage2) {
  int p = blockIdx.x & 7;
  int kb = blockIdx.x >> 3;              // 0..127 block within partition
  int t = threadIdx.x;
  int n = stageCur[p * 16];
  const int2* reg = stage + (size_t)p * REGION;
  __shared__ int cnt[64];
  __shared__ int pos[64];                // exclusive prefix (chunk-local)
  __shared__ int gb[64];                 // reserved global base per sub-bucket
  __shared__ int mvs;
  __shared__ uint buf[2048];

  for (int base = kb * 2048; base < n; base += 128 * 2048) {
    if (t < 64) cnt[t] = 0;
    __syncthreads();
    uint v[8]; int sb[8];
#pragma unroll
    for (int i = 0; i < 8; i++) {
      int idx = base + t + i * 256;
      if (idx < n) {
        int2 e = reg[idx];
        int dlow = e.y & 16383;
        sb[i] = dlow >> 8;               // sub-bucket 0..63
        v[i] = ((uint)e.x << 14) | (uint)dlow;
        atomicAdd(&cnt[sb[i]], 1);
      } else sb[i] = -1;
    }
    __syncthreads();
    if (t < 64) {                        // one wave: scan + reserve
      int c = cnt[t];
      int x = c;
#pragma unroll
      for (int d = 1; d < 64; d <<= 1) {
        int y = __shfl_up(x, d);
        if (t >= d) x += y;
      }
      pos[t] = x - c;
      gb[t] = c ? atomicAdd(&subCur[(p * 64 + t) * 16], c) : 0;
      if (t == 63) mvs = x;
      cnt[t] = 0;                        // reuse as placement cursor
    }
    __syncthreads();
#pragma unroll
    for (int i = 0; i < 8; i++) {
      if (sb[i] >= 0) {
        int loc = pos[sb[i]] + atomicAdd(&cnt[sb[i]], 1);
        buf[loc] = v[i];
      }
    }
    __syncthreads();
    int mv = mvs;
    for (int j = t; j < mv; j += 256) {  // contiguous runs per sub-bucket
      uint w = buf[j];
      int s2 = (int)((w & 16383u) >> 8);
      stage2[((size_t)(p * 64 + s2)) * REGION2 + gb[s2] + (j - pos[s2])] = w;
    }
    __syncthreads();
  }
}

// ------- hist_sb: per-sub-bucket exclusive histogram, PLAIN stores, no global atomics ----
__global__ __launch_bounds__(256) void hist_sb(
    const uint* __restrict__ stage2, const int* __restrict__ subCur,
    int* __restrict__ counts) {
  int g = blockIdx.x;                    // 0..511 = p*64 + sb
  int p = g >> 6;
  int n = subCur[g * 16];
  const uint* reg = stage2 + (size_t)g * REGION2;
  int dbase = p * 16384 + (g & 63) * 256;
  __shared__ int cnt[256];
  int t = threadIdx.x;
  cnt[t] = 0;
  __syncthreads();
  for (int i = t; i < n; i += 256) atomicAdd(&cnt[reg[i] & 255u], 1);
  __syncthreads();
  if (dbase + t < NN) counts[dbase + t] = cnt[t];
}

// ------- K2 (fallback): partition-local histogram from stage-1 -------
__global__ __launch_bounds__(256) void hist_part(
    const int2* __restrict__ stage, const int* __restrict__ stageCur,
    int* __restrict__ counts) {
  int p = blockIdx.x & 7;
  int k = blockIdx.x >> 3;              // 0..31
  int n = stageCur[p * 16];
  const int2* reg = stage + (size_t)p * REGION;
  for (int i = k * 256 + threadIdx.x; i < n; i += 32 * 256)
    atomicAdd(&counts[reg[i].y], 1);
}

// ---------------- MFMA GEMM: 64x128 tile, 48 KB LDS, 3 blocks/CU ----------------
// MODE 0: float out + relu. MODE 1: bf16 out. MODE 2: fused int8 quant epilogue
template <int MODE>
__global__ __launch_bounds__(256) void mfma_gemm(
    const ushort* __restrict__ A, const ushort* __restrict__ BT,
    const float* __restrict__ bias, void* __restrict__ Cp, int M, int ncols,
    char* __restrict__ Zkm, char* __restrict__ Zq8,
    float* __restrict__ scales, float* __restrict__ sqv) {
  __shared__ ushort As[64 * 128];    // 16 KB
  __shared__ ushort Bs[128 * 128];   // 32 KB

  int t = threadIdx.x;
  int rowBase = blockIdx.x * 64, colBase = blockIdx.y * 128;

#pragma unroll
  for (int i = 0; i < 4; i++) {      // A: 1024 chunks of 16B
    int flat = t + i * 256;
    int row = flat >> 4;
    int kb = (flat & 15) * 16;
    int soff = kb ^ ((row & 7) << 4);
    int ar = rowBase + row; if (ar >= M) ar = M - 1;
    __builtin_amdgcn_global_load_lds(
        (const __attribute__((address_space(1))) uint32_t*)((const char*)A + (size_t)ar * 256 + soff),
        (__attribute__((address_space(3))) uint32_t*)((char*)As + row * 256 + kb), 16, 0, 0);
  }
#pragma unroll
  for (int i = 0; i < 8; i++) {      // B: 2048 chunks of 16B
    int flat = t + i * 256;
    int row = flat >> 4;
    int kb = (flat & 15) * 16;
    int soff = kb ^ ((row & 7) << 4);
    __builtin_amdgcn_global_load_lds(
        (const __attribute__((address_space(1))) uint32_t*)((const char*)BT + (size_t)(colBase + row) * 256 + soff),
        (__attribute__((address_space(3))) uint32_t*)((char*)Bs + row * 256 + kb), 16, 0, 0);
  }
  __syncthreads();

  int wv = t >> 6, L = t & 63;
  int wrow = (wv >> 1) * 32, wcol = (wv & 1) * 64;
  int lr = L & 15;
  int lk = (L >> 4) * 16;
  f32x4 acc[2][4] = {};

#pragma unroll
  for (int ks = 0; ks < 4; ks++) {
    bf16x8 a[2], b[4];
#pragma unroll
    for (int i = 0; i < 2; i++) {
      int row = wrow + i * 16 + lr;
      a[i] = *(const bf16x8*)((const char*)As + row * 256 + ((ks * 64 + lk) ^ ((row & 7) << 4)));
    }
#pragma unroll
    for (int j = 0; j < 4; j++) {
      int col = wcol + j * 16 + lr;
      b[j] = *(const bf16x8*)((const char*)Bs + col * 256 + ((ks * 64 + lk) ^ ((col & 7) << 4)));
    }
#pragma unroll
    for (int i = 0; i < 2; i++)
#pragma unroll
      for (int j = 0; j < 4; j++)
        acc[i][j] = __builtin_amdgcn_mfma_f32_16x16x32_bf16(a[i], b[j], acc[i][j], 0, 0, 0);
  }

  int rquad = (L >> 4) * 4;

  if (MODE == 2) {
    __syncthreads();
    float* Cs = (float*)Bs;              // 64*128*4 = 32 KB
#pragma unroll
    for (int j = 0; j < 4; j++) {
      float bs = bias[colBase + wcol + j * 16 + lr];
#pragma unroll
      for (int i = 0; i < 2; i++) {
        int rl = wrow + i * 16 + rquad;
#pragma unroll
        for (int r = 0; r < 4; r++)
          Cs[(rl + r) * 128 + wcol + j * 16 + lr] = acc[i][j][r] + bs;
      }
    }
    __syncthreads();

    int row = t >> 2, part = t & 3;      // 4 threads per row, 32 cols each
    int row_g = rowBase + row;
    const float4* rp = (const float4*)(Cs + row * 128 + part * 32);
    float4 v[8];
    float vmax = 0.f;
#pragma unroll
    for (int i = 0; i < 8; i++) {
      v[i] = rp[i];
      vmax = fmaxf(vmax, fmaxf(fmaxf(fabsf(v[i].x), fabsf(v[i].y)),
                               fmaxf(fabsf(v[i].z), fabsf(v[i].w))));
    }
    vmax = fmaxf(vmax, __shfl_xor(vmax, 1));
    vmax = fmaxf(vmax, __shfl_xor(vmax, 2));
    vmax = fmaxf(vmax, 1e-20f);
    float qs = 127.0f / vmax;
    int w = blockIdx.y;
    if (row_g < M) {
      if (w == 0) {
        uint b8[8];
#pragma unroll
        for (int i = 0; i < 8; i++)
          b8[i] = (uint)(__float2int_rn(v[i].x * qs) & 0xff)
                | ((uint)(__float2int_rn(v[i].y * qs) & 0xff) << 8)
                | ((uint)(__float2int_rn(v[i].z * qs) & 0xff) << 16)
                | ((uint)(__float2int_rn(v[i].w * qs) & 0xff) << 24);
        uint4* dst4 = (uint4*)(Zq8 + (size_t)row_g * 128 + part * 32);
        dst4[0] = make_uint4(b8[0], b8[1], b8[2], b8[3]);
        dst4[1] = make_uint4(b8[4], b8[5], b8[6], b8[7]);
        if (part == 0) sqv[row_g] = vmax * (1.0f / 127.0f);
      } else {
#pragma unroll
        for (int u = 0; u < 2; u++) {
#pragma unroll
          for (int hh = 0; hh < 2; hh++) {
            int un = part * 4 + u * 2 + hh;
            float4 va = v[u * 4 + hh * 2], vb = v[u * 4 + hh * 2 + 1];
            uint lo, hi;
            if (w == 1) {
              lo = (uint)(__float2int_rn(va.x * qs) & 0xff)
                 | ((uint)(__float2int_rn(va.y * qs) & 0xff) << 8)
                 | ((uint)(__float2int_rn(va.z * qs) & 0xff) << 16)
                 | ((uint)(__float2int_rn(va.w * qs) & 0xff) << 24);
              hi = (uint)(__float2int_rn(vb.x * qs) & 0xff)
                 | ((uint)(__float2int_rn(vb.y * qs) & 0xff) << 8)
                 | ((uint)(__float2int_rn(vb.z * qs) & 0xff) << 16)
                 | ((uint)(__float2int_rn(vb.w * qs) & 0xff) << 24);
            } else {
              lo = (uint)((__float2int_rn(va.x * qs) + 128) & 0xff)
                 | ((uint)((__float2int_rn(va.y * qs) + 128) & 0xff) << 8)
                 | ((uint)((__float2int_rn(va.z * qs) + 128) & 0xff) << 16)
                 | ((uint)((__float2int_rn(va.w * qs) + 128) & 0xff) << 24);
              hi = (uint)((__float2int_rn(vb.x * qs) + 128) & 0xff)
                 | ((uint)((__float2int_rn(vb.y * qs) + 128) & 0xff) << 8)
                 | ((uint)((__float2int_rn(vb.z * qs) + 128) & 0xff) << 16)
                 | ((uint)((__float2int_rn(vb.w * qs) + 128) & 0xff) << 24);
            }
            uint2* d2 = (uint2*)(Zkm + (size_t)row_g * 256 + un * 16 + (w == 2 ? 8 : 0));
            *d2 = make_uint2(lo, hi);
          }
        }
        if (part == 0) scales[row_g * 2 + (w - 1)] = vmax * (1.0f / 127.0f);
      }
    }
    return;
  }

#pragma unroll
  for (int j = 0; j < 4; j++) {
    int col = colBase + wcol + j * 16 + lr;
    float bs = bias[col];
#pragma unroll
    for (int i = 0; i < 2; i++) {
      int row0 = rowBase + wrow + i * 16 + rquad;
#pragma unroll
      for (int r = 0; r < 4; r++) {
        int row = row0 + r;
        if (row >= M) continue;
        float vv = acc[i][j][r] + bs;
        if (MODE == 0) {
          vv = fmaxf(vv, 0.f);
          ((float*)Cp)[(size_t)row * ncols + col] = vv;
        } else {
          ((ushort*)Cp)[(size_t)row * ncols + col] = f2b(vv);
        }
      }
    }
  }
}

// ---------------- CSR scans ----------------
__global__ __launch_bounds__(256) void scan_a(const int* __restrict__ counts,
                                              int* __restrict__ offsets,
                                              int* __restrict__ blockSums, int n) {
  __shared__ int lds[256];
  int b = blockIdx.x, t = threadIdx.x;
  int base = b * 1024 + t * 4;
  int4 v = make_int4(0, 0, 0, 0);
  if (base < n) v = *(const int4*)&counts[base];
  int s1 = v.x + v.y, s2 = s1 + v.z, s3 = s2 + v.w;
  lds[t] = s3;
  __syncthreads();
  for (int dd = 1; dd < 256; dd <<= 1) {
    int x = (t >= dd) ? lds[t - dd] : 0;
    __syncthreads();
    lds[t] += x;
    __syncthreads();
  }
  int excl = (t > 0) ? lds[t - 1] : 0;
  if (base < n) {
    int4 o = make_int4(excl, excl + v.x, excl + s1, excl + s2);
    *(int4*)&offsets[base] = o;
  }
  if (t == 255) blockSums[b] = lds[255];
}

__global__ __launch_bounds__(128) void scan_b(int* __restrict__ blockSums, int nb) {
  __shared__ int lds[128];
  int t = threadIdx.x;
  lds[t] = (t < nb) ? blockSums[t] : 0;
  __syncthreads();
  for (int dd = 1; dd < 128; dd <<= 1) {
    int x = (t >= dd) ? lds[t - dd] : 0;
    __syncthreads();
    lds[t] += x;
    __syncthreads();
  }
  if (t < nb) blockSums[t] = (t > 0) ? lds[t - 1] : 0;
}

__global__ __launch_bounds__(256) void scan_c(int* __restrict__ offsets,
                                              const int* __restrict__ blockSums,
                                              int* __restrict__ cursor, int n) {
  int i = blockIdx.x * 256 + threadIdx.x;
  if (i < n) {
    int v = offsets[i] + blockSums[i >> 10];
    offsets[i] = v;
    cursor[i] = v;
  }
  if (i == 0) offsets[n] = NE;
}

// ------- quant (fallback only): Zbf -> int8 (biased m) -------
__global__ __launch_bounds__(256) void quant_kernel(
    const ushort* __restrict__ Zbf, char* __restrict__ Zkm, float2* __restrict__ scales,
    char* __restrict__ Zq8, float* __restrict__ sqv) {
  int g = blockIdx.x * 256 + threadIdx.x;
  int row = g >> 4, u = g & 15;
  const ushort* zr = Zbf + (size_t)row * 384;
  uint4 kk = *(const uint4*)(zr + 128 + u * 8);
  uint4 mm = *(const uint4*)(zr + 256 + u * 8);
  uint4 qq = *(const uint4*)(zr + u * 8);
  float kf[8] = {b2f_lo(kk.x), b2f_hi(kk.x), b2f_lo(kk.y), b2f_hi(kk.y),
                 b2f_lo(kk.z), b2f_hi(kk.z), b2f_lo(kk.w), b2f_hi(kk.w)};
  float mf[8] = {b2f_lo(mm.x), b2f_hi(mm.x), b2f_lo(mm.y), b2f_hi(mm.y),
                 b2f_lo(mm.z), b2f_hi(mm.z), b2f_lo(mm.w), b2f_hi(mm.w)};
  float qf[8] = {b2f_lo(qq.x), b2f_hi(qq.x), b2f_lo(qq.y), b2f_hi(qq.y),
                 b2f_lo(qq.z), b2f_hi(qq.z), b2f_lo(qq.w), b2f_hi(qq.w)};
  float mk = 0.f, mx = 0.f, mqv = 0.f;
#pragma unroll
  for (int i = 0; i < 8; i++) {
    mk = fmaxf(mk, fabsf(kf[i]));
    mx = fmaxf(mx, fabsf(mf[i]));
    mqv = fmaxf(mqv, fabsf(qf[i]));
  }
#pragma unroll
  for (int dd = 1; dd < 16; dd <<= 1) {
    mk = fmaxf(mk, __shfl_xor(mk, dd));
    mx = fmaxf(mx, __shfl_xor(mx, dd));
    mqv = fmaxf(mqv, __shfl_xor(mqv, dd));
  }
  mk = fmaxf(mk, 1e-20f); mx = fmaxf(mx, 1e-20f); mqv = fmaxf(mqv, 1e-20f);
  float qk = 127.0f / mk, qm = 127.0f / mx;
  int q[16];
#pragma unroll
  for (int i = 0; i < 8; i++) {
    q[i] = __float2int_rn(kf[i] * qk) & 0xff;
    q[8 + i] = (__float2int_rn(mf[i] * qm) + 128) & 0xff;
  }
  uint4 o;
  o.x = (uint)(q[0] | (q[1] << 8) | (q[2] << 16) | (q[3] << 24));
  o.y = (uint)(q[4] | (q[5] << 8) | (q[6] << 16) | (q[7] << 24));
  o.z = (uint)(q[8] | (q[9] << 8) | (q[10] << 16) | (q[11] << 24));
  o.w = (uint)(q[12] | (q[13] << 8) | (q[14] << 16) | (q[15] << 24));
  *(uint4*)(Zkm + (size_t)row * 256 + u * 16) = o;
  if (u == 0) scales[row] = make_float2(mk * (1.0f / 127.0f), mx * (1.0f / 127.0f));
  float qsv = 127.0f / mqv;
  int r[8];
#pragma unroll
  for (int i = 0; i < 8; i++) r[i] = __float2int_rn(qf[i] * qsv) & 0xff;
  uint2 oq;
  oq.x = (uint)(r[0] | (r[1] << 8) | (r[2] << 16) | (r[3] << 24));
  oq.y = (uint)(r[4] | (r[5] << 8) | (r[6] << 16) | (r[7] << 24));
  *(uint2*)(Zq8 + (size_t)row * 128 + u * 8) = oq;
  if (u == 0) sqv[row] = mqv * (1.0f / 127.0f);
}

// ------- scatter_sb: per-sub-bucket LDS reorder -> contiguous CSR flush, NO atomics ----
__global__ __launch_bounds__(256) void scatter_sb(
    const uint* __restrict__ stage2, const int* __restrict__ subCur,
    const int* __restrict__ offsets, int* __restrict__ csr_src) {
  int g = blockIdx.x;                    // 0..511
  int p = g >> 6;
  int n = subCur[g * 16];
  if (n == 0) return;
  const uint* reg = stage2 + (size_t)g * REGION2;
  int dbase = p * 16384 + (g & 63) * 256;
  __shared__ int offs[257];
  __shared__ int cur[256];
  __shared__ uint buf[REGION2];          // 20 KB
  int t = threadIdx.x;
  for (int i = t; i < 257; i += 256) {
    int d = dbase + i;
    offs[i] = offsets[d > NN ? NN : d];
  }
  __syncthreads();
  int base0 = offs[0];
  cur[t] = offs[t] - base0;
  __syncthreads();
  for (int i = t; i < n; i += 256) {
    uint v = reg[i];
    int ld = (int)(v & 255u);
    int pos = atomicAdd(&cur[ld], 1);    // LDS atomic only
    buf[pos] = v >> 14;                  // src index
  }
  __syncthreads();
  for (int j = t; j < n; j += 256)       // fully coalesced contiguous flush
    csr_src[base0 + j] = (int)buf[j];
}

// ------- scatter (fallback) -------
__global__ __launch_bounds__(256) void scatter_final(
    const int2* __restrict__ stage, const int* __restrict__ stageCur,
    int* __restrict__ cursor, int* __restrict__ csr_src) {
  int p = blockIdx.x & 7;
  int k = blockIdx.x >> 3;
  int n = stageCur[p * 16];
  const int2* reg = stage + (size_t)p * REGION;
  for (int i = k * 256 + threadIdx.x; i < n; i += 130 * 256) {
    int2 e = reg[i];
    int pos = atomicAdd(&cursor[e.y], 1);
    csr_src[pos] = e.x;
  }
}

// ---------------- fused attention + aggregation, int8 gathers ----------------
__global__ __launch_bounds__(256) void aggregate_q(
    const char* __restrict__ Zkm, const float* __restrict__ scales,
    const int* __restrict__ offsets, const int* __restrict__ csr_src,
    ushort* __restrict__ aggbf,
    const char* __restrict__ Zq8, const float* __restrict__ sqv) {
  int wv = threadIdx.x >> 6, L = threadIdx.x & 63;
  int n = blockIdx.x * 4 + wv;
  if (n >= NN) return;
  int qt = L >> 4, l = L & 15;
  int lb = l << 4;                         // byte offset within 256B row

  uint2 q8 = *(const uint2*)(Zq8 + (size_t)n * 128 + l * 8);
  float tq = TAU * sqv[n];

  int start = offsets[n], end = offsets[n + 1];
  float den = 0.f, swm = 0.f;
  float a0 = 0.f, a1 = 0.f, a2 = 0.f, a3 = 0.f, a4 = 0.f, a5 = 0.f, a6 = 0.f, a7 = 0.f;
  int p = start;

  for (; p + 8 <= end; p += 8) {
    int s0 = csr_src[p + qt];
    int s1 = csr_src[p + 4 + qt];
    uint4 v0 = *(const uint4*)(Zkm + ((size_t)s0 << 8) + lb);
    uint4 v1 = *(const uint4*)(Zkm + ((size_t)s1 << 8) + lb);
    float2 sc0 = *(const float2*)(scales + s0 * 2);
    float2 sc1 = *(const float2*)(scales + s1 * 2);

    int p0 = dot4i8(v0.x, q8.x, 0); p0 = dot4i8(v0.y, q8.y, p0);
    int p1 = dot4i8(v1.x, q8.x, 0); p1 = dot4i8(v1.y, q8.y, p1);
    p0 += __shfl_xor(p0, 1); p1 += __shfl_xor(p1, 1);
    p0 += __shfl_xor(p0, 2); p1 += __shfl_xor(p1, 2);
    float w0 = __expf(tq * sc0.x * (float)p0);
    float w1 = __expf(tq * sc1.x * (float)p1);
    den += w0 + w1;
    float wm0 = w0 * sc0.y, wm1 = w1 * sc1.y;
    swm += wm0 + wm1;

    a0 = fmaf(UB0(v0.z), wm0, a0); a1 = fmaf(UB1(v0.z), wm0, a1);
    a2 = fmaf(UB2(v0.z), wm0, a2); a3 = fmaf(UB3(v0.z), wm0, a3);
    a4 = fmaf(UB0(v0.w), wm0, a4); a5 = fmaf(UB1(v0.w), wm0, a5);
    a6 = fmaf(UB2(v0.w), wm0, a6); a7 = fmaf(UB3(v0.w), wm0, a7);
    a0 = fmaf(UB0(v1.z), wm1, a0); a1 = fmaf(UB1(v1.z), wm1, a1);
    a2 = fmaf(UB2(v1.z), wm1, a2); a3 = fmaf(UB3(v1.z), wm1, a3);
    a4 = fmaf(UB0(v1.w), wm1, a4); a5 = fmaf(UB1(v1.w), wm1, a5);
    a6 = fmaf(UB2(v1.w), wm1, a6); a7 = fmaf(UB3(v1.w), wm1, a7);
  }

  for (; p < end; p += 4) {               // masked tail, whole wave stays
    int e = p + qt;
    int idx = (e < end) ? e : (end - 1);
    int s0 = csr_src[idx];
    uint4 v = *(const uint4*)(Zkm + ((size_t)s0 << 8) + lb);
    float2 sc = *(const float2*)(scales + s0 * 2);
    int p0 = dot4i8(v.x, q8.x, 0); p0 = dot4i8(v.y, q8.y, p0);
    p0 += __shfl_xor(p0, 1);
    p0 += __shfl_xor(p0, 2);
    float w = (e < end) ? __expf(tq * sc.x * (float)p0) : 0.f;
    den += w;
    float wm = w * sc.y;
    swm += wm;
    a0 = fmaf(UB0(v.z), wm, a0); a1 = fmaf(UB1(v.z), wm, a1);
    a2 = fmaf(UB2(v.z), wm, a2); a3 = fmaf(UB3(v.z), wm, a3);
    a4 = fmaf(UB0(v.w), wm, a4); a5 = fmaf(UB1(v.w), wm, a5);
    a6 = fmaf(UB2(v.w), wm, a6); a7 = fmaf(UB3(v.w), wm, a7);
  }

  den += __shfl_xor(den, 16); den += __shfl_xor(den, 32);
  swm += __shfl_xor(swm, 16); swm += __shfl_xor(swm, 32);
  a0 += __shfl_xor(a0, 16); a0 += __shfl_xor(a0, 32);
  a1 += __shfl_xor(a1, 16); a1 += __shfl_xor(a1, 32);
  a2 += __shfl_xor(a2, 16); a2 += __shfl_xor(a2, 32);
  a3 += __shfl_xor(a3, 16); a3 += __shfl_xor(a3, 32);
  a4 += __shfl_xor(a4, 16); a4 += __shfl_xor(a4, 32);
  a5 += __shfl_xor(a5, 16); a5 += __shfl_xor(a5, 32);
  a6 += __shfl_xor(a6, 16); a6 += __shfl_xor(a6, 32);
  a7 += __shfl_xor(a7, 16); a7 += __shfl_xor(a7, 32);

  float bcorr = 128.f * swm;
  float inv = (den > 0.f) ? 1.0f / den : 0.f;
  if (qt == 0) {
    uint4 o;
    o.x = (uint)f2b((a0 - bcorr) * inv) | ((uint)f2b((a1 - bcorr) * inv) << 16);
    o.y = (uint)f2b((a2 - bcorr) * inv) | ((uint)f2b((a3 - bcorr) * inv) << 16);
    o.z = (uint)f2b((a4 - bcorr) * inv) | ((uint)f2b((a5 - bcorr) * inv) << 16);
    o.w = (uint)f2b((a6 - bcorr) * inv) | ((uint)f2b((a7 - bcorr) * inv) << 16);
    *(uint4*)((char*)aggbf + (size_t)n * 256 + lb) = o;
  }
}

// ---------------- launch ----------------
extern "C" void kernel_launch(void* const* d_in, const int* in_sizes, int n_in,
                              void* d_out, int out_size, void* d_ws, size_t ws_size,
                              hipStream_t stream) {
  const float* h    = (const float*)d_in[0];
  const int*   src  = (const int*)d_in[1];
  const int*   dst  = (const int*)d_in[2];
  const float* Wq   = (const float*)d_in[3];
  const float* bq   = (const float*)d_in[4];
  const float* Wk   = (const float*)d_in[5];
  const float* bk   = (const float*)d_in[6];
  const float* Wm   = (const float*)d_in[7];
  const float* bm   = (const float*)d_in[8];
  const float* Wout = (const float*)d_in[9];
  const float* bout = (const float*)d_in[10];
  float* out = (float*)d_out;

  char* base = (char*)d_ws;
  ushort* Abf    = (ushort*)base;                         // NN*128 bf16
  char*   Zkm    = base + 25600000;                       // NN*256B int8
  char*   Zq8    = base + 51200000;                       // NN*128 int8
  ushort* Zbf    = (ushort*)(base + 25600000);            // fallback only
  ushort* aggbf  = (ushort*)(base + 102400000);           // NN*128 bf16
  int2*   stage  = (int2*)(base + 102400000);             // dead before aggbf written
  float*  scales = (float*)(base + 128000000);            // NN float2
  ushort* BTproj = (ushort*)(base + 128800000);
  ushort* BTout  = (ushort*)(base + 128898304);
  float*  bvec   = (float*)(base + 128931072);
  int* counts    = (int*)(base + 128933120);              // 400000
  int* stageCur  = (int*)(base + 129333120);              // 1024
  int* subCur    = (int*)(base + 129334144);              // 32768
  int* offsets   = (int*)(base + 129366912);              // 400128
  int* cursor    = (int*)(base + 129767040);              // 400000
  int* blockSums = (int*)(base + 130167040);              // 512
  int* csr_src   = (int*)(base + 130167552);              // NE*4 -> 136567552
  char* Zq8_fb   = base + 136567552;                      // fallback Zq8
  float* sqv     = (float*)(base + 149367552);            // NN f32 -> 149767552
  uint* stage2   = (uint*)(base + 149767552);             // -> 160253312

  int fast = (ws_size >= (size_t)160253312) ? 1 : 0;

  hipMemsetAsync(counts, 0, 433792, stream);   // counts + stageCur + subCur

  setup_stage<<<7288, 256, 0, stream>>>(h, Abf, Wq, Wk, Wm, bq, bk, bm, Wout,
                                        BTproj, BTout, bvec, src, dst, stageCur, stage);
  if (fast) {
    stage2_kernel<<<1024, 256, 0, stream>>>(stage, stageCur, subCur, stage2);
    hist_sb<<<512, 256, 0, stream>>>(stage2, subCur, counts);
  } else {
    hist_part<<<256, 256, 0, stream>>>(stage, stageCur, counts);
  }
  scan_a<<<98, 256, 0, stream>>>(counts, offsets, blockSums, NN);
  scan_b<<<1, 128, 0, stream>>>(blockSums, 98);
  scan_c<<<391, 256, 0, stream>>>(offsets, blockSums, cursor, NN);

  if (fast) {
    mfma_gemm<2><<<dim3(1563, 3), 256, 0, stream>>>(
        Abf, BTproj, bvec, nullptr, NN, 384, Zkm, Zq8, scales, sqv);
    scatter_sb<<<512, 256, 0, stream>>>(stage2, subCur, offsets, csr_src);
    aggregate_q<<<25000, 256, 0, stream>>>(Zkm, scales, offsets, csr_src, aggbf, Zq8, sqv);
  } else {
    mfma_gemm<1><<<dim3(1563, 3), 256, 0, stream>>>(
        Abf, BTproj, bvec, Zbf, NN, 384, nullptr, nullptr, nullptr, nullptr);
    quant_kernel<<<6250, 256, 0, stream>>>(Zbf, (char*)base, (float2*)scales, Zq8_fb, sqv);
    scatter_final<<<1040, 256, 0, stream>>>(stage, stageCur, cursor, csr_src);
    aggregate_q<<<25000, 256, 0, stream>>>((char*)base, scales, offsets, csr_src,
                                           aggbf, Zq8_fb, sqv);
  }

  mfma_gemm<0><<<dim3(1563, 1), 256, 0, stream>>>(
      aggbf, BTout, bout, out, NN, 128, nullptr, nullptr, nullptr, nullptr);
}

// Round 19
// 197.185 us; speedup vs baseline: 1.8625x; 1.0267x over previous
//
#include <hip/hip_runtime.h>
#include <hip/hip_bf16.h>
#include <cstdint>
#include <cstddef>

#define NN 100000
#define NE 1600000
#define TAU 0.3f
#define REGION 400000   // stage-1 slots per dst-partition (8 partitions)
#define REGION2 5120    // stage-2 slots per (partition,sub-bucket)

typedef __attribute__((ext_vector_type(8))) short bf16x8;
typedef __attribute__((ext_vector_type(4))) float f32x4;

#if __has_builtin(__builtin_amdgcn_sdot4)
#define HAVE_SDOT4 1
#else
#define HAVE_SDOT4 0
#endif

static __device__ __forceinline__ float b2f_hi(uint w) {
  return __uint_as_float(w & 0xffff0000u);
}
static __device__ __forceinline__ float b2f_lo(uint w) {
  return __uint_as_float(w << 16);
}
static __device__ __forceinline__ ushort f2b(float f) {
  uint x = __float_as_uint(f);
  return (ushort)((x + 0x7fffu + ((x >> 16) & 1u)) >> 16);
}
static __device__ __forceinline__ float i8f(uint w, int k) {
  return (float)((int)(w << (24 - 8 * k)) >> 24);
}
static __device__ __forceinline__ int dot4i8(uint a, uint b, int c) {
#if HAVE_SDOT4
  return __builtin_amdgcn_sdot4((int)a, (int)b, c, false);
#else
  return c + (int)(char)(a) * (int)(char)(b)
           + (int)(char)(a >> 8) * (int)(char)(b >> 8)
           + (int)(char)(a >> 16) * (int)(char)(b >> 16)
           + (int)(char)(a >> 24) * (int)(char)(b >> 24);
#endif
}
#if __has_builtin(__builtin_amdgcn_cvt_f32_ubyte0)
#define UB0(w) __builtin_amdgcn_cvt_f32_ubyte0(w)
#define UB1(w) __builtin_amdgcn_cvt_f32_ubyte1(w)
#define UB2(w) __builtin_amdgcn_cvt_f32_ubyte2(w)
#define UB3(w) __builtin_amdgcn_cvt_f32_ubyte3(w)
#else
#define UB0(w) ((float)((w) & 0xffu))
#define UB1(w) ((float)(((w) >> 8) & 0xffu))
#define UB2(w) ((float)(((w) >> 16) & 0xffu))
#define UB3(w) ((float)(((w) >> 24) & 0xffu))
#endif

// ------- K1: conv_h (blocks 0..6249) + prep (6250..6505) + stage (6506..7287) -------
__global__ __launch_bounds__(256) void setup_stage(
    const float* __restrict__ h, ushort* __restrict__ A,
    const float* __restrict__ Wq, const float* __restrict__ Wk, const float* __restrict__ Wm,
    const float* __restrict__ bq, const float* __restrict__ bk, const float* __restrict__ bm,
    const float* __restrict__ Wout,
    ushort* __restrict__ BTproj, ushort* __restrict__ BTout, float* __restrict__ bvec,
    const int* __restrict__ src, const int* __restrict__ dst,
    int* __restrict__ stageCur, int2* __restrict__ stage) {
  int b = blockIdx.x;
  int t = threadIdx.x;
  if (b < 6250) {                       // h f32 -> bf16
    int i = b * 256 + t;
    const float4* hv = (const float4*)h + (size_t)i * 2;
    float4 a = hv[0], c = hv[1];
    uint4 o;
    o.x = (uint)f2b(a.x) | ((uint)f2b(a.y) << 16);
    o.y = (uint)f2b(a.z) | ((uint)f2b(a.w) << 16);
    o.z = (uint)f2b(c.x) | ((uint)f2b(c.y) << 16);
    o.w = (uint)f2b(c.z) | ((uint)f2b(c.w) << 16);
    ((uint4*)A)[i] = o;
    return;
  }
  if (b < 6506) {                       // weight prep, 65536 threads
    int id = (b - 6250) * 256 + t;
    if (id < 384 * 128) {
      int j = id >> 7, k = id & 127;
      int w = j >> 7, r = j & 127, hh = r >> 5, d = r & 31;
      const float* W = (w == 0) ? Wq : (w == 1) ? Wk : Wm;
      BTproj[id] = f2b(W[hh * 4096 + k * 32 + d]);
      if (k == 0) {
        const float* bb = (w == 0) ? bq : (w == 1) ? bk : bm;
        bvec[j] = bb[hh * 32 + d];
      }
    } else {
      int id2 = id - 384 * 128;                // 16384
      int c = id2 >> 7, k = id2 & 127;
      BTout[id2] = f2b(Wout[k * 128 + c]);
    }
    return;
  }
  // stage branch: 782 blocks x 2048 edges, bin by dst>>14 into fixed regions
  __shared__ int cnt[8];
  __shared__ int gbase[8];
  if (t < 8) cnt[t] = 0;
  __syncthreads();
  int e0 = (b - 6506) * 2048 + t;
  int d[8], s[8];
#pragma unroll
  for (int i = 0; i < 8; i++) {
    int e = e0 + i * 256;
    if (e < NE) {
      d[i] = dst[e];
      s[i] = src[e];
      atomicAdd(&cnt[d[i] >> 14], 1);
    } else {
      d[i] = -1;
    }
  }
  __syncthreads();
  if (t < 8) gbase[t] = atomicAdd(&stageCur[t * 16], cnt[t]);
  __syncthreads();
  if (t < 8) cnt[t] = 0;
  __syncthreads();
#pragma unroll
  for (int i = 0; i < 8; i++) {
    if (d[i] >= 0) {
      int p = d[i] >> 14;
      int slot = p * REGION + gbase[p] + atomicAdd(&cnt[p], 1);
      stage[slot] = make_int2(s[i], d[i]);
    }
  }
}

// ------- fused: MODE2 quant-GEMM (blocks 0..4688) + stage2 binning (4689..5712) -------
__global__ __launch_bounds__(256) void gemm2_stage2(
    const ushort* __restrict__ A, const ushort* __restrict__ BT,
    const float* __restrict__ bias,
    char* __restrict__ Zkm, char* __restrict__ Zq8,
    float* __restrict__ scales, float* __restrict__ sqv, int M,
    const int2* __restrict__ stage, const int* __restrict__ stageCur,
    int* __restrict__ subCur, uint* __restrict__ stage2) {
  int t = threadIdx.x;
  int b = blockIdx.x;

  if (b >= 4689) {
    // ---------------- stage2 branch ----------------
    int idx = b - 4689;
    int p = idx & 7;
    int kb = idx >> 3;                   // 0..127 block within partition
    int n = stageCur[p * 16];
    const int2* reg = stage + (size_t)p * REGION;
    __shared__ int cnt[64];
    __shared__ int pos[64];
    __shared__ int gb[64];
    __shared__ int mvs;
    __shared__ uint buf[2048];

    for (int base = kb * 2048; base < n; base += 128 * 2048) {
      if (t < 64) cnt[t] = 0;
      __syncthreads();
      uint v[8]; int sb[8];
#pragma unroll
      for (int i = 0; i < 8; i++) {
        int idx2 = base + t + i * 256;
        if (idx2 < n) {
          int2 e = reg[idx2];
          int dlow = e.y & 16383;
          sb[i] = dlow >> 8;
          v[i] = ((uint)e.x << 14) | (uint)dlow;
          atomicAdd(&cnt[sb[i]], 1);
        } else sb[i] = -1;
      }
      __syncthreads();
      if (t < 64) {
        int c = cnt[t];
        int x = c;
#pragma unroll
        for (int d = 1; d < 64; d <<= 1) {
          int y = __shfl_up(x, d);
          if (t >= d) x += y;
        }
        pos[t] = x - c;
        gb[t] = c ? atomicAdd(&subCur[(p * 64 + t) * 16], c) : 0;
        if (t == 63) mvs = x;
        cnt[t] = 0;
      }
      __syncthreads();
#pragma unroll
      for (int i = 0; i < 8; i++) {
        if (sb[i] >= 0) {
          int loc = pos[sb[i]] + atomicAdd(&cnt[sb[i]], 1);
          buf[loc] = v[i];
        }
      }
      __syncthreads();
      int mv = mvs;
      for (int j = t; j < mv; j += 256) {
        uint w = buf[j];
        int s2 = (int)((w & 16383u) >> 8);
        stage2[((size_t)(p * 64 + s2)) * REGION2 + gb[s2] + (j - pos[s2])] = w;
      }
      __syncthreads();
    }
    return;
  }

  // ---------------- MODE2 GEMM branch ----------------
  __shared__ ushort As[64 * 128];    // 16 KB
  __shared__ ushort Bs[128 * 128];   // 32 KB
  int rowBase = (b % 1563) * 64;
  int w = b / 1563;                    // 0=zq 1=zk 2=zm
  int colBase = w * 128;

#pragma unroll
  for (int i = 0; i < 4; i++) {
    int flat = t + i * 256;
    int row = flat >> 4;
    int kb = (flat & 15) * 16;
    int soff = kb ^ ((row & 7) << 4);
    int ar = rowBase + row; if (ar >= M) ar = M - 1;
    __builtin_amdgcn_global_load_lds(
        (const __attribute__((address_space(1))) uint32_t*)((const char*)A + (size_t)ar * 256 + soff),
        (__attribute__((address_space(3))) uint32_t*)((char*)As + row * 256 + kb), 16, 0, 0);
  }
#pragma unroll
  for (int i = 0; i < 8; i++) {
    int flat = t + i * 256;
    int row = flat >> 4;
    int kb = (flat & 15) * 16;
    int soff = kb ^ ((row & 7) << 4);
    __builtin_amdgcn_global_load_lds(
        (const __attribute__((address_space(1))) uint32_t*)((const char*)BT + (size_t)(colBase + row) * 256 + soff),
        (__attribute__((address_space(3))) uint32_t*)((char*)Bs + row * 256 + kb), 16, 0, 0);
  }
  __syncthreads();

  int wv = t >> 6, L = t & 63;
  int wrow = (wv >> 1) * 32, wcol = (wv & 1) * 64;
  int lr = L & 15;
  int lk = (L >> 4) * 16;
  f32x4 acc[2][4] = {};

#pragma unroll
  for (int ks = 0; ks < 4; ks++) {
    bf16x8 a[2], bb[4];
#pragma unroll
    for (int i = 0; i < 2; i++) {
      int row = wrow + i * 16 + lr;
      a[i] = *(const bf16x8*)((const char*)As + row * 256 + ((ks * 64 + lk) ^ ((row & 7) << 4)));
    }
#pragma unroll
    for (int j = 0; j < 4; j++) {
      int col = wcol + j * 16 + lr;
      bb[j] = *(const bf16x8*)((const char*)Bs + col * 256 + ((ks * 64 + lk) ^ ((col & 7) << 4)));
    }
#pragma unroll
    for (int i = 0; i < 2; i++)
#pragma unroll
      for (int j = 0; j < 4; j++)
        acc[i][j] = __builtin_amdgcn_mfma_f32_16x16x32_bf16(a[i], bb[j], acc[i][j], 0, 0, 0);
  }

  int rquad = (L >> 4) * 4;
  __syncthreads();
  float* Cs = (float*)Bs;              // 32 KB
#pragma unroll
  for (int j = 0; j < 4; j++) {
    float bs = bias[colBase + wcol + j * 16 + lr];
#pragma unroll
    for (int i = 0; i < 2; i++) {
      int rl = wrow + i * 16 + rquad;
#pragma unroll
      for (int r = 0; r < 4; r++)
        Cs[(rl + r) * 128 + wcol + j * 16 + lr] = acc[i][j][r] + bs;
    }
  }
  __syncthreads();

  int row = t >> 2, part = t & 3;
  int row_g = rowBase + row;
  const float4* rp = (const float4*)(Cs + row * 128 + part * 32);
  float4 v[8];
  float vmax = 0.f;
#pragma unroll
  for (int i = 0; i < 8; i++) {
    v[i] = rp[i];
    vmax = fmaxf(vmax, fmaxf(fmaxf(fabsf(v[i].x), fabsf(v[i].y)),
                             fmaxf(fabsf(v[i].z), fabsf(v[i].w))));
  }
  vmax = fmaxf(vmax, __shfl_xor(vmax, 1));
  vmax = fmaxf(vmax, __shfl_xor(vmax, 2));
  vmax = fmaxf(vmax, 1e-20f);
  float qs = 127.0f / vmax;
  if (row_g < M) {
    if (w == 0) {
      uint b8[8];
#pragma unroll
      for (int i = 0; i < 8; i++)
        b8[i] = (uint)(__float2int_rn(v[i].x * qs) & 0xff)
              | ((uint)(__float2int_rn(v[i].y * qs) & 0xff) << 8)
              | ((uint)(__float2int_rn(v[i].z * qs) & 0xff) << 16)
              | ((uint)(__float2int_rn(v[i].w * qs) & 0xff) << 24);
      uint4* dst4 = (uint4*)(Zq8 + (size_t)row_g * 128 + part * 32);
      dst4[0] = make_uint4(b8[0], b8[1], b8[2], b8[3]);
      dst4[1] = make_uint4(b8[4], b8[5], b8[6], b8[7]);
      if (part == 0) sqv[row_g] = vmax * (1.0f / 127.0f);
    } else {
#pragma unroll
      for (int u = 0; u < 2; u++) {
#pragma unroll
        for (int hh = 0; hh < 2; hh++) {
          int un = part * 4 + u * 2 + hh;
          float4 va = v[u * 4 + hh * 2], vb = v[u * 4 + hh * 2 + 1];
          uint lo, hi;
          if (w == 1) {
            lo = (uint)(__float2int_rn(va.x * qs) & 0xff)
               | ((uint)(__float2int_rn(va.y * qs) & 0xff) << 8)
               | ((uint)(__float2int_rn(va.z * qs) & 0xff) << 16)
               | ((uint)(__float2int_rn(va.w * qs) & 0xff) << 24);
            hi = (uint)(__float2int_rn(vb.x * qs) & 0xff)
               | ((uint)(__float2int_rn(vb.y * qs) & 0xff) << 8)
               | ((uint)(__float2int_rn(vb.z * qs) & 0xff) << 16)
               | ((uint)(__float2int_rn(vb.w * qs) & 0xff) << 24);
          } else {
            lo = (uint)((__float2int_rn(va.x * qs) + 128) & 0xff)
               | ((uint)((__float2int_rn(va.y * qs) + 128) & 0xff) << 8)
               | ((uint)((__float2int_rn(va.z * qs) + 128) & 0xff) << 16)
               | ((uint)((__float2int_rn(va.w * qs) + 128) & 0xff) << 24);
            hi = (uint)((__float2int_rn(vb.x * qs) + 128) & 0xff)
               | ((uint)((__float2int_rn(vb.y * qs) + 128) & 0xff) << 8)
               | ((uint)((__float2int_rn(vb.z * qs) + 128) & 0xff) << 16)
               | ((uint)((__float2int_rn(vb.w * qs) + 128) & 0xff) << 24);
          }
          uint2* d2 = (uint2*)(Zkm + (size_t)row_g * 256 + un * 16 + (w == 2 ? 8 : 0));
          *d2 = make_uint2(lo, hi);
        }
      }
      if (part == 0) scales[row_g * 2 + (w - 1)] = vmax * (1.0f / 127.0f);
    }
  }
}

// ------- scan_sub: 1 block; exclusive scan of 512 sub-bucket totals -------
__global__ __launch_bounds__(256) void scan_sub(
    const int* __restrict__ subCur, int* __restrict__ subOff,
    int* __restrict__ offsets) {
  __shared__ int lds[256];
  int t = threadIdx.x;
  int c0 = subCur[(2 * t) * 16];
  int c1 = subCur[(2 * t + 1) * 16];
  lds[t] = c0 + c1;
  __syncthreads();
  for (int dd = 1; dd < 256; dd <<= 1) {
    int x = (t >= dd) ? lds[t - dd] : 0;
    __syncthreads();
    lds[t] += x;
    __syncthreads();
  }
  int excl = (t > 0) ? lds[t - 1] : 0;
  subOff[2 * t] = excl;
  subOff[2 * t + 1] = excl + c0;
  if (t == 0) offsets[NN] = NE;
}

// ------- hsc_sb: per-sub-bucket hist + scan + offsets-write + reorder + CSR flush ----
// Exclusive ownership of 256 dsts -> zero global atomics anywhere.
__global__ __launch_bounds__(256) void hsc_sb(
    const uint* __restrict__ stage2, const int* __restrict__ subCur,
    const int* __restrict__ subOff, int* __restrict__ offsets,
    int* __restrict__ csr_src) {
  int g = blockIdx.x;                    // 0..511
  int p = g >> 6;
  int n = subCur[g * 16];
  const uint* reg = stage2 + (size_t)g * REGION2;
  int dbase = p * 16384 + (g & 63) * 256;
  int base0 = subOff[g];
  __shared__ int cnt[256];
  __shared__ int lds[256];
  __shared__ int cur[256];
  __shared__ uint buf[REGION2];          // 20 KB
  int t = threadIdx.x;
  cnt[t] = 0;
  __syncthreads();
  for (int i = t; i < n; i += 256) atomicAdd(&cnt[reg[i] & 255u], 1);
  __syncthreads();
  lds[t] = cnt[t];
  __syncthreads();
  for (int dd = 1; dd < 256; dd <<= 1) {
    int x = (t >= dd) ? lds[t - dd] : 0;
    __syncthreads();
    lds[t] += x;
    __syncthreads();
  }
  int excl = (t > 0) ? lds[t - 1] : 0;
  if (dbase + t < NN) offsets[dbase + t] = base0 + excl;
  cur[t] = excl;
  __syncthreads();
  for (int i = t; i < n; i += 256) {
    uint v = reg[i];
    int ld = (int)(v & 255u);
    int pos = atomicAdd(&cur[ld], 1);    // LDS atomic only
    buf[pos] = v >> 14;
  }
  __syncthreads();
  for (int j = t; j < n; j += 256)
    csr_src[base0 + j] = (int)buf[j];
}

// ---------------- fallback path kernels (ws too small) ----------------
__global__ __launch_bounds__(256) void hist_part(
    const int2* __restrict__ stage, const int* __restrict__ stageCur,
    int* __restrict__ counts) {
  int p = blockIdx.x & 7;
  int k = blockIdx.x >> 3;
  int n = stageCur[p * 16];
  const int2* reg = stage + (size_t)p * REGION;
  for (int i = k * 256 + threadIdx.x; i < n; i += 32 * 256)
    atomicAdd(&counts[reg[i].y], 1);
}

__global__ __launch_bounds__(256) void scan_a(const int* __restrict__ counts,
                                              int* __restrict__ offsets,
                                              int* __restrict__ blockSums, int n) {
  __shared__ int lds[256];
  int b = blockIdx.x, t = threadIdx.x;
  int base = b * 1024 + t * 4;
  int4 v = make_int4(0, 0, 0, 0);
  if (base < n) v = *(const int4*)&counts[base];
  int s1 = v.x + v.y, s2 = s1 + v.z, s3 = s2 + v.w;
  lds[t] = s3;
  __syncthreads();
  for (int dd = 1; dd < 256; dd <<= 1) {
    int x = (t >= dd) ? lds[t - dd] : 0;
    __syncthreads();
    lds[t] += x;
    __syncthreads();
  }
  int excl = (t > 0) ? lds[t - 1] : 0;
  if (base < n) {
    int4 o = make_int4(excl, excl + v.x, excl + s1, excl + s2);
    *(int4*)&offsets[base] = o;
  }
  if (t == 255) blockSums[b] = lds[255];
}

__global__ __launch_bounds__(128) void scan_b(int* __restrict__ blockSums, int nb) {
  __shared__ int lds[128];
  int t = threadIdx.x;
  lds[t] = (t < nb) ? blockSums[t] : 0;
  __syncthreads();
  for (int dd = 1; dd < 128; dd <<= 1) {
    int x = (t >= dd) ? lds[t - dd] : 0;
    __syncthreads();
    lds[t] += x;
    __syncthreads();
  }
  if (t < nb) blockSums[t] = (t > 0) ? lds[t - 1] : 0;
}

__global__ __launch_bounds__(256) void scan_c(int* __restrict__ offsets,
                                              const int* __restrict__ blockSums,
                                              int* __restrict__ cursor, int n) {
  int i = blockIdx.x * 256 + threadIdx.x;
  if (i < n) {
    int v = offsets[i] + blockSums[i >> 10];
    offsets[i] = v;
    cursor[i] = v;
  }
  if (i == 0) offsets[n] = NE;
}

template <int MODE>
__global__ __launch_bounds__(256) void mfma_gemm(
    const ushort* __restrict__ A, const ushort* __restrict__ BT,
    const float* __restrict__ bias, void* __restrict__ Cp, int M, int ncols) {
  __shared__ ushort As[64 * 128];
  __shared__ ushort Bs[128 * 128];

  int t = threadIdx.x;
  int rowBase = blockIdx.x * 64, colBase = blockIdx.y * 128;

#pragma unroll
  for (int i = 0; i < 4; i++) {
    int flat = t + i * 256;
    int row = flat >> 4;
    int kb = (flat & 15) * 16;
    int soff = kb ^ ((row & 7) << 4);
    int ar = rowBase + row; if (ar >= M) ar = M - 1;
    __builtin_amdgcn_global_load_lds(
        (const __attribute__((address_space(1))) uint32_t*)((const char*)A + (size_t)ar * 256 + soff),
        (__attribute__((address_space(3))) uint32_t*)((char*)As + row * 256 + kb), 16, 0, 0);
  }
#pragma unroll
  for (int i = 0; i < 8; i++) {
    int flat = t + i * 256;
    int row = flat >> 4;
    int kb = (flat & 15) * 16;
    int soff = kb ^ ((row & 7) << 4);
    __builtin_amdgcn_global_load_lds(
        (const __attribute__((address_space(1))) uint32_t*)((const char*)BT + (size_t)(colBase + row) * 256 + soff),
        (__attribute__((address_space(3))) uint32_t*)((char*)Bs + row * 256 + kb), 16, 0, 0);
  }
  __syncthreads();

  int wv = t >> 6, L = t & 63;
  int wrow = (wv >> 1) * 32, wcol = (wv & 1) * 64;
  int lr = L & 15;
  int lk = (L >> 4) * 16;
  f32x4 acc[2][4] = {};

#pragma unroll
  for (int ks = 0; ks < 4; ks++) {
    bf16x8 a[2], b[4];
#pragma unroll
    for (int i = 0; i < 2; i++) {
      int row = wrow + i * 16 + lr;
      a[i] = *(const bf16x8*)((const char*)As + row * 256 + ((ks * 64 + lk) ^ ((row & 7) << 4)));
    }
#pragma unroll
    for (int j = 0; j < 4; j++) {
      int col = wcol + j * 16 + lr;
      b[j] = *(const bf16x8*)((const char*)Bs + col * 256 + ((ks * 64 + lk) ^ ((col & 7) << 4)));
    }
#pragma unroll
    for (int i = 0; i < 2; i++)
#pragma unroll
      for (int j = 0; j < 4; j++)
        acc[i][j] = __builtin_amdgcn_mfma_f32_16x16x32_bf16(a[i], b[j], acc[i][j], 0, 0, 0);
  }

  int rquad = (L >> 4) * 4;
#pragma unroll
  for (int j = 0; j < 4; j++) {
    int col = colBase + wcol + j * 16 + lr;
    float bs = bias[col];
#pragma unroll
    for (int i = 0; i < 2; i++) {
      int row0 = rowBase + wrow + i * 16 + rquad;
#pragma unroll
      for (int r = 0; r < 4; r++) {
        int row = row0 + r;
        if (row >= M) continue;
        float vv = acc[i][j][r] + bs;
        if (MODE == 0) {
          vv = fmaxf(vv, 0.f);
          ((float*)Cp)[(size_t)row * ncols + col] = vv;
        } else {
          ((ushort*)Cp)[(size_t)row * ncols + col] = f2b(vv);
        }
      }
    }
  }
}

__global__ __launch_bounds__(256) void quant_kernel(
    const ushort* __restrict__ Zbf, char* __restrict__ Zkm, float2* __restrict__ scales,
    char* __restrict__ Zq8, float* __restrict__ sqv) {
  int g = blockIdx.x * 256 + threadIdx.x;
  int row = g >> 4, u = g & 15;
  const ushort* zr = Zbf + (size_t)row * 384;
  uint4 kk = *(const uint4*)(zr + 128 + u * 8);
  uint4 mm = *(const uint4*)(zr + 256 + u * 8);
  uint4 qq = *(const uint4*)(zr + u * 8);
  float kf[8] = {b2f_lo(kk.x), b2f_hi(kk.x), b2f_lo(kk.y), b2f_hi(kk.y),
                 b2f_lo(kk.z), b2f_hi(kk.z), b2f_lo(kk.w), b2f_hi(kk.w)};
  float mf[8] = {b2f_lo(mm.x), b2f_hi(mm.x), b2f_lo(mm.y), b2f_hi(mm.y),
                 b2f_lo(mm.z), b2f_hi(mm.z), b2f_lo(mm.w), b2f_hi(mm.w)};
  float qf[8] = {b2f_lo(qq.x), b2f_hi(qq.x), b2f_lo(qq.y), b2f_hi(qq.y),
                 b2f_lo(qq.z), b2f_hi(qq.z), b2f_lo(qq.w), b2f_hi(qq.w)};
  float mk = 0.f, mx = 0.f, mqv = 0.f;
#pragma unroll
  for (int i = 0; i < 8; i++) {
    mk = fmaxf(mk, fabsf(kf[i]));
    mx = fmaxf(mx, fabsf(mf[i]));
    mqv = fmaxf(mqv, fabsf(qf[i]));
  }
#pragma unroll
  for (int dd = 1; dd < 16; dd <<= 1) {
    mk = fmaxf(mk, __shfl_xor(mk, dd));
    mx = fmaxf(mx, __shfl_xor(mx, dd));
    mqv = fmaxf(mqv, __shfl_xor(mqv, dd));
  }
  mk = fmaxf(mk, 1e-20f); mx = fmaxf(mx, 1e-20f); mqv = fmaxf(mqv, 1e-20f);
  float qk = 127.0f / mk, qm = 127.0f / mx;
  int q[16];
#pragma unroll
  for (int i = 0; i < 8; i++) {
    q[i] = __float2int_rn(kf[i] * qk) & 0xff;
    q[8 + i] = (__float2int_rn(mf[i] * qm) + 128) & 0xff;
  }
  uint4 o;
  o.x = (uint)(q[0] | (q[1] << 8) | (q[2] << 16) | (q[3] << 24));
  o.y = (uint)(q[4] | (q[5] << 8) | (q[6] << 16) | (q[7] << 24));
  o.z = (uint)(q[8] | (q[9] << 8) | (q[10] << 16) | (q[11] << 24));
  o.w = (uint)(q[12] | (q[13] << 8) | (q[14] << 16) | (q[15] << 24));
  *(uint4*)(Zkm + (size_t)row * 256 + u * 16) = o;
  if (u == 0) scales[row] = make_float2(mk * (1.0f / 127.0f), mx * (1.0f / 127.0f));
  float qsv = 127.0f / mqv;
  int r[8];
#pragma unroll
  for (int i = 0; i < 8; i++) r[i] = __float2int_rn(qf[i] * qsv) & 0xff;
  uint2 oq;
  oq.x = (uint)(r[0] | (r[1] << 8) | (r[2] << 16) | (r[3] << 24));
  oq.y = (uint)(r[4] | (r[5] << 8) | (r[6] << 16) | (r[7] << 24));
  *(uint2*)(Zq8 + (size_t)row * 128 + u * 8) = oq;
  if (u == 0) sqv[row] = mqv * (1.0f / 127.0f);
}

__global__ __launch_bounds__(256) void scatter_final(
    const int2* __restrict__ stage, const int* __restrict__ stageCur,
    int* __restrict__ cursor, int* __restrict__ csr_src) {
  int p = blockIdx.x & 7;
  int k = blockIdx.x >> 3;
  int n = stageCur[p * 16];
  const int2* reg = stage + (size_t)p * REGION;
  for (int i = k * 256 + threadIdx.x; i < n; i += 130 * 256) {
    int2 e = reg[i];
    int pos = atomicAdd(&cursor[e.y], 1);
    csr_src[pos] = e.x;
  }
}

// ---------------- fused attention + aggregation, int8 gathers ----------------
__global__ __launch_bounds__(256) void aggregate_q(
    const char* __restrict__ Zkm, const float* __restrict__ scales,
    const int* __restrict__ offsets, const int* __restrict__ csr_src,
    ushort* __restrict__ aggbf,
    const char* __restrict__ Zq8, const float* __restrict__ sqv) {
  int wv = threadIdx.x >> 6, L = threadIdx.x & 63;
  int n = blockIdx.x * 4 + wv;
  if (n >= NN) return;
  int qt = L >> 4, l = L & 15;
  int lb = l << 4;

  uint2 q8 = *(const uint2*)(Zq8 + (size_t)n * 128 + l * 8);
  float tq = TAU * sqv[n];

  int start = offsets[n], end = offsets[n + 1];
  float den = 0.f, swm = 0.f;
  float a0 = 0.f, a1 = 0.f, a2 = 0.f, a3 = 0.f, a4 = 0.f, a5 = 0.f, a6 = 0.f, a7 = 0.f;
  int p = start;

  for (; p + 8 <= end; p += 8) {
    int s0 = csr_src[p + qt];
    int s1 = csr_src[p + 4 + qt];
    uint4 v0 = *(const uint4*)(Zkm + ((size_t)s0 << 8) + lb);
    uint4 v1 = *(const uint4*)(Zkm + ((size_t)s1 << 8) + lb);
    float2 sc0 = *(const float2*)(scales + s0 * 2);
    float2 sc1 = *(const float2*)(scales + s1 * 2);

    int p0 = dot4i8(v0.x, q8.x, 0); p0 = dot4i8(v0.y, q8.y, p0);
    int p1 = dot4i8(v1.x, q8.x, 0); p1 = dot4i8(v1.y, q8.y, p1);
    p0 += __shfl_xor(p0, 1); p1 += __shfl_xor(p1, 1);
    p0 += __shfl_xor(p0, 2); p1 += __shfl_xor(p1, 2);
    float w0 = __expf(tq * sc0.x * (float)p0);
    float w1 = __expf(tq * sc1.x * (float)p1);
    den += w0 + w1;
    float wm0 = w0 * sc0.y, wm1 = w1 * sc1.y;
    swm += wm0 + wm1;

    a0 = fmaf(UB0(v0.z), wm0, a0); a1 = fmaf(UB1(v0.z), wm0, a1);
    a2 = fmaf(UB2(v0.z), wm0, a2); a3 = fmaf(UB3(v0.z), wm0, a3);
    a4 = fmaf(UB0(v0.w), wm0, a4); a5 = fmaf(UB1(v0.w), wm0, a5);
    a6 = fmaf(UB2(v0.w), wm0, a6); a7 = fmaf(UB3(v0.w), wm0, a7);
    a0 = fmaf(UB0(v1.z), wm1, a0); a1 = fmaf(UB1(v1.z), wm1, a1);
    a2 = fmaf(UB2(v1.z), wm1, a2); a3 = fmaf(UB3(v1.z), wm1, a3);
    a4 = fmaf(UB0(v1.w), wm1, a4); a5 = fmaf(UB1(v1.w), wm1, a5);
    a6 = fmaf(UB2(v1.w), wm1, a6); a7 = fmaf(UB3(v1.w), wm1, a7);
  }

  for (; p < end; p += 4) {
    int e = p + qt;
    int idx = (e < end) ? e : (end - 1);
    int s0 = csr_src[idx];
    uint4 v = *(const uint4*)(Zkm + ((size_t)s0 << 8) + lb);
    float2 sc = *(const float2*)(scales + s0 * 2);
    int p0 = dot4i8(v.x, q8.x, 0); p0 = dot4i8(v.y, q8.y, p0);
    p0 += __shfl_xor(p0, 1);
    p0 += __shfl_xor(p0, 2);
    float w = (e < end) ? __expf(tq * sc.x * (float)p0) : 0.f;
    den += w;
    float wm = w * sc.y;
    swm += wm;
    a0 = fmaf(UB0(v.z), wm, a0); a1 = fmaf(UB1(v.z), wm, a1);
    a2 = fmaf(UB2(v.z), wm, a2); a3 = fmaf(UB3(v.z), wm, a3);
    a4 = fmaf(UB0(v.w), wm, a4); a5 = fmaf(UB1(v.w), wm, a5);
    a6 = fmaf(UB2(v.w), wm, a6); a7 = fmaf(UB3(v.w), wm, a7);
  }

  den += __shfl_xor(den, 16); den += __shfl_xor(den, 32);
  swm += __shfl_xor(swm, 16); swm += __shfl_xor(swm, 32);
  a0 += __shfl_xor(a0, 16); a0 += __shfl_xor(a0, 32);
  a1 += __shfl_xor(a1, 16); a1 += __shfl_xor(a1, 32);
  a2 += __shfl_xor(a2, 16); a2 += __shfl_xor(a2, 32);
  a3 += __shfl_xor(a3, 16); a3 += __shfl_xor(a3, 32);
  a4 += __shfl_xor(a4, 16); a4 += __shfl_xor(a4, 32);
  a5 += __shfl_xor(a5, 16); a5 += __shfl_xor(a5, 32);
  a6 += __shfl_xor(a6, 16); a6 += __shfl_xor(a6, 32);
  a7 += __shfl_xor(a7, 16); a7 += __shfl_xor(a7, 32);

  float bcorr = 128.f * swm;
  float inv = (den > 0.f) ? 1.0f / den : 0.f;
  if (qt == 0) {
    uint4 o;
    o.x = (uint)f2b((a0 - bcorr) * inv) | ((uint)f2b((a1 - bcorr) * inv) << 16);
    o.y = (uint)f2b((a2 - bcorr) * inv) | ((uint)f2b((a3 - bcorr) * inv) << 16);
    o.z = (uint)f2b((a4 - bcorr) * inv) | ((uint)f2b((a5 - bcorr) * inv) << 16);
    o.w = (uint)f2b((a6 - bcorr) * inv) | ((uint)f2b((a7 - bcorr) * inv) << 16);
    *(uint4*)((char*)aggbf + (size_t)n * 256 + lb) = o;
  }
}

// ---------------- launch ----------------
extern "C" void kernel_launch(void* const* d_in, const int* in_sizes, int n_in,
                              void* d_out, int out_size, void* d_ws, size_t ws_size,
                              hipStream_t stream) {
  const float* h    = (const float*)d_in[0];
  const int*   src  = (const int*)d_in[1];
  const int*   dst  = (const int*)d_in[2];
  const float* Wq   = (const float*)d_in[3];
  const float* bq   = (const float*)d_in[4];
  const float* Wk   = (const float*)d_in[5];
  const float* bk   = (const float*)d_in[6];
  const float* Wm   = (const float*)d_in[7];
  const float* bm   = (const float*)d_in[8];
  const float* Wout = (const float*)d_in[9];
  const float* bout = (const float*)d_in[10];
  float* out = (float*)d_out;

  char* base = (char*)d_ws;
  ushort* Abf    = (ushort*)base;                         // NN*128 bf16
  char*   Zkm    = base + 25600000;                       // NN*256B int8
  char*   Zq8    = base + 51200000;                       // NN*128 int8
  ushort* Zbf    = (ushort*)(base + 25600000);            // fallback only
  ushort* aggbf  = (ushort*)(base + 102400000);           // NN*128 bf16
  int2*   stage  = (int2*)(base + 102400000);             // dead before aggbf written
  float*  scales = (float*)(base + 128000000);            // NN float2
  ushort* BTproj = (ushort*)(base + 128800000);
  ushort* BTout  = (ushort*)(base + 128898304);
  float*  bvec   = (float*)(base + 128931072);
  int* counts    = (int*)(base + 128933120);              // 400000
  int* stageCur  = (int*)(base + 129333120);              // 1024
  int* subCur    = (int*)(base + 129334144);              // 32768
  int* offsets   = (int*)(base + 129366912);              // 400128
  int* cursor    = (int*)(base + 129767040);              // 400000
  int* blockSums = (int*)(base + 130167040);              // 512
  int* subOff    = (int*)(base + 130167552);              // 2048 -> 130169600
  int* csr_src   = (int*)(base + 130169600);              // NE*4 -> 136569600
  char* Zq8_fb   = base + 136569600;                      // fallback Zq8
  float* sqv     = (float*)(base + 149369600);            // NN f32 -> 149769600
  uint* stage2   = (uint*)(base + 149769600);             // -> 160255360

  int fast = (ws_size >= (size_t)160255360) ? 1 : 0;

  hipMemsetAsync(counts, 0, 433792, stream);   // counts + stageCur + subCur

  setup_stage<<<7288, 256, 0, stream>>>(h, Abf, Wq, Wk, Wm, bq, bk, bm, Wout,
                                        BTproj, BTout, bvec, src, dst, stageCur, stage);

  if (fast) {
    gemm2_stage2<<<5713, 256, 0, stream>>>(Abf, BTproj, bvec, Zkm, Zq8, scales, sqv,
                                           NN, stage, stageCur, subCur, stage2);
    scan_sub<<<1, 256, 0, stream>>>(subCur, subOff, offsets);
    hsc_sb<<<512, 256, 0, stream>>>(stage2, subCur, subOff, offsets, csr_src);
    aggregate_q<<<25000, 256, 0, stream>>>(Zkm, scales, offsets, csr_src, aggbf, Zq8, sqv);
  } else {
    hist_part<<<256, 256, 0, stream>>>(stage, stageCur, counts);
    scan_a<<<98, 256, 0, stream>>>(counts, offsets, blockSums, NN);
    scan_b<<<1, 128, 0, stream>>>(blockSums, 98);
    scan_c<<<391, 256, 0, stream>>>(offsets, blockSums, cursor, NN);
    mfma_gemm<1><<<dim3(1563, 3), 256, 0, stream>>>(Abf, BTproj, bvec, Zbf, NN, 384);
    quant_kernel<<<6250, 256, 0, stream>>>(Zbf, (char*)base, (float2*)scales, Zq8_fb, sqv);
    scatter_final<<<1040, 256, 0, stream>>>(stage, stageCur, cursor, csr_src);
    aggregate_q<<<25000, 256, 0, stream>>>((char*)base, scales, offsets, csr_src,
                                           aggbf, Zq8_fb, sqv);
  }

  mfma_gemm<0><<<dim3(1563, 1), 256, 0, stream>>>(aggbf, BTout, bout, out, NN, 128);
}